// Round 1
// baseline (1333.215 us; speedup 1.0000x reference)
//
#include <hip/hip_runtime.h>

#define N_NODES 50000
#define N_EDGES 400000
#define F_IN    128
#define F_EDGE  32
#define F       32
#define H       4
#define NHF     128   // H*F

// ---- monotonic float<->uint encoding for atomicMax on signed floats ----
// init-0 workspace acts as "-inf": every finite float encodes > 0.
__device__ __forceinline__ unsigned enc_f32(float f) {
    unsigned u = __float_as_uint(f);
    return (u & 0x80000000u) ? ~u : (u | 0x80000000u);
}
__device__ __forceinline__ float dec_f32(unsigned e) {
    unsigned u = (e & 0x80000000u) ? (e & 0x7FFFFFFFu) : ~e;
    return __uint_as_float(u);
}

// ---- atom_in = relu(x @ atom_w + atom_b), x:(N,128), W:(128,128) ----
__global__ __launch_bounds__(256) void k_atom(const float* __restrict__ x,
                                              const float* __restrict__ w,
                                              const float* __restrict__ b,
                                              float* __restrict__ out) {
    __shared__ float wlds[F_IN * NHF];              // 64 KB
    const float4* w4 = (const float4*)w;
    float4* wl4 = (float4*)wlds;
    for (int i = threadIdx.x; i < F_IN * NHF / 4; i += 256) wl4[i] = w4[i];
    __syncthreads();
    int jg = threadIdx.x & 31;                      // output group: j = jg*4
    int nl = threadIdx.x >> 5;                      // 0..7 node-in-block
    int n = blockIdx.x * 8 + nl;
    if (n >= N_NODES) return;
    const float* xr = x + (size_t)n * F_IN;
    float4 acc = *(const float4*)(b + jg * 4);
    for (int k = 0; k < F_IN; k++) {
        float xk = xr[k];
        float4 wv = *(const float4*)(wlds + k * NHF + jg * 4);
        acc.x += xk * wv.x; acc.y += xk * wv.y;
        acc.z += xk * wv.z; acc.w += xk * wv.w;
    }
    acc.x = fmaxf(acc.x, 0.f); acc.y = fmaxf(acc.y, 0.f);
    acc.z = fmaxf(acc.z, 0.f); acc.w = fmaxf(acc.w, 0.f);
    *(float4*)(out + (size_t)n * NHF + jg * 4) = acc;
}

// ---- xs,xd,xm = h @ {Ws,Wd,Wm} + b  (per-head shared 32x32 weights) ----
__global__ __launch_bounds__(256) void k_nodelin3(const float* __restrict__ h,
        const float* __restrict__ ws, const float* __restrict__ bs,
        const float* __restrict__ wd, const float* __restrict__ bd,
        const float* __restrict__ wm, const float* __restrict__ bm,
        float* __restrict__ xs, float* __restrict__ xd, float* __restrict__ xm) {
    __shared__ float Ws[F * F], Wd[F * F], Wm[F * F];
    for (int i = threadIdx.x; i < F * F; i += 256) {
        Ws[i] = ws[i]; Wd[i] = wd[i]; Wm[i] = wm[i];
    }
    __syncthreads();
    int j = threadIdx.x & 31;
    int rl = threadIdx.x >> 5;
    size_t r = (size_t)blockIdx.x * 8 + rl;         // row in [0, N*H)
    if (r >= (size_t)N_NODES * H) return;
    const float* hr = h + r * F;                    // (n*H+head)*F == n*128+head*32
    float as = bs[j], ad = bd[j], am = bm[j];
    for (int k = 0; k < F; k++) {
        float hk = hr[k];
        as += hk * Ws[k * F + j];
        ad += hk * Wd[k * F + j];
        am += hk * Wm[k * F + j];
    }
    xs[r * F + j] = as; xd[r * F + j] = ad; xm[r * F + j] = am;
}

// ---- out = edge_attr @ W + b, (E,32)@(32,32) ----
__global__ __launch_bounds__(256) void k_edgelin(const float* __restrict__ ein,
        const float* __restrict__ w, const float* __restrict__ b,
        float* __restrict__ out) {
    __shared__ float W[F_EDGE * F];
    for (int i = threadIdx.x; i < F_EDGE * F; i += 256) W[i] = w[i];
    __syncthreads();
    int j = threadIdx.x & 31;
    int rl = threadIdx.x >> 5;
    int e = blockIdx.x * 8 + rl;
    if (e >= N_EDGES) return;
    const float* er = ein + (size_t)e * F_EDGE;
    float acc = b[j];
    for (int k = 0; k < F_EDGE; k++) acc += er[k] * W[k * F + j];
    out[(size_t)e * F + j] = acc;
}

// ---- alpha_raw[e,h] = relu(xs[dst]+xd[src]+ea) . dw + db ; atomicMax node_max ----
__global__ __launch_bounds__(256) void k_logits(const float* __restrict__ xs,
        const float* __restrict__ xd, const float* __restrict__ ea,
        const int* __restrict__ src, const int* __restrict__ dst,
        const float* __restrict__ dw, const float* __restrict__ db,
        float* __restrict__ logits, unsigned* __restrict__ node_max) {
    int t = blockIdx.x * 256 + threadIdx.x;         // t = e*4 + h, total E*H
    int e = t >> 2, hh = t & 3;
    int d = dst[e], s = src[e];
    const float4* a4 = (const float4*)(xs + (size_t)d * NHF + hh * F);
    const float4* b4 = (const float4*)(xd + (size_t)s * NHF + hh * F);
    const float4* c4 = (const float4*)(ea + (size_t)e * F);
    const float4* w4 = (const float4*)dw;
    float acc = 0.f;
#pragma unroll
    for (int q = 0; q < 8; q++) {
        float4 av = a4[q], bv = b4[q], cv = c4[q], wv = w4[q];
        acc += fmaxf(av.x + bv.x + cv.x, 0.f) * wv.x;
        acc += fmaxf(av.y + bv.y + cv.y, 0.f) * wv.y;
        acc += fmaxf(av.z + bv.z + cv.z, 0.f) * wv.z;
        acc += fmaxf(av.w + bv.w + cv.w, 0.f) * wv.w;
    }
    acc += db[0];
    logits[t] = acc;
    // joint-over-heads max: reduce across the 4 consecutive lanes of this edge
    float m = acc;
    m = fmaxf(m, __shfl_xor(m, 1));
    m = fmaxf(m, __shfl_xor(m, 2));
    if (hh == 0) atomicMax(node_max + d, enc_f32(m));
}

// ---- exp in place + per-node sum (joint over heads) ----
__global__ __launch_bounds__(256) void k_expsum(const int* __restrict__ dst,
        const unsigned* __restrict__ node_max, float* __restrict__ logits,
        float* __restrict__ node_sum) {
    int e = blockIdx.x * 256 + threadIdx.x;
    if (e >= N_EDGES) return;
    int d = dst[e];
    float m = dec_f32(node_max[d]);
    float4 a = *(float4*)(logits + (size_t)e * 4);
    a.x = __expf(a.x - m); a.y = __expf(a.y - m);
    a.z = __expf(a.z - m); a.w = __expf(a.w - m);
    *(float4*)(logits + (size_t)e * 4) = a;
    atomicAdd(node_sum + d, a.x + a.y + a.z + a.w);
}

// ---- messages + scatter. Message k=e*H+h targets flat row dst[k mod E] of
// (N*H, F). The 4 k's with k≡r (mod E) share target dst[r]: accumulate in
// registers, one atomic burst per r (4x atomic reduction). ----
__global__ __launch_bounds__(256) void k_msg(const float* __restrict__ xm,
        const float* __restrict__ em, const float* __restrict__ logits,
        const float* __restrict__ node_sum, const int* __restrict__ dst,
        float* __restrict__ aggr) {
    int t = blockIdx.x * 256 + threadIdx.x;         // t = r*8 + f4 ; E*8 total
    int r = t >> 3, f4 = t & 7;
    float4 acc = make_float4(0.f, 0.f, 0.f, 0.f);
#pragma unroll
    for (int j = 0; j < 4; j++) {
        int k = r + j * N_EDGES;
        int e = k >> 2, hh = k & 3;
        int de = dst[e];
        float a = logits[k] / (node_sum[de] + 1e-8f);
        float4 xv = *(const float4*)(xm + (size_t)de * NHF + hh * F + f4 * 4);
        float4 ev = *(const float4*)(em + (size_t)e * F + f4 * 4);
        acc.x += a * (xv.x + ev.x); acc.y += a * (xv.y + ev.y);
        acc.z += a * (xv.z + ev.z); acc.w += a * (xv.w + ev.w);
    }
    int dr = dst[r];
    float* o = aggr + (size_t)dr * F + f4 * 4;
    atomicAdd(o + 0, acc.x); atomicAdd(o + 1, acc.y);
    atomicAdd(o + 2, acc.z); atomicAdd(o + 3, acc.w);
}

// ---- h_out = relu(aggr + h@Wn + bn + atom_in); final layer: mean over heads ----
__global__ __launch_bounds__(128) void k_combine(const float* __restrict__ h,
        const float* __restrict__ aggr, const float* __restrict__ atom_in,
        const float* __restrict__ wn, const float* __restrict__ bn,
        float* __restrict__ hout, float* __restrict__ final_out, int is_final) {
    __shared__ float W[F * F];
    __shared__ float sm[NHF];
    for (int i = threadIdx.x; i < F * F; i += 128) W[i] = wn[i];
    __syncthreads();
    int n = blockIdx.x;
    int head = threadIdx.x >> 5, j = threadIdx.x & 31;
    const float* hr = h + (size_t)n * NHF + head * F;
    float acc = bn[j];
    for (int k = 0; k < F; k++) acc += hr[k] * W[k * F + j];
    size_t idx = (size_t)n * NHF + head * F + j;
    float v = aggr[idx] + acc + atom_in[idx];       // aggr flat (N*H,F) == (N,H,F)
    v = fmaxf(v, 0.f);
    if (!is_final) {
        hout[idx] = v;
    } else {
        sm[threadIdx.x] = v;
        __syncthreads();
        if (threadIdx.x < F) {
            float o = 0.25f * (sm[threadIdx.x] + sm[F + threadIdx.x] +
                               sm[2 * F + threadIdx.x] + sm[3 * F + threadIdx.x]);
            final_out[(size_t)n * F + threadIdx.x] = o;
        }
    }
}

extern "C" void kernel_launch(void* const* d_in, const int* in_sizes, int n_in,
                              void* d_out, int out_size, void* d_ws, size_t ws_size,
                              hipStream_t stream) {
    const float* x         = (const float*)d_in[0];
    const float* edge_attr = (const float*)d_in[1];
    const int*   eidx      = (const int*)d_in[2];
    const int*   src       = eidx;
    const int*   dst       = eidx + N_EDGES;
    const float* atom_w    = (const float*)d_in[3];
    const float* atom_b    = (const float*)d_in[4];
    const float* asw = (const float*)d_in[5],  *asb = (const float*)d_in[6];
    const float* adw = (const float*)d_in[7],  *adb = (const float*)d_in[8];
    const float* aew = (const float*)d_in[9],  *aeb = (const float*)d_in[10];
    const float* dww = (const float*)d_in[11], *dwb = (const float*)d_in[12];
    const float* mdw = (const float*)d_in[13], *mdb = (const float*)d_in[14];
    const float* mew = (const float*)d_in[15], *meb = (const float*)d_in[16];
    const float* wnw = (const float*)d_in[17], *wnb = (const float*)d_in[18];
    float* out = (float*)d_out;

    // workspace layout (floats); em aliases xs+xd (dead after k_logits)
    float* ws = (float*)d_ws;
    size_t off = 0;
    float* atom_in = ws + off; off += (size_t)N_NODES * NHF;
    float* hbuf    = ws + off; off += (size_t)N_NODES * NHF;
    float* xs      = ws + off; off += (size_t)N_NODES * NHF;
    float* xd      = ws + off; off += (size_t)N_NODES * NHF;
    float* xm      = ws + off; off += (size_t)N_NODES * NHF;
    float* ea      = ws + off; off += (size_t)N_EDGES * F;
    float* logits  = ws + off; off += (size_t)N_EDGES * H;
    float* node_max= ws + off; off += N_NODES;
    float* node_sum= ws + off; off += N_NODES;
    float* aggr    = ws + off; off += (size_t)N_NODES * H * F;
    float* em      = xs;  // E*F == 2 * N*NHF exactly

    k_atom<<<N_NODES / 8, 256, 0, stream>>>(x, atom_w, atom_b, atom_in);

    for (int l = 0; l < 2; l++) {
        const float* hin  = (l == 0) ? atom_in : hbuf;
        float*       hout = hbuf;
        int is_final = (l == 1);
        // zero node_max + node_sum + aggr (contiguous)
        hipMemsetAsync(node_max, 0,
                       (size_t)(2 * N_NODES + (size_t)N_NODES * H * F) * sizeof(float),
                       stream);
        k_nodelin3<<<(N_NODES * H) / 8, 256, 0, stream>>>(
            hin, asw + l * F * F, asb + l * F, adw + l * F * F, adb + l * F,
            mdw + l * F * F, mdb + l * F, xs, xd, xm);
        k_edgelin<<<N_EDGES / 8, 256, 0, stream>>>(edge_attr, aew + l * F_EDGE * F,
                                                   aeb + l * F, ea);
        k_logits<<<(N_EDGES * H) / 256, 256, 0, stream>>>(
            xs, xd, ea, src, dst, dww + l * F, dwb + l, logits,
            (unsigned*)node_max);
        k_edgelin<<<N_EDGES / 8, 256, 0, stream>>>(edge_attr, mew + l * F_EDGE * F,
                                                   meb + l * F, em);
        k_expsum<<<(N_EDGES + 255) / 256, 256, 0, stream>>>(
            dst, (const unsigned*)node_max, logits, node_sum);
        k_msg<<<(N_EDGES * 8) / 256, 256, 0, stream>>>(xm, em, logits, node_sum,
                                                       dst, aggr);
        k_combine<<<N_NODES, 128, 0, stream>>>(hin, aggr, atom_in,
                                               wnw + l * F * F, wnb + l * F,
                                               hout, out, is_final);
    }
}

// Round 2
// 1155.604 us; speedup vs baseline: 1.1537x; 1.1537x over previous
//
#include <hip/hip_runtime.h>

#define N_NODES 50000
#define N_EDGES 400000
#define F_IN    128
#define F_EDGE  32
#define F       32
#define H       4
#define NHF     128   // H*F

#define SCAN_BLK 512
#define N_SCAN_BLKS ((N_NODES + SCAN_BLK - 1) / SCAN_BLK)   // 98

// ---- atom_in = relu(x @ atom_w + atom_b); 32 nodes/block, x tile in LDS ----
__global__ __launch_bounds__(256) void k_atom(const float* __restrict__ x,
                                              const float* __restrict__ w,
                                              const float* __restrict__ b,
                                              float* __restrict__ out) {
    __shared__ float wlds[F_IN * NHF];              // 64 KB
    __shared__ float xl[32 * F_IN];                 // 16 KB
    const float4* w4 = (const float4*)w;
    float4* wl4 = (float4*)wlds;
    for (int i = threadIdx.x; i < F_IN * NHF / 4; i += 256) wl4[i] = w4[i];
    int nb = blockIdx.x * 32;
    int nrows = min(32, N_NODES - nb);
    const float4* x4 = (const float4*)(x + (size_t)nb * F_IN);
    float4* xl4 = (float4*)xl;
    for (int i = threadIdx.x; i < nrows * F_IN / 4; i += 256) xl4[i] = x4[i];
    __syncthreads();
    int jg = threadIdx.x & 31;                      // output col group (4 cols)
    int nl = threadIdx.x >> 5;                      // 0..7
    float4 bv = *(const float4*)(b + jg * 4);
    float4 acc[4] = {bv, bv, bv, bv};
    for (int k = 0; k < F_IN; k++) {
        float4 wv = *(const float4*)(wlds + k * NHF + jg * 4);
#pragma unroll
        for (int q = 0; q < 4; q++) {
            float xk = xl[(nl + 8 * q) * F_IN + k];
            acc[q].x += xk * wv.x; acc[q].y += xk * wv.y;
            acc[q].z += xk * wv.z; acc[q].w += xk * wv.w;
        }
    }
#pragma unroll
    for (int q = 0; q < 4; q++) {
        int n = nb + nl + 8 * q;
        if (n < N_NODES) {
            float4 a = acc[q];
            a.x = fmaxf(a.x, 0.f); a.y = fmaxf(a.y, 0.f);
            a.z = fmaxf(a.z, 0.f); a.w = fmaxf(a.w, 0.f);
            *(float4*)(out + (size_t)n * NHF + jg * 4) = a;
        }
    }
}

// ---- CSR build: histogram / scan / fill ----
__global__ __launch_bounds__(256) void k_hist(const int* __restrict__ dst,
                                              int* __restrict__ counts) {
    int e = blockIdx.x * 256 + threadIdx.x;
    if (e < N_EDGES) atomicAdd(counts + dst[e], 1);
}

__global__ __launch_bounds__(SCAN_BLK) void k_scan1(const int* __restrict__ counts,
        int* __restrict__ excl, int* __restrict__ bsum) {
    __shared__ int s[SCAN_BLK];
    int i = blockIdx.x * SCAN_BLK + threadIdx.x;
    int v = (i < N_NODES) ? counts[i] : 0;
    s[threadIdx.x] = v;
    __syncthreads();
    for (int d = 1; d < SCAN_BLK; d <<= 1) {
        int t = (threadIdx.x >= d) ? s[threadIdx.x - d] : 0;
        __syncthreads();
        s[threadIdx.x] += t;
        __syncthreads();
    }
    if (i < N_NODES) excl[i] = s[threadIdx.x] - v;   // exclusive within block
    if (threadIdx.x == SCAN_BLK - 1) bsum[blockIdx.x] = s[SCAN_BLK - 1];
}

__global__ __launch_bounds__(128) void k_scan2(int* __restrict__ bsum) {
    __shared__ int s[128];
    int v = (threadIdx.x < N_SCAN_BLKS) ? bsum[threadIdx.x] : 0;
    s[threadIdx.x] = v;
    __syncthreads();
    for (int d = 1; d < 128; d <<= 1) {
        int t = (threadIdx.x >= d) ? s[threadIdx.x - d] : 0;
        __syncthreads();
        s[threadIdx.x] += t;
        __syncthreads();
    }
    if (threadIdx.x < N_SCAN_BLKS) bsum[threadIdx.x] = s[threadIdx.x] - v;
}

__global__ __launch_bounds__(SCAN_BLK) void k_scan3(const int* __restrict__ excl,
        const int* __restrict__ bsum, int* __restrict__ row_start,
        int* __restrict__ cursor) {
    int i = blockIdx.x * SCAN_BLK + threadIdx.x;
    if (i < N_NODES) {
        int v = excl[i] + bsum[blockIdx.x];
        row_start[i] = v;
        cursor[i] = v;
    }
}

__global__ __launch_bounds__(256) void k_fill(const int* __restrict__ dst,
        int* __restrict__ cursor, int* __restrict__ csr_e) {
    int e = blockIdx.x * 256 + threadIdx.x;
    if (e < N_EDGES) {
        int pos = atomicAdd(cursor + dst[e], 1);
        csr_e[pos] = e;
    }
}

// ---- xs,xd,xm = h @ {Ws,Wd,Wm} + b ----
__global__ __launch_bounds__(256) void k_nodelin3(const float* __restrict__ h,
        const float* __restrict__ ws, const float* __restrict__ bs,
        const float* __restrict__ wd, const float* __restrict__ bd,
        const float* __restrict__ wm, const float* __restrict__ bm,
        float* __restrict__ xs, float* __restrict__ xd, float* __restrict__ xm) {
    __shared__ float Ws[F * F], Wd[F * F], Wm[F * F];
    for (int i = threadIdx.x; i < F * F; i += 256) {
        Ws[i] = ws[i]; Wd[i] = wd[i]; Wm[i] = wm[i];
    }
    __syncthreads();
    int j = threadIdx.x & 31;
    int rl = threadIdx.x >> 5;
    size_t r = (size_t)blockIdx.x * 8 + rl;
    if (r >= (size_t)N_NODES * H) return;
    const float* hr = h + r * F;
    float as = bs[j], ad = bd[j], am = bm[j];
    for (int k = 0; k < F; k++) {
        float hk = hr[k];
        as += hk * Ws[k * F + j];
        ad += hk * Wd[k * F + j];
        am += hk * Wm[k * F + j];
    }
    xs[r * F + j] = as; xd[r * F + j] = ad; xm[r * F + j] = am;
}

// ---- out = edge_attr @ W + b ----
__global__ __launch_bounds__(256) void k_edgelin(const float* __restrict__ ein,
        const float* __restrict__ w, const float* __restrict__ b,
        float* __restrict__ out) {
    __shared__ float W[F_EDGE * F];
    for (int i = threadIdx.x; i < F_EDGE * F; i += 256) W[i] = w[i];
    __syncthreads();
    int j = threadIdx.x & 31;
    int rl = threadIdx.x >> 5;
    int e = blockIdx.x * 8 + rl;
    if (e >= N_EDGES) return;
    const float* er = ein + (size_t)e * F_EDGE;
    float acc = b[j];
    for (int k = 0; k < F_EDGE; k++) acc += er[k] * W[k * F + j];
    out[(size_t)e * F + j] = acc;
}

// ---- raw logits: relu(xs[dst]+xd[src]+ea) . dw + db ----
__global__ __launch_bounds__(256) void k_logits(const float* __restrict__ xs,
        const float* __restrict__ xd, const float* __restrict__ ea,
        const int* __restrict__ src, const int* __restrict__ dst,
        const float* __restrict__ dw, const float* __restrict__ db,
        float* __restrict__ logits) {
    int t = blockIdx.x * 256 + threadIdx.x;         // t = e*4 + h
    int e = t >> 2, hh = t & 3;
    int d = dst[e], s = src[e];
    const float4* a4 = (const float4*)(xs + (size_t)d * NHF + hh * F);
    const float4* b4 = (const float4*)(xd + (size_t)s * NHF + hh * F);
    const float4* c4 = (const float4*)(ea + (size_t)e * F);
    const float4* w4 = (const float4*)dw;
    float acc = 0.f;
#pragma unroll
    for (int q = 0; q < 8; q++) {
        float4 av = a4[q], bv = b4[q], cv = c4[q], wv = w4[q];
        acc += fmaxf(av.x + bv.x + cv.x, 0.f) * wv.x;
        acc += fmaxf(av.y + bv.y + cv.y, 0.f) * wv.y;
        acc += fmaxf(av.z + bv.z + cv.z, 0.f) * wv.z;
        acc += fmaxf(av.w + bv.w + cv.w, 0.f) * wv.w;
    }
    logits[t] = acc + db[0];
}

// ---- pull softmax per node (joint over heads), alpha written in place ----
__global__ __launch_bounds__(256) void k_softmax(const int* __restrict__ row_start,
        const int* __restrict__ counts, const int* __restrict__ csr_e,
        float* __restrict__ logits) {
    int n = blockIdx.x * 4 + (threadIdx.x >> 6);
    if (n >= N_NODES) return;
    int lane = threadIdx.x & 63;
    int start = row_start[n];
    int items = counts[n] * 4;
    float m = -1e30f;
    for (int i = lane; i < items; i += 64) {
        int e = csr_e[start + (i >> 2)];
        m = fmaxf(m, logits[e * 4 + (i & 3)]);
    }
#pragma unroll
    for (int d = 1; d < 64; d <<= 1) m = fmaxf(m, __shfl_xor(m, d));
    float ssum = 0.f;
    for (int i = lane; i < items; i += 64) {
        int e = csr_e[start + (i >> 2)];
        ssum += __expf(logits[e * 4 + (i & 3)] - m);
    }
#pragma unroll
    for (int d = 1; d < 64; d <<= 1) ssum += __shfl_xor(ssum, d);
    float inv = 1.f / (ssum + 1e-8f);
    for (int i = lane; i < items; i += 64) {
        int e = csr_e[start + (i >> 2)];
        int idx = e * 4 + (i & 3);
        logits[idx] = __expf(logits[idx] - m) * inv;
    }
}

// ---- pull aggregation: flat row m of (N*H,F) view gets messages k with
// dst[k mod E] == m; k = r + j*E, e=k>>2, h=k&3. Register accumulate, one
// plain 128B store per row. No atomics, no memset. ----
__global__ __launch_bounds__(256) void k_msg_pull(const int* __restrict__ row_start,
        const int* __restrict__ counts, const int* __restrict__ csr_e,
        const float* __restrict__ xm, const float* __restrict__ em,
        const float* __restrict__ alpha, const int* __restrict__ dst,
        float* __restrict__ aggr) {
    int m = blockIdx.x * 8 + (threadIdx.x >> 5);
    if (m >= N_NODES) return;
    int f = threadIdx.x & 31;
    int start = row_start[m];
    int deg = counts[m];
    float acc = 0.f;
    for (int ii = 0; ii < deg; ii++) {
        int r = csr_e[start + ii];
#pragma unroll
        for (int j = 0; j < 4; j++) {
            int k = r + j * N_EDGES;
            int e = k >> 2, hh = k & 3;
            int de = dst[e];
            float a = alpha[k];
            acc += a * (xm[(size_t)de * NHF + hh * F + f] + em[(size_t)e * F + f]);
        }
    }
    aggr[(size_t)m * F + f] = acc;
}

// ---- h_out = relu(aggr + h@Wn + bn + atom_in); final: mean over heads ----
__global__ __launch_bounds__(128) void k_combine(const float* __restrict__ h,
        const float* __restrict__ aggr, const float* __restrict__ atom_in,
        const float* __restrict__ wn, const float* __restrict__ bn,
        float* __restrict__ hout, float* __restrict__ final_out, int is_final) {
    __shared__ float W[F * F];
    __shared__ float sm[NHF];
    for (int i = threadIdx.x; i < F * F; i += 128) W[i] = wn[i];
    __syncthreads();
    int n = blockIdx.x;
    int head = threadIdx.x >> 5, j = threadIdx.x & 31;
    const float* hr = h + (size_t)n * NHF + head * F;
    float acc = bn[j];
    for (int k = 0; k < F; k++) acc += hr[k] * W[k * F + j];
    int flat = n * H + head;                        // row of (N*H,F) view
    float ag = (flat < N_NODES) ? aggr[(size_t)flat * F + j] : 0.f;
    size_t idx = (size_t)n * NHF + head * F + j;
    float v = ag + acc + atom_in[idx];
    v = fmaxf(v, 0.f);
    if (!is_final) {
        hout[idx] = v;
    } else {
        sm[threadIdx.x] = v;
        __syncthreads();
        if (threadIdx.x < F) {
            float o = 0.25f * (sm[threadIdx.x] + sm[F + threadIdx.x] +
                               sm[2 * F + threadIdx.x] + sm[3 * F + threadIdx.x]);
            final_out[(size_t)n * F + threadIdx.x] = o;
        }
    }
}

extern "C" void kernel_launch(void* const* d_in, const int* in_sizes, int n_in,
                              void* d_out, int out_size, void* d_ws, size_t ws_size,
                              hipStream_t stream) {
    const float* x         = (const float*)d_in[0];
    const float* edge_attr = (const float*)d_in[1];
    const int*   eidx      = (const int*)d_in[2];
    const int*   src       = eidx;
    const int*   dst       = eidx + N_EDGES;
    const float* atom_w    = (const float*)d_in[3];
    const float* atom_b    = (const float*)d_in[4];
    const float* asw = (const float*)d_in[5],  *asb = (const float*)d_in[6];
    const float* adw = (const float*)d_in[7],  *adb = (const float*)d_in[8];
    const float* aew = (const float*)d_in[9],  *aeb = (const float*)d_in[10];
    const float* dww = (const float*)d_in[11], *dwb = (const float*)d_in[12];
    const float* mdw = (const float*)d_in[13], *mdb = (const float*)d_in[14];
    const float* mew = (const float*)d_in[15], *meb = (const float*)d_in[16];
    const float* wnw = (const float*)d_in[17], *wnb = (const float*)d_in[18];
    float* out = (float*)d_out;

    // workspace layout (floats); em aliases xs+xd (dead after k_logits)
    float* ws = (float*)d_ws;
    size_t off = 0;
    float* atom_in = ws + off; off += (size_t)N_NODES * NHF;
    float* hbuf    = ws + off; off += (size_t)N_NODES * NHF;
    float* xs      = ws + off; off += (size_t)N_NODES * NHF;
    float* xd      = ws + off; off += (size_t)N_NODES * NHF;
    float* xm      = ws + off; off += (size_t)N_NODES * NHF;
    float* ea      = ws + off; off += (size_t)N_EDGES * F;
    float* logits  = ws + off; off += (size_t)N_EDGES * H;
    float* aggr    = ws + off; off += (size_t)N_NODES * F;
    int* counts    = (int*)(ws + off); off += N_NODES;
    int* row_start = (int*)(ws + off); off += N_NODES;
    int* cursor    = (int*)(ws + off); off += N_NODES;
    int* excl      = (int*)(ws + off); off += N_NODES;
    int* bsum      = (int*)(ws + off); off += 128;
    int* csr_e     = (int*)(ws + off); off += N_EDGES;
    float* em      = xs;  // E*F == 2 * N*NHF exactly

    // ---- CSR build (dst is layer-invariant; once per call) ----
    hipMemsetAsync(counts, 0, N_NODES * sizeof(int), stream);
    k_hist <<<(N_EDGES + 255) / 256, 256, 0, stream>>>(dst, counts);
    k_scan1<<<N_SCAN_BLKS, SCAN_BLK, 0, stream>>>(counts, excl, bsum);
    k_scan2<<<1, 128, 0, stream>>>(bsum);
    k_scan3<<<N_SCAN_BLKS, SCAN_BLK, 0, stream>>>(excl, bsum, row_start, cursor);
    k_fill <<<(N_EDGES + 255) / 256, 256, 0, stream>>>(dst, cursor, csr_e);

    k_atom<<<(N_NODES + 31) / 32, 256, 0, stream>>>(x, atom_w, atom_b, atom_in);

    for (int l = 0; l < 2; l++) {
        const float* hin  = (l == 0) ? atom_in : hbuf;
        float*       hout = hbuf;
        int is_final = (l == 1);
        k_nodelin3<<<(N_NODES * H) / 8, 256, 0, stream>>>(
            hin, asw + l * F * F, asb + l * F, adw + l * F * F, adb + l * F,
            mdw + l * F * F, mdb + l * F, xs, xd, xm);
        k_edgelin<<<N_EDGES / 8, 256, 0, stream>>>(edge_attr, aew + l * F_EDGE * F,
                                                   aeb + l * F, ea);
        k_logits<<<(N_EDGES * H) / 256, 256, 0, stream>>>(
            xs, xd, ea, src, dst, dww + l * F, dwb + l, logits);
        k_edgelin<<<N_EDGES / 8, 256, 0, stream>>>(edge_attr, mew + l * F_EDGE * F,
                                                   meb + l * F, em);
        k_softmax<<<(N_NODES + 3) / 4, 256, 0, stream>>>(row_start, counts, csr_e,
                                                         logits);
        k_msg_pull<<<(N_NODES + 7) / 8, 256, 0, stream>>>(row_start, counts, csr_e,
                                                          xm, em, logits, dst, aggr);
        k_combine<<<N_NODES, 128, 0, stream>>>(hin, aggr, atom_in,
                                               wnw + l * F * F, wnb + l * F,
                                               hout, out, is_final);
    }
}

// Round 3
// 904.601 us; speedup vs baseline: 1.4738x; 1.2775x over previous
//
#include <hip/hip_runtime.h>

#define N_NODES 50000
#define N_EDGES 400000
#define F_IN    128
#define F_EDGE  32
#define F       32
#define H       4
#define NHF     128   // H*F

#define SCAN_BLK 512
#define N_SCAN_BLKS ((N_NODES + SCAN_BLK - 1) / SCAN_BLK)   // 98

// ---- atom_in = relu(x @ atom_w + atom_b); 32 nodes/block, x tile in LDS ----
__global__ __launch_bounds__(256) void k_atom(const float* __restrict__ x,
                                              const float* __restrict__ w,
                                              const float* __restrict__ b,
                                              float* __restrict__ out) {
    __shared__ float wlds[F_IN * NHF];              // 64 KB
    __shared__ float xl[32 * F_IN];                 // 16 KB
    const float4* w4 = (const float4*)w;
    float4* wl4 = (float4*)wlds;
    for (int i = threadIdx.x; i < F_IN * NHF / 4; i += 256) wl4[i] = w4[i];
    int nb = blockIdx.x * 32;
    int nrows = min(32, N_NODES - nb);
    const float4* x4 = (const float4*)(x + (size_t)nb * F_IN);
    float4* xl4 = (float4*)xl;
    for (int i = threadIdx.x; i < nrows * F_IN / 4; i += 256) xl4[i] = x4[i];
    __syncthreads();
    int jg = threadIdx.x & 31;                      // output col group (4 cols)
    int nl = threadIdx.x >> 5;                      // 0..7
    float4 bv = *(const float4*)(b + jg * 4);
    float4 acc[4] = {bv, bv, bv, bv};
    for (int k = 0; k < F_IN; k++) {
        float4 wv = *(const float4*)(wlds + k * NHF + jg * 4);
#pragma unroll
        for (int q = 0; q < 4; q++) {
            float xk = xl[(nl + 8 * q) * F_IN + k];
            acc[q].x += xk * wv.x; acc[q].y += xk * wv.y;
            acc[q].z += xk * wv.z; acc[q].w += xk * wv.w;
        }
    }
#pragma unroll
    for (int q = 0; q < 4; q++) {
        int n = nb + nl + 8 * q;
        if (n < N_NODES) {
            float4 a = acc[q];
            a.x = fmaxf(a.x, 0.f); a.y = fmaxf(a.y, 0.f);
            a.z = fmaxf(a.z, 0.f); a.w = fmaxf(a.w, 0.f);
            *(float4*)(out + (size_t)n * NHF + jg * 4) = a;
        }
    }
}

// ---- CSR build: histogram / scan / fill ----
__global__ __launch_bounds__(256) void k_hist(const int* __restrict__ dst,
                                              int* __restrict__ counts) {
    int e = blockIdx.x * 256 + threadIdx.x;
    if (e < N_EDGES) atomicAdd(counts + dst[e], 1);
}

__global__ __launch_bounds__(SCAN_BLK) void k_scan1(const int* __restrict__ counts,
        int* __restrict__ excl, int* __restrict__ bsum) {
    __shared__ int s[SCAN_BLK];
    int i = blockIdx.x * SCAN_BLK + threadIdx.x;
    int v = (i < N_NODES) ? counts[i] : 0;
    s[threadIdx.x] = v;
    __syncthreads();
    for (int d = 1; d < SCAN_BLK; d <<= 1) {
        int t = (threadIdx.x >= d) ? s[threadIdx.x - d] : 0;
        __syncthreads();
        s[threadIdx.x] += t;
        __syncthreads();
    }
    if (i < N_NODES) excl[i] = s[threadIdx.x] - v;   // exclusive within block
    if (threadIdx.x == SCAN_BLK - 1) bsum[blockIdx.x] = s[SCAN_BLK - 1];
}

__global__ __launch_bounds__(128) void k_scan2(int* __restrict__ bsum) {
    __shared__ int s[128];
    int v = (threadIdx.x < N_SCAN_BLKS) ? bsum[threadIdx.x] : 0;
    s[threadIdx.x] = v;
    __syncthreads();
    for (int d = 1; d < 128; d <<= 1) {
        int t = (threadIdx.x >= d) ? s[threadIdx.x - d] : 0;
        __syncthreads();
        s[threadIdx.x] += t;
        __syncthreads();
    }
    if (threadIdx.x < N_SCAN_BLKS) bsum[threadIdx.x] = s[threadIdx.x] - v;
}

__global__ __launch_bounds__(SCAN_BLK) void k_scan3(const int* __restrict__ excl,
        const int* __restrict__ bsum, int* __restrict__ row_start,
        int* __restrict__ cursor) {
    int i = blockIdx.x * SCAN_BLK + threadIdx.x;
    if (i < N_NODES) {
        int v = excl[i] + bsum[blockIdx.x];
        row_start[i] = v;
        cursor[i] = v;
    }
}

__global__ __launch_bounds__(256) void k_fill(const int* __restrict__ dst,
        int* __restrict__ cursor, int* __restrict__ csr_e) {
    int e = blockIdx.x * 256 + threadIdx.x;
    if (e < N_EDGES) {
        int pos = atomicAdd(cursor + dst[e], 1);
        csr_e[pos] = e;
    }
}

// ---- xs,xd,xm = h @ {Ws,Wd,Wm} + b; 64 rows/block, input tile transposed
// in LDS (conflict-free broadcast reads), 4 threads/row x 8 cols ----
__global__ __launch_bounds__(256) void k_nodelin3(const float* __restrict__ h,
        const float* __restrict__ ws, const float* __restrict__ bs,
        const float* __restrict__ wd, const float* __restrict__ bd,
        const float* __restrict__ wm, const float* __restrict__ bm,
        float* __restrict__ xs, float* __restrict__ xd, float* __restrict__ xm) {
    __shared__ float Ws[F * F], Wd[F * F], Wm[F * F];   // 12 KB
    __shared__ float hrt[F][64];                         // 8 KB, [k][row_local]
    for (int i = threadIdx.x; i < F * F; i += 256) {
        Ws[i] = ws[i]; Wd[i] = wd[i]; Wm[i] = wm[i];
    }
    int rbase = blockIdx.x * 64;                         // row in (N*H, F) view
    for (int i = threadIdx.x; i < 512; i += 256) {       // 64 rows * 8 float4
        int row = i >> 3, kq = i & 7;                    // coalesced 1KB/wave
        float4 v = *(const float4*)(h + (size_t)(rbase + row) * F + kq * 4);
        hrt[kq * 4 + 0][row] = v.x; hrt[kq * 4 + 1][row] = v.y;
        hrt[kq * 4 + 2][row] = v.z; hrt[kq * 4 + 3][row] = v.w;
    }
    __syncthreads();
    int rl = threadIdx.x >> 2;                           // 0..63
    int jg = threadIdx.x & 3;                            // 8-col group
    float4 s0 = *(const float4*)(bs + jg * 8), s1 = *(const float4*)(bs + jg * 8 + 4);
    float4 d0 = *(const float4*)(bd + jg * 8), d1 = *(const float4*)(bd + jg * 8 + 4);
    float4 m0 = *(const float4*)(bm + jg * 8), m1 = *(const float4*)(bm + jg * 8 + 4);
    for (int k = 0; k < F; k++) {
        float hv = hrt[k][rl];
        float4 a, b2;
        a = *(const float4*)(Ws + k * F + jg * 8); b2 = *(const float4*)(Ws + k * F + jg * 8 + 4);
        s0.x += hv * a.x; s0.y += hv * a.y; s0.z += hv * a.z; s0.w += hv * a.w;
        s1.x += hv * b2.x; s1.y += hv * b2.y; s1.z += hv * b2.z; s1.w += hv * b2.w;
        a = *(const float4*)(Wd + k * F + jg * 8); b2 = *(const float4*)(Wd + k * F + jg * 8 + 4);
        d0.x += hv * a.x; d0.y += hv * a.y; d0.z += hv * a.z; d0.w += hv * a.w;
        d1.x += hv * b2.x; d1.y += hv * b2.y; d1.z += hv * b2.z; d1.w += hv * b2.w;
        a = *(const float4*)(Wm + k * F + jg * 8); b2 = *(const float4*)(Wm + k * F + jg * 8 + 4);
        m0.x += hv * a.x; m0.y += hv * a.y; m0.z += hv * a.z; m0.w += hv * a.w;
        m1.x += hv * b2.x; m1.y += hv * b2.y; m1.z += hv * b2.z; m1.w += hv * b2.w;
    }
    size_t o = (size_t)(rbase + rl) * F + jg * 8;
    *(float4*)(xs + o) = s0; *(float4*)(xs + o + 4) = s1;
    *(float4*)(xd + o) = d0; *(float4*)(xd + o + 4) = d1;
    *(float4*)(xm + o) = m0; *(float4*)(xm + o + 4) = m1;
}

// ---- out = edge_attr @ W + b; 64 edges/block, transposed LDS tile ----
__global__ __launch_bounds__(256) void k_edgelin(const float* __restrict__ ein,
        const float* __restrict__ w, const float* __restrict__ b,
        float* __restrict__ out) {
    __shared__ float W[F_EDGE * F];                      // 4 KB
    __shared__ float ert[F_EDGE][64];                    // 8 KB
    for (int i = threadIdx.x; i < F_EDGE * F; i += 256) W[i] = w[i];
    int ebase = blockIdx.x * 64;
    for (int i = threadIdx.x; i < 512; i += 256) {
        int row = i >> 3, kq = i & 7;
        float4 v = *(const float4*)(ein + (size_t)(ebase + row) * F_EDGE + kq * 4);
        ert[kq * 4 + 0][row] = v.x; ert[kq * 4 + 1][row] = v.y;
        ert[kq * 4 + 2][row] = v.z; ert[kq * 4 + 3][row] = v.w;
    }
    __syncthreads();
    int el = threadIdx.x >> 2;                           // 0..63
    int jg = threadIdx.x & 3;                            // 8-col group
    float4 a0 = *(const float4*)(b + jg * 8);
    float4 a1 = *(const float4*)(b + jg * 8 + 4);
    for (int k = 0; k < F_EDGE; k++) {
        float ev = ert[k][el];
        float4 w0 = *(const float4*)(W + k * F + jg * 8);
        float4 w1 = *(const float4*)(W + k * F + jg * 8 + 4);
        a0.x += ev * w0.x; a0.y += ev * w0.y; a0.z += ev * w0.z; a0.w += ev * w0.w;
        a1.x += ev * w1.x; a1.y += ev * w1.y; a1.z += ev * w1.z; a1.w += ev * w1.w;
    }
    size_t o = (size_t)(ebase + el) * F + jg * 8;
    *(float4*)(out + o) = a0;
    *(float4*)(out + o + 4) = a1;
}

// ---- raw logits: relu(xs[dst]+xd[src]+ea) . dw + db ----
__global__ __launch_bounds__(256) void k_logits(const float* __restrict__ xs,
        const float* __restrict__ xd, const float* __restrict__ ea,
        const int* __restrict__ src, const int* __restrict__ dst,
        const float* __restrict__ dw, const float* __restrict__ db,
        float* __restrict__ logits) {
    int t = blockIdx.x * 256 + threadIdx.x;         // t = e*4 + h
    int e = t >> 2, hh = t & 3;
    int d = dst[e], s = src[e];
    const float4* a4 = (const float4*)(xs + (size_t)d * NHF + hh * F);
    const float4* b4 = (const float4*)(xd + (size_t)s * NHF + hh * F);
    const float4* c4 = (const float4*)(ea + (size_t)e * F);
    const float4* w4 = (const float4*)dw;
    float acc = 0.f;
#pragma unroll
    for (int q = 0; q < 8; q++) {
        float4 av = a4[q], bv = b4[q], cv = c4[q], wv = w4[q];
        acc += fmaxf(av.x + bv.x + cv.x, 0.f) * wv.x;
        acc += fmaxf(av.y + bv.y + cv.y, 0.f) * wv.y;
        acc += fmaxf(av.z + bv.z + cv.z, 0.f) * wv.z;
        acc += fmaxf(av.w + bv.w + cv.w, 0.f) * wv.w;
    }
    logits[t] = acc + db[0];
}

// ---- pull softmax per node (joint over heads), alpha written in place ----
__global__ __launch_bounds__(256) void k_softmax(const int* __restrict__ row_start,
        const int* __restrict__ counts, const int* __restrict__ csr_e,
        float* __restrict__ logits) {
    int n = blockIdx.x * 4 + (threadIdx.x >> 6);
    if (n >= N_NODES) return;
    int lane = threadIdx.x & 63;
    int start = row_start[n];
    int items = counts[n] * 4;
    float m = -1e30f;
    for (int i = lane; i < items; i += 64) {
        int e = csr_e[start + (i >> 2)];
        m = fmaxf(m, logits[e * 4 + (i & 3)]);
    }
#pragma unroll
    for (int d = 1; d < 64; d <<= 1) m = fmaxf(m, __shfl_xor(m, d));
    float ssum = 0.f;
    for (int i = lane; i < items; i += 64) {
        int e = csr_e[start + (i >> 2)];
        ssum += __expf(logits[e * 4 + (i & 3)] - m);
    }
#pragma unroll
    for (int d = 1; d < 64; d <<= 1) ssum += __shfl_xor(ssum, d);
    float inv = 1.f / (ssum + 1e-8f);
    for (int i = lane; i < items; i += 64) {
        int e = csr_e[start + (i >> 2)];
        int idx = e * 4 + (i & 3);
        logits[idx] = __expf(logits[idx] - m) * inv;
    }
}

// ---- pull aggregation: no atomics, one 128B store per (N*H,F) flat row ----
__global__ __launch_bounds__(256) void k_msg_pull(const int* __restrict__ row_start,
        const int* __restrict__ counts, const int* __restrict__ csr_e,
        const float* __restrict__ xm, const float* __restrict__ em,
        const float* __restrict__ alpha, const int* __restrict__ dst,
        float* __restrict__ aggr) {
    int m = blockIdx.x * 8 + (threadIdx.x >> 5);
    if (m >= N_NODES) return;
    int f = threadIdx.x & 31;
    int start = row_start[m];
    int deg = counts[m];
    float acc = 0.f;
    for (int ii = 0; ii < deg; ii++) {
        int r = csr_e[start + ii];
#pragma unroll
        for (int j = 0; j < 4; j++) {
            int k = r + j * N_EDGES;
            int e = k >> 2, hh = k & 3;
            int de = dst[e];
            float a = alpha[k];
            acc += a * (xm[(size_t)de * NHF + hh * F + f] + em[(size_t)e * F + f]);
        }
    }
    aggr[(size_t)m * F + f] = acc;
}

// ---- h_out = relu(aggr + h@Wn + bn + atom_in); final: mean over heads ----
__global__ __launch_bounds__(128) void k_combine(const float* __restrict__ h,
        const float* __restrict__ aggr, const float* __restrict__ atom_in,
        const float* __restrict__ wn, const float* __restrict__ bn,
        float* __restrict__ hout, float* __restrict__ final_out, int is_final) {
    __shared__ float W[F * F];
    __shared__ float sm[NHF];
    for (int i = threadIdx.x; i < F * F; i += 128) W[i] = wn[i];
    __syncthreads();
    int n = blockIdx.x;
    int head = threadIdx.x >> 5, j = threadIdx.x & 31;
    const float* hr = h + (size_t)n * NHF + head * F;
    float acc = bn[j];
    for (int k = 0; k < F; k++) acc += hr[k] * W[k * F + j];
    int flat = n * H + head;                        // row of (N*H,F) view
    float ag = (flat < N_NODES) ? aggr[(size_t)flat * F + j] : 0.f;
    size_t idx = (size_t)n * NHF + head * F + j;
    float v = ag + acc + atom_in[idx];
    v = fmaxf(v, 0.f);
    if (!is_final) {
        hout[idx] = v;
    } else {
        sm[threadIdx.x] = v;
        __syncthreads();
        if (threadIdx.x < F) {
            float o = 0.25f * (sm[threadIdx.x] + sm[F + threadIdx.x] +
                               sm[2 * F + threadIdx.x] + sm[3 * F + threadIdx.x]);
            final_out[(size_t)n * F + threadIdx.x] = o;
        }
    }
}

extern "C" void kernel_launch(void* const* d_in, const int* in_sizes, int n_in,
                              void* d_out, int out_size, void* d_ws, size_t ws_size,
                              hipStream_t stream) {
    const float* x         = (const float*)d_in[0];
    const float* edge_attr = (const float*)d_in[1];
    const int*   eidx      = (const int*)d_in[2];
    const int*   src       = eidx;
    const int*   dst       = eidx + N_EDGES;
    const float* atom_w    = (const float*)d_in[3];
    const float* atom_b    = (const float*)d_in[4];
    const float* asw = (const float*)d_in[5],  *asb = (const float*)d_in[6];
    const float* adw = (const float*)d_in[7],  *adb = (const float*)d_in[8];
    const float* aew = (const float*)d_in[9],  *aeb = (const float*)d_in[10];
    const float* dww = (const float*)d_in[11], *dwb = (const float*)d_in[12];
    const float* mdw = (const float*)d_in[13], *mdb = (const float*)d_in[14];
    const float* mew = (const float*)d_in[15], *meb = (const float*)d_in[16];
    const float* wnw = (const float*)d_in[17], *wnb = (const float*)d_in[18];
    float* out = (float*)d_out;

    // workspace layout (floats); em aliases xs+xd (dead after k_logits)
    float* ws = (float*)d_ws;
    size_t off = 0;
    float* atom_in = ws + off; off += (size_t)N_NODES * NHF;
    float* hbuf    = ws + off; off += (size_t)N_NODES * NHF;
    float* xs      = ws + off; off += (size_t)N_NODES * NHF;
    float* xd      = ws + off; off += (size_t)N_NODES * NHF;
    float* xm      = ws + off; off += (size_t)N_NODES * NHF;
    float* ea      = ws + off; off += (size_t)N_EDGES * F;
    float* logits  = ws + off; off += (size_t)N_EDGES * H;
    float* aggr    = ws + off; off += (size_t)N_NODES * F;
    int* counts    = (int*)(ws + off); off += N_NODES;
    int* row_start = (int*)(ws + off); off += N_NODES;
    int* cursor    = (int*)(ws + off); off += N_NODES;
    int* excl      = (int*)(ws + off); off += N_NODES;
    int* bsum      = (int*)(ws + off); off += 128;
    int* csr_e     = (int*)(ws + off); off += N_EDGES;
    float* em      = xs;  // E*F == 2 * N*NHF exactly

    // ---- CSR build (dst is layer-invariant; once per call) ----
    hipMemsetAsync(counts, 0, N_NODES * sizeof(int), stream);
    k_hist <<<(N_EDGES + 255) / 256, 256, 0, stream>>>(dst, counts);
    k_scan1<<<N_SCAN_BLKS, SCAN_BLK, 0, stream>>>(counts, excl, bsum);
    k_scan2<<<1, 128, 0, stream>>>(bsum);
    k_scan3<<<N_SCAN_BLKS, SCAN_BLK, 0, stream>>>(excl, bsum, row_start, cursor);
    k_fill <<<(N_EDGES + 255) / 256, 256, 0, stream>>>(dst, cursor, csr_e);

    k_atom<<<(N_NODES + 31) / 32, 256, 0, stream>>>(x, atom_w, atom_b, atom_in);

    for (int l = 0; l < 2; l++) {
        const float* hin  = (l == 0) ? atom_in : hbuf;
        float*       hout = hbuf;
        int is_final = (l == 1);
        k_nodelin3<<<(N_NODES * H) / 64, 256, 0, stream>>>(
            hin, asw + l * F * F, asb + l * F, adw + l * F * F, adb + l * F,
            mdw + l * F * F, mdb + l * F, xs, xd, xm);
        k_edgelin<<<N_EDGES / 64, 256, 0, stream>>>(edge_attr, aew + l * F_EDGE * F,
                                                    aeb + l * F, ea);
        k_logits<<<(N_EDGES * H) / 256, 256, 0, stream>>>(
            xs, xd, ea, src, dst, dww + l * F, dwb + l, logits);
        k_edgelin<<<N_EDGES / 64, 256, 0, stream>>>(edge_attr, mew + l * F_EDGE * F,
                                                    meb + l * F, em);
        k_softmax<<<(N_NODES + 3) / 4, 256, 0, stream>>>(row_start, counts, csr_e,
                                                         logits);
        k_msg_pull<<<(N_NODES + 7) / 8, 256, 0, stream>>>(row_start, counts, csr_e,
                                                          xm, em, logits, dst, aggr);
        k_combine<<<N_NODES, 128, 0, stream>>>(hin, aggr, atom_in,
                                               wnw + l * F * F, wnb + l * F,
                                               hout, out, is_final);
    }
}

// Round 4
// 816.290 us; speedup vs baseline: 1.6333x; 1.1082x over previous
//
#include <hip/hip_runtime.h>

#define N_NODES 50000
#define N_EDGES 400000
#define EQ      100000   // N_EDGES/4
#define F_IN    128
#define F_EDGE  32
#define F       32
#define H       4
#define NHF     128   // H*F

#define SCAN_BLK 512
#define N_SCAN_BLKS ((N_NODES + SCAN_BLK - 1) / SCAN_BLK)   // 98

// ---- atom_in = relu(x @ atom_w + atom_b); 32 nodes/block ----
__global__ __launch_bounds__(256) void k_atom(const float* __restrict__ x,
                                              const float* __restrict__ w,
                                              const float* __restrict__ b,
                                              float* __restrict__ out) {
    __shared__ float wlds[F_IN * NHF];              // 64 KB
    __shared__ float xl[32 * F_IN];                 // 16 KB
    const float4* w4 = (const float4*)w;
    float4* wl4 = (float4*)wlds;
    for (int i = threadIdx.x; i < F_IN * NHF / 4; i += 256) wl4[i] = w4[i];
    int nb = blockIdx.x * 32;
    int nrows = min(32, N_NODES - nb);
    const float4* x4 = (const float4*)(x + (size_t)nb * F_IN);
    float4* xl4 = (float4*)xl;
    for (int i = threadIdx.x; i < nrows * F_IN / 4; i += 256) xl4[i] = x4[i];
    __syncthreads();
    int jg = threadIdx.x & 31;
    int nl = threadIdx.x >> 5;
    float4 bv = *(const float4*)(b + jg * 4);
    float4 acc[4] = {bv, bv, bv, bv};
    for (int k = 0; k < F_IN; k++) {
        float4 wv = *(const float4*)(wlds + k * NHF + jg * 4);
#pragma unroll
        for (int q = 0; q < 4; q++) {
            float xk = xl[(nl + 8 * q) * F_IN + k];
            acc[q].x += xk * wv.x; acc[q].y += xk * wv.y;
            acc[q].z += xk * wv.z; acc[q].w += xk * wv.w;
        }
    }
#pragma unroll
    for (int q = 0; q < 4; q++) {
        int n = nb + nl + 8 * q;
        if (n < N_NODES) {
            float4 a = acc[q];
            a.x = fmaxf(a.x, 0.f); a.y = fmaxf(a.y, 0.f);
            a.z = fmaxf(a.z, 0.f); a.w = fmaxf(a.w, 0.f);
            *(float4*)(out + (size_t)n * NHF + jg * 4) = a;
        }
    }
}

// ---- CSR build ----
__global__ __launch_bounds__(256) void k_hist(const int* __restrict__ dst,
                                              int* __restrict__ counts) {
    int e = blockIdx.x * 256 + threadIdx.x;
    if (e < N_EDGES) atomicAdd(counts + dst[e], 1);
}

__global__ __launch_bounds__(SCAN_BLK) void k_scan1(const int* __restrict__ counts,
        int* __restrict__ excl, int* __restrict__ bsum) {
    __shared__ int s[SCAN_BLK];
    int i = blockIdx.x * SCAN_BLK + threadIdx.x;
    int v = (i < N_NODES) ? counts[i] : 0;
    s[threadIdx.x] = v;
    __syncthreads();
    for (int d = 1; d < SCAN_BLK; d <<= 1) {
        int t = (threadIdx.x >= d) ? s[threadIdx.x - d] : 0;
        __syncthreads();
        s[threadIdx.x] += t;
        __syncthreads();
    }
    if (i < N_NODES) excl[i] = s[threadIdx.x] - v;
    if (threadIdx.x == SCAN_BLK - 1) bsum[blockIdx.x] = s[SCAN_BLK - 1];
}

__global__ __launch_bounds__(128) void k_scan2(int* __restrict__ bsum) {
    __shared__ int s[128];
    int v = (threadIdx.x < N_SCAN_BLKS) ? bsum[threadIdx.x] : 0;
    s[threadIdx.x] = v;
    __syncthreads();
    for (int d = 1; d < 128; d <<= 1) {
        int t = (threadIdx.x >= d) ? s[threadIdx.x - d] : 0;
        __syncthreads();
        s[threadIdx.x] += t;
        __syncthreads();
    }
    if (threadIdx.x < N_SCAN_BLKS) bsum[threadIdx.x] = s[threadIdx.x] - v;
}

__global__ __launch_bounds__(SCAN_BLK) void k_scan3(const int* __restrict__ excl,
        const int* __restrict__ bsum, int* __restrict__ row_start,
        int* __restrict__ cursor) {
    int i = blockIdx.x * SCAN_BLK + threadIdx.x;
    if (i < N_NODES) {
        int v = excl[i] + bsum[blockIdx.x];
        row_start[i] = v;
        cursor[i] = v;
    }
}

__global__ __launch_bounds__(256) void k_fill(const int* __restrict__ dst,
        int* __restrict__ cursor, int* __restrict__ csr_e) {
    int e = blockIdx.x * 256 + threadIdx.x;
    if (e < N_EDGES) {
        int pos = atomicAdd(cursor + dst[e], 1);
        csr_e[pos] = e;
    }
}

// ---- xs,xd,xm = h @ {Ws,Wd,Wm} + b; 64 rows/block, transposed LDS tile ----
__global__ __launch_bounds__(256) void k_nodelin3(const float* __restrict__ h,
        const float* __restrict__ ws, const float* __restrict__ bs,
        const float* __restrict__ wd, const float* __restrict__ bd,
        const float* __restrict__ wm, const float* __restrict__ bm,
        float* __restrict__ xs, float* __restrict__ xd, float* __restrict__ xm) {
    __shared__ float Ws[F * F], Wd[F * F], Wm[F * F];
    __shared__ float hrt[F][64];
    for (int i = threadIdx.x; i < F * F; i += 256) {
        Ws[i] = ws[i]; Wd[i] = wd[i]; Wm[i] = wm[i];
    }
    int rbase = blockIdx.x * 64;
    for (int i = threadIdx.x; i < 512; i += 256) {
        int row = i >> 3, kq = i & 7;
        float4 v = *(const float4*)(h + (size_t)(rbase + row) * F + kq * 4);
        hrt[kq * 4 + 0][row] = v.x; hrt[kq * 4 + 1][row] = v.y;
        hrt[kq * 4 + 2][row] = v.z; hrt[kq * 4 + 3][row] = v.w;
    }
    __syncthreads();
    int rl = threadIdx.x >> 2;
    int jg = threadIdx.x & 3;
    float4 s0 = *(const float4*)(bs + jg * 8), s1 = *(const float4*)(bs + jg * 8 + 4);
    float4 d0 = *(const float4*)(bd + jg * 8), d1 = *(const float4*)(bd + jg * 8 + 4);
    float4 m0 = *(const float4*)(bm + jg * 8), m1 = *(const float4*)(bm + jg * 8 + 4);
    for (int k = 0; k < F; k++) {
        float hv = hrt[k][rl];
        float4 a, b2;
        a = *(const float4*)(Ws + k * F + jg * 8); b2 = *(const float4*)(Ws + k * F + jg * 8 + 4);
        s0.x += hv * a.x; s0.y += hv * a.y; s0.z += hv * a.z; s0.w += hv * a.w;
        s1.x += hv * b2.x; s1.y += hv * b2.y; s1.z += hv * b2.z; s1.w += hv * b2.w;
        a = *(const float4*)(Wd + k * F + jg * 8); b2 = *(const float4*)(Wd + k * F + jg * 8 + 4);
        d0.x += hv * a.x; d0.y += hv * a.y; d0.z += hv * a.z; d0.w += hv * a.w;
        d1.x += hv * b2.x; d1.y += hv * b2.y; d1.z += hv * b2.z; d1.w += hv * b2.w;
        a = *(const float4*)(Wm + k * F + jg * 8); b2 = *(const float4*)(Wm + k * F + jg * 8 + 4);
        m0.x += hv * a.x; m0.y += hv * a.y; m0.z += hv * a.z; m0.w += hv * a.w;
        m1.x += hv * b2.x; m1.y += hv * b2.y; m1.z += hv * b2.z; m1.w += hv * b2.w;
    }
    size_t o = (size_t)(rbase + rl) * F + jg * 8;
    *(float4*)(xs + o) = s0; *(float4*)(xs + o + 4) = s1;
    *(float4*)(xd + o) = d0; *(float4*)(xd + o + 4) = d1;
    *(float4*)(xm + o) = m0; *(float4*)(xm + o + 4) = m1;
}

// ---- out = edge_attr @ W + b (used for em only now) ----
__global__ __launch_bounds__(256) void k_edgelin(const float* __restrict__ ein,
        const float* __restrict__ w, const float* __restrict__ b,
        float* __restrict__ out) {
    __shared__ float W[F_EDGE * F];
    __shared__ float ert[F_EDGE][64];
    for (int i = threadIdx.x; i < F_EDGE * F; i += 256) W[i] = w[i];
    int ebase = blockIdx.x * 64;
    for (int i = threadIdx.x; i < 512; i += 256) {
        int row = i >> 3, kq = i & 7;
        float4 v = *(const float4*)(ein + (size_t)(ebase + row) * F_EDGE + kq * 4);
        ert[kq * 4 + 0][row] = v.x; ert[kq * 4 + 1][row] = v.y;
        ert[kq * 4 + 2][row] = v.z; ert[kq * 4 + 3][row] = v.w;
    }
    __syncthreads();
    int el = threadIdx.x >> 2;
    int jg = threadIdx.x & 3;
    float4 a0 = *(const float4*)(b + jg * 8);
    float4 a1 = *(const float4*)(b + jg * 8 + 4);
    for (int k = 0; k < F_EDGE; k++) {
        float ev = ert[k][el];
        float4 w0 = *(const float4*)(W + k * F + jg * 8);
        float4 w1 = *(const float4*)(W + k * F + jg * 8 + 4);
        a0.x += ev * w0.x; a0.y += ev * w0.y; a0.z += ev * w0.z; a0.w += ev * w0.w;
        a1.x += ev * w1.x; a1.y += ev * w1.y; a1.z += ev * w1.z; a1.w += ev * w1.w;
    }
    size_t o = (size_t)(ebase + el) * F + jg * 8;
    *(float4*)(out + o) = a0;
    *(float4*)(out + o + 4) = a1;
}

// ---- fused: ea = edge_attr@aew+aeb (LDS tile), then
// logits[e*4+h] = relu(xs[dst]+xd[src]+ea).dw + db ----
__global__ __launch_bounds__(256) void k_logits(const float* __restrict__ edge_attr,
        const float* __restrict__ aew, const float* __restrict__ aeb,
        const float* __restrict__ xs, const float* __restrict__ xd,
        const int* __restrict__ src, const int* __restrict__ dst,
        const float* __restrict__ dw, const float* __restrict__ db,
        float* __restrict__ logits) {
    __shared__ float W[F_EDGE * F];                  // 4 KB
    __shared__ float ert[F_EDGE][64];                // 8 KB
    __shared__ float ea_t[64][F + 4];                // 9 KB, +4 pad kills 16-way conflict
    for (int i = threadIdx.x; i < F_EDGE * F; i += 256) W[i] = aew[i];
    int ebase = blockIdx.x * 64;
    for (int i = threadIdx.x; i < 512; i += 256) {
        int row = i >> 3, kq = i & 7;
        float4 v = *(const float4*)(edge_attr + (size_t)(ebase + row) * F_EDGE + kq * 4);
        ert[kq * 4 + 0][row] = v.x; ert[kq * 4 + 1][row] = v.y;
        ert[kq * 4 + 2][row] = v.z; ert[kq * 4 + 3][row] = v.w;
    }
    __syncthreads();
    {
        int el = threadIdx.x >> 2, jg = threadIdx.x & 3;
        float4 a0 = *(const float4*)(aeb + jg * 8);
        float4 a1 = *(const float4*)(aeb + jg * 8 + 4);
        for (int k = 0; k < F_EDGE; k++) {
            float ev = ert[k][el];
            float4 w0 = *(const float4*)(W + k * F + jg * 8);
            float4 w1 = *(const float4*)(W + k * F + jg * 8 + 4);
            a0.x += ev * w0.x; a0.y += ev * w0.y; a0.z += ev * w0.z; a0.w += ev * w0.w;
            a1.x += ev * w1.x; a1.y += ev * w1.y; a1.z += ev * w1.z; a1.w += ev * w1.w;
        }
        *(float4*)(&ea_t[el][jg * 8]) = a0;
        *(float4*)(&ea_t[el][jg * 8 + 4]) = a1;
    }
    __syncthreads();
    int el = threadIdx.x >> 2, hh = threadIdx.x & 3;
    int e = ebase + el;
    int d = dst[e], s = src[e];
    const float4* a4 = (const float4*)(xs + (size_t)d * NHF + hh * F);
    const float4* b4 = (const float4*)(xd + (size_t)s * NHF + hh * F);
    const float4* w4 = (const float4*)dw;
    float acc = 0.f;
#pragma unroll
    for (int q = 0; q < 8; q++) {
        float4 av = a4[q], bv = b4[q], wv = w4[q];
        float4 cv = *(const float4*)(&ea_t[el][q * 4]);
        acc += fmaxf(av.x + bv.x + cv.x, 0.f) * wv.x;
        acc += fmaxf(av.y + bv.y + cv.y, 0.f) * wv.y;
        acc += fmaxf(av.z + bv.z + cv.z, 0.f) * wv.z;
        acc += fmaxf(av.w + bv.w + cv.w, 0.f) * wv.w;
    }
    logits[e * 4 + hh] = acc + db[0];
}

// ---- per-node max & inv-sum only (no per-edge write) ----
__global__ __launch_bounds__(256) void k_softmax(const int* __restrict__ row_start,
        const int* __restrict__ counts, const int* __restrict__ csr_e,
        const float* __restrict__ logits, float* __restrict__ nmax,
        float* __restrict__ ninv) {
    int n = blockIdx.x * 4 + (threadIdx.x >> 6);
    if (n >= N_NODES) return;
    int lane = threadIdx.x & 63;
    int start = row_start[n];
    int items = counts[n] * 4;
    float m = -1e30f;
    for (int i = lane; i < items; i += 64) {
        int e = csr_e[start + (i >> 2)];
        m = fmaxf(m, logits[e * 4 + (i & 3)]);
    }
#pragma unroll
    for (int d = 1; d < 64; d <<= 1) m = fmaxf(m, __shfl_xor(m, d));
    float ssum = 0.f;
    for (int i = lane; i < items; i += 64) {
        int e = csr_e[start + (i >> 2)];
        ssum += __expf(logits[e * 4 + (i & 3)] - m);
    }
#pragma unroll
    for (int d = 1; d < 64; d <<= 1) ssum += __shfl_xor(ssum, d);
    if (lane == 0) {
        nmax[n] = m;
        ninv[n] = 1.f / (ssum + 1e-8f);
    }
}

// ---- alphaT[r*4+j] = normalized alpha for message k=r+jE ----
__global__ __launch_bounds__(256) void k_alphat(const float* __restrict__ raw,
        const int* __restrict__ dst, const float* __restrict__ nmax,
        const float* __restrict__ ninv, float* __restrict__ alphaT) {
    int t = blockIdx.x * 256 + threadIdx.x;
    if (t >= N_EDGES) return;
    float o[4];
#pragma unroll
    for (int j = 0; j < 4; j++) {
        int k = t + j * N_EDGES;
        int e = k >> 2;                              // = (t>>2) + j*EQ
        int n = dst[e];
        o[j] = __expf(raw[k] - nmax[n]) * ninv[n];
    }
    *(float4*)(alphaT + (size_t)t * 4) = make_float4(o[0], o[1], o[2], o[3]);
}

// ---- pull aggregation; alphaT float4 per residue; 2-entry unroll for ILP.
// message k=r+jE: hh=r&3 (E%4==0), e_j=(r>>2)+j*EQ ----
__global__ __launch_bounds__(256) void k_msg_pull(const int* __restrict__ row_start,
        const int* __restrict__ counts, const int* __restrict__ csr_e,
        const float* __restrict__ xm, const float* __restrict__ em,
        const float* __restrict__ alphaT, const int* __restrict__ dst,
        float* __restrict__ aggr) {
    int m = blockIdx.x * 8 + (threadIdx.x >> 5);
    if (m >= N_NODES) return;
    int f = threadIdx.x & 31;
    int start = row_start[m];
    int deg = counts[m];
    float acc0 = 0.f, acc1 = 0.f;
    int ii = 0;
    for (; ii + 2 <= deg; ii += 2) {
        int r0 = csr_e[start + ii], r1 = csr_e[start + ii + 1];
        int q0 = r0 >> 2, h0 = (r0 & 3) * F;
        int q1 = r1 >> 2, h1 = (r1 & 3) * F;
        float4 a0 = *(const float4*)(alphaT + (size_t)r0 * 4);
        float4 a1 = *(const float4*)(alphaT + (size_t)r1 * 4);
#pragma unroll
        for (int j = 0; j < 4; j++) {
            int e0 = q0 + j * EQ, e1 = q1 + j * EQ;
            int d0 = dst[e0], d1 = dst[e1];
            float w0 = (j == 0) ? a0.x : (j == 1) ? a0.y : (j == 2) ? a0.z : a0.w;
            float w1 = (j == 0) ? a1.x : (j == 1) ? a1.y : (j == 2) ? a1.z : a1.w;
            acc0 += w0 * (xm[(size_t)d0 * NHF + h0 + f] + em[(size_t)e0 * F + f]);
            acc1 += w1 * (xm[(size_t)d1 * NHF + h1 + f] + em[(size_t)e1 * F + f]);
        }
    }
    if (ii < deg) {
        int r0 = csr_e[start + ii];
        int q0 = r0 >> 2, h0 = (r0 & 3) * F;
        float4 a0 = *(const float4*)(alphaT + (size_t)r0 * 4);
#pragma unroll
        for (int j = 0; j < 4; j++) {
            int e0 = q0 + j * EQ;
            int d0 = dst[e0];
            float w0 = (j == 0) ? a0.x : (j == 1) ? a0.y : (j == 2) ? a0.z : a0.w;
            acc0 += w0 * (xm[(size_t)d0 * NHF + h0 + f] + em[(size_t)e0 * F + f]);
        }
    }
    aggr[(size_t)m * F + f] = acc0 + acc1;
}

// ---- h_out = relu(aggr + h@Wn + bn + atom_in); final: mean over heads ----
__global__ __launch_bounds__(128) void k_combine(const float* __restrict__ h,
        const float* __restrict__ aggr, const float* __restrict__ atom_in,
        const float* __restrict__ wn, const float* __restrict__ bn,
        float* __restrict__ hout, float* __restrict__ final_out, int is_final) {
    __shared__ float W[F * F];
    __shared__ float sm[NHF];
    for (int i = threadIdx.x; i < F * F; i += 128) W[i] = wn[i];
    __syncthreads();
    int n = blockIdx.x;
    int head = threadIdx.x >> 5, j = threadIdx.x & 31;
    const float* hr = h + (size_t)n * NHF + head * F;
    float acc = bn[j];
    for (int k = 0; k < F; k++) acc += hr[k] * W[k * F + j];
    int flat = n * H + head;
    float ag = (flat < N_NODES) ? aggr[(size_t)flat * F + j] : 0.f;
    size_t idx = (size_t)n * NHF + head * F + j;
    float v = ag + acc + atom_in[idx];
    v = fmaxf(v, 0.f);
    if (!is_final) {
        hout[idx] = v;
    } else {
        sm[threadIdx.x] = v;
        __syncthreads();
        if (threadIdx.x < F) {
            float o = 0.25f * (sm[threadIdx.x] + sm[F + threadIdx.x] +
                               sm[2 * F + threadIdx.x] + sm[3 * F + threadIdx.x]);
            final_out[(size_t)n * F + threadIdx.x] = o;
        }
    }
}

extern "C" void kernel_launch(void* const* d_in, const int* in_sizes, int n_in,
                              void* d_out, int out_size, void* d_ws, size_t ws_size,
                              hipStream_t stream) {
    const float* x         = (const float*)d_in[0];
    const float* edge_attr = (const float*)d_in[1];
    const int*   eidx      = (const int*)d_in[2];
    const int*   src       = eidx;
    const int*   dst       = eidx + N_EDGES;
    const float* atom_w    = (const float*)d_in[3];
    const float* atom_b    = (const float*)d_in[4];
    const float* asw = (const float*)d_in[5],  *asb = (const float*)d_in[6];
    const float* adw = (const float*)d_in[7],  *adb = (const float*)d_in[8];
    const float* aew = (const float*)d_in[9],  *aeb = (const float*)d_in[10];
    const float* dww = (const float*)d_in[11], *dwb = (const float*)d_in[12];
    const float* mdw = (const float*)d_in[13], *mdb = (const float*)d_in[14];
    const float* mew = (const float*)d_in[15], *meb = (const float*)d_in[16];
    const float* wnw = (const float*)d_in[17], *wnb = (const float*)d_in[18];
    float* out = (float*)d_out;

    float* ws = (float*)d_ws;
    size_t off = 0;
    float* atom_in = ws + off; off += (size_t)N_NODES * NHF;
    float* hbuf    = ws + off; off += (size_t)N_NODES * NHF;
    float* xs      = ws + off; off += (size_t)N_NODES * NHF;
    float* xd      = ws + off; off += (size_t)N_NODES * NHF;
    float* xm      = ws + off; off += (size_t)N_NODES * NHF;
    float* logits  = ws + off; off += (size_t)N_EDGES * H;
    float* alphaT  = ws + off; off += (size_t)N_EDGES * H;
    float* aggr    = ws + off; off += (size_t)N_NODES * F;
    float* nmax    = ws + off; off += N_NODES;
    float* ninv    = ws + off; off += N_NODES;
    int* counts    = (int*)(ws + off); off += N_NODES;
    int* row_start = (int*)(ws + off); off += N_NODES;
    int* cursor    = (int*)(ws + off); off += N_NODES;
    int* excl      = (int*)(ws + off); off += N_NODES;
    int* bsum      = (int*)(ws + off); off += 128;
    int* csr_e     = (int*)(ws + off); off += N_EDGES;
    float* em      = xs;  // E*F == 2 * N*NHF exactly; xs dead after k_logits

    // ---- CSR build (dst is layer-invariant) ----
    hipMemsetAsync(counts, 0, N_NODES * sizeof(int), stream);
    k_hist <<<(N_EDGES + 255) / 256, 256, 0, stream>>>(dst, counts);
    k_scan1<<<N_SCAN_BLKS, SCAN_BLK, 0, stream>>>(counts, excl, bsum);
    k_scan2<<<1, 128, 0, stream>>>(bsum);
    k_scan3<<<N_SCAN_BLKS, SCAN_BLK, 0, stream>>>(excl, bsum, row_start, cursor);
    k_fill <<<(N_EDGES + 255) / 256, 256, 0, stream>>>(dst, cursor, csr_e);

    k_atom<<<(N_NODES + 31) / 32, 256, 0, stream>>>(x, atom_w, atom_b, atom_in);

    for (int l = 0; l < 2; l++) {
        const float* hin  = (l == 0) ? atom_in : hbuf;
        float*       hout = hbuf;
        int is_final = (l == 1);
        k_nodelin3<<<(N_NODES * H) / 64, 256, 0, stream>>>(
            hin, asw + l * F * F, asb + l * F, adw + l * F * F, adb + l * F,
            mdw + l * F * F, mdb + l * F, xs, xd, xm);
        k_logits<<<N_EDGES / 64, 256, 0, stream>>>(
            edge_attr, aew + l * F_EDGE * F, aeb + l * F,
            xs, xd, src, dst, dww + l * F, dwb + l, logits);
        k_edgelin<<<N_EDGES / 64, 256, 0, stream>>>(edge_attr, mew + l * F_EDGE * F,
                                                    meb + l * F, em);
        k_softmax<<<(N_NODES + 3) / 4, 256, 0, stream>>>(row_start, counts, csr_e,
                                                         logits, nmax, ninv);
        k_alphat<<<(N_EDGES + 255) / 256, 256, 0, stream>>>(logits, dst, nmax,
                                                            ninv, alphaT);
        k_msg_pull<<<(N_NODES + 7) / 8, 256, 0, stream>>>(row_start, counts, csr_e,
                                                          xm, em, alphaT, dst, aggr);
        k_combine<<<N_NODES, 128, 0, stream>>>(hin, aggr, atom_in,
                                               wnw + l * F * F, wnb + l * F,
                                               hout, out, is_final);
    }
}

// Round 5
// 709.419 us; speedup vs baseline: 1.8793x; 1.1506x over previous
//
#include <hip/hip_runtime.h>

#define N_NODES 50000
#define N_EDGES 400000
#define EQ      100000   // N_EDGES/4
#define F_IN    128
#define F_EDGE  32
#define F       32
#define H       4
#define NHF     128   // H*F

#define SCAN_BLK 512
#define N_SCAN_BLKS ((N_NODES + SCAN_BLK - 1) / SCAN_BLK)   // 98

// ---- bf16 helpers (RNE) ----
__device__ __forceinline__ float bf2f(unsigned short u) {
    return __uint_as_float(((unsigned)u) << 16);
}
__device__ __forceinline__ unsigned short f2bf(float f) {
    unsigned u = __float_as_uint(f);
    return (unsigned short)((u + 0x7FFFu + ((u >> 16) & 1u)) >> 16);
}
__device__ __forceinline__ ushort4 pack4(float4 v) {
    return make_ushort4(f2bf(v.x), f2bf(v.y), f2bf(v.z), f2bf(v.w));
}

// ---- atom_in = relu(x @ atom_w + atom_b); 32 nodes/block ----
__global__ __launch_bounds__(256) void k_atom(const float* __restrict__ x,
                                              const float* __restrict__ w,
                                              const float* __restrict__ b,
                                              float* __restrict__ out) {
    __shared__ float wlds[F_IN * NHF];              // 64 KB
    __shared__ float xl[32 * F_IN];                 // 16 KB
    const float4* w4 = (const float4*)w;
    float4* wl4 = (float4*)wlds;
    for (int i = threadIdx.x; i < F_IN * NHF / 4; i += 256) wl4[i] = w4[i];
    int nb = blockIdx.x * 32;
    int nrows = min(32, N_NODES - nb);
    const float4* x4 = (const float4*)(x + (size_t)nb * F_IN);
    float4* xl4 = (float4*)xl;
    for (int i = threadIdx.x; i < nrows * F_IN / 4; i += 256) xl4[i] = x4[i];
    __syncthreads();
    int jg = threadIdx.x & 31;
    int nl = threadIdx.x >> 5;
    float4 bv = *(const float4*)(b + jg * 4);
    float4 acc[4] = {bv, bv, bv, bv};
    for (int k = 0; k < F_IN; k++) {
        float4 wv = *(const float4*)(wlds + k * NHF + jg * 4);
#pragma unroll
        for (int q = 0; q < 4; q++) {
            float xk = xl[(nl + 8 * q) * F_IN + k];
            acc[q].x += xk * wv.x; acc[q].y += xk * wv.y;
            acc[q].z += xk * wv.z; acc[q].w += xk * wv.w;
        }
    }
#pragma unroll
    for (int q = 0; q < 4; q++) {
        int n = nb + nl + 8 * q;
        if (n < N_NODES) {
            float4 a = acc[q];
            a.x = fmaxf(a.x, 0.f); a.y = fmaxf(a.y, 0.f);
            a.z = fmaxf(a.z, 0.f); a.w = fmaxf(a.w, 0.f);
            *(float4*)(out + (size_t)n * NHF + jg * 4) = a;
        }
    }
}

// ---- CSR build ----
__global__ __launch_bounds__(256) void k_hist(const int* __restrict__ dst,
                                              int* __restrict__ counts) {
    int e = blockIdx.x * 256 + threadIdx.x;
    if (e < N_EDGES) atomicAdd(counts + dst[e], 1);
}

__global__ __launch_bounds__(SCAN_BLK) void k_scan1(const int* __restrict__ counts,
        int* __restrict__ excl, int* __restrict__ bsum) {
    __shared__ int s[SCAN_BLK];
    int i = blockIdx.x * SCAN_BLK + threadIdx.x;
    int v = (i < N_NODES) ? counts[i] : 0;
    s[threadIdx.x] = v;
    __syncthreads();
    for (int d = 1; d < SCAN_BLK; d <<= 1) {
        int t = (threadIdx.x >= d) ? s[threadIdx.x - d] : 0;
        __syncthreads();
        s[threadIdx.x] += t;
        __syncthreads();
    }
    if (i < N_NODES) excl[i] = s[threadIdx.x] - v;
    if (threadIdx.x == SCAN_BLK - 1) bsum[blockIdx.x] = s[SCAN_BLK - 1];
}

__global__ __launch_bounds__(128) void k_scan2(int* __restrict__ bsum) {
    __shared__ int s[128];
    int v = (threadIdx.x < N_SCAN_BLKS) ? bsum[threadIdx.x] : 0;
    s[threadIdx.x] = v;
    __syncthreads();
    for (int d = 1; d < 128; d <<= 1) {
        int t = (threadIdx.x >= d) ? s[threadIdx.x - d] : 0;
        __syncthreads();
        s[threadIdx.x] += t;
        __syncthreads();
    }
    if (threadIdx.x < N_SCAN_BLKS) bsum[threadIdx.x] = s[threadIdx.x] - v;
}

__global__ __launch_bounds__(SCAN_BLK) void k_scan3(const int* __restrict__ excl,
        const int* __restrict__ bsum, int* __restrict__ row_start,
        int* __restrict__ cursor) {
    int i = blockIdx.x * SCAN_BLK + threadIdx.x;
    if (i < N_NODES) {
        int v = excl[i] + bsum[blockIdx.x];
        row_start[i] = v;
        cursor[i] = v;
    }
}

__global__ __launch_bounds__(256) void k_fill(const int* __restrict__ src,
        const int* __restrict__ dst, int* __restrict__ cursor,
        int* __restrict__ csr_e, int* __restrict__ srcp,
        int* __restrict__ inv_pos) {
    int e = blockIdx.x * 256 + threadIdx.x;
    if (e < N_EDGES) {
        int pos = atomicAdd(cursor + dst[e], 1);
        csr_e[pos] = e;
        srcp[pos] = src[e];
        inv_pos[e] = pos;
    }
}

// ---- xs,xd,xm = h @ {Ws,Wd,Wm} + b -> bf16 outputs ----
__global__ __launch_bounds__(256) void k_nodelin3(const float* __restrict__ h,
        const float* __restrict__ ws, const float* __restrict__ bs,
        const float* __restrict__ wd, const float* __restrict__ bd,
        const float* __restrict__ wm, const float* __restrict__ bm,
        unsigned short* __restrict__ xs, unsigned short* __restrict__ xd,
        unsigned short* __restrict__ xm) {
    __shared__ float Ws[F * F], Wd[F * F], Wm[F * F];
    __shared__ float hrt[F][64];
    for (int i = threadIdx.x; i < F * F; i += 256) {
        Ws[i] = ws[i]; Wd[i] = wd[i]; Wm[i] = wm[i];
    }
    int rbase = blockIdx.x * 64;
    for (int i = threadIdx.x; i < 512; i += 256) {
        int row = i >> 3, kq = i & 7;
        float4 v = *(const float4*)(h + (size_t)(rbase + row) * F + kq * 4);
        hrt[kq * 4 + 0][row] = v.x; hrt[kq * 4 + 1][row] = v.y;
        hrt[kq * 4 + 2][row] = v.z; hrt[kq * 4 + 3][row] = v.w;
    }
    __syncthreads();
    int rl = threadIdx.x >> 2;
    int jg = threadIdx.x & 3;
    float4 s0 = *(const float4*)(bs + jg * 8), s1 = *(const float4*)(bs + jg * 8 + 4);
    float4 d0 = *(const float4*)(bd + jg * 8), d1 = *(const float4*)(bd + jg * 8 + 4);
    float4 m0 = *(const float4*)(bm + jg * 8), m1 = *(const float4*)(bm + jg * 8 + 4);
    for (int k = 0; k < F; k++) {
        float hv = hrt[k][rl];
        float4 a, b2;
        a = *(const float4*)(Ws + k * F + jg * 8); b2 = *(const float4*)(Ws + k * F + jg * 8 + 4);
        s0.x += hv * a.x; s0.y += hv * a.y; s0.z += hv * a.z; s0.w += hv * a.w;
        s1.x += hv * b2.x; s1.y += hv * b2.y; s1.z += hv * b2.z; s1.w += hv * b2.w;
        a = *(const float4*)(Wd + k * F + jg * 8); b2 = *(const float4*)(Wd + k * F + jg * 8 + 4);
        d0.x += hv * a.x; d0.y += hv * a.y; d0.z += hv * a.z; d0.w += hv * a.w;
        d1.x += hv * b2.x; d1.y += hv * b2.y; d1.z += hv * b2.z; d1.w += hv * b2.w;
        a = *(const float4*)(Wm + k * F + jg * 8); b2 = *(const float4*)(Wm + k * F + jg * 8 + 4);
        m0.x += hv * a.x; m0.y += hv * a.y; m0.z += hv * a.z; m0.w += hv * a.w;
        m1.x += hv * b2.x; m1.y += hv * b2.y; m1.z += hv * b2.z; m1.w += hv * b2.w;
    }
    size_t o = (size_t)(rbase + rl) * F + jg * 8;
    *(ushort4*)(xs + o) = pack4(s0); *(ushort4*)(xs + o + 4) = pack4(s1);
    *(ushort4*)(xd + o) = pack4(d0); *(ushort4*)(xd + o + 4) = pack4(d1);
    *(ushort4*)(xm + o) = pack4(m0); *(ushort4*)(xm + o + 4) = pack4(m1);
}

// ---- fused edge linears: ea (fp32, scattered to csr order) + em (bf16) ----
__global__ __launch_bounds__(256) void k_edgepair(const float* __restrict__ edge_attr,
        const float* __restrict__ aew, const float* __restrict__ aeb,
        const float* __restrict__ mew, const float* __restrict__ meb,
        const int* __restrict__ inv_pos, float* __restrict__ ea_perm,
        unsigned short* __restrict__ em_bf) {
    __shared__ float Wa[F_EDGE * F], Wm2[F_EDGE * F];    // 8 KB
    __shared__ float ert[F_EDGE][64];                    // 8 KB
    for (int i = threadIdx.x; i < F_EDGE * F; i += 256) {
        Wa[i] = aew[i]; Wm2[i] = mew[i];
    }
    int ebase = blockIdx.x * 64;
    for (int i = threadIdx.x; i < 512; i += 256) {
        int row = i >> 3, kq = i & 7;
        float4 v = *(const float4*)(edge_attr + (size_t)(ebase + row) * F_EDGE + kq * 4);
        ert[kq * 4 + 0][row] = v.x; ert[kq * 4 + 1][row] = v.y;
        ert[kq * 4 + 2][row] = v.z; ert[kq * 4 + 3][row] = v.w;
    }
    __syncthreads();
    int el = threadIdx.x >> 2;
    int jg = threadIdx.x & 3;
    float4 a0 = *(const float4*)(aeb + jg * 8), a1 = *(const float4*)(aeb + jg * 8 + 4);
    float4 m0 = *(const float4*)(meb + jg * 8), m1 = *(const float4*)(meb + jg * 8 + 4);
    for (int k = 0; k < F_EDGE; k++) {
        float ev = ert[k][el];
        float4 w0, w1;
        w0 = *(const float4*)(Wa + k * F + jg * 8); w1 = *(const float4*)(Wa + k * F + jg * 8 + 4);
        a0.x += ev * w0.x; a0.y += ev * w0.y; a0.z += ev * w0.z; a0.w += ev * w0.w;
        a1.x += ev * w1.x; a1.y += ev * w1.y; a1.z += ev * w1.z; a1.w += ev * w1.w;
        w0 = *(const float4*)(Wm2 + k * F + jg * 8); w1 = *(const float4*)(Wm2 + k * F + jg * 8 + 4);
        m0.x += ev * w0.x; m0.y += ev * w0.y; m0.z += ev * w0.z; m0.w += ev * w0.w;
        m1.x += ev * w1.x; m1.y += ev * w1.y; m1.z += ev * w1.z; m1.w += ev * w1.w;
    }
    int e = ebase + el;
    int p = inv_pos[e];
    *(float4*)(ea_perm + (size_t)p * F + jg * 8) = a0;
    *(float4*)(ea_perm + (size_t)p * F + jg * 8 + 4) = a1;
    size_t o = (size_t)e * F + jg * 8;
    *(ushort4*)(em_bf + o) = pack4(m0);
    *(ushort4*)(em_bf + o + 4) = pack4(m1);
}

// ---- fused attention: one wave per dst node; logits + joint softmax +
// alphaT scatter. items = deg*4 (edge-in-node, head) pairs. ----
__global__ __launch_bounds__(256) void k_attn(const float* __restrict__ ea_perm,
        const unsigned short* __restrict__ xs, const unsigned short* __restrict__ xd,
        const int* __restrict__ srcp, const int* __restrict__ row_start,
        const int* __restrict__ counts, const int* __restrict__ csr_e,
        const float* __restrict__ dw, const float* __restrict__ db,
        float* __restrict__ alphaT) {
    __shared__ float lg[4][512];                    // 8 KB; deg cap 128 (max ~25)
    int wv = threadIdx.x >> 6, lane = threadIdx.x & 63;
    int n = blockIdx.x * 4 + wv;
    if (n >= N_NODES) return;
    int start = row_start[n];
    int items = counts[n] * 4;
    float4 wreg[8];
#pragma unroll
    for (int q = 0; q < 8; q++) wreg[q] = *(const float4*)(dw + q * 4);
    float dbv = db[0];
    const unsigned short* xsr = xs + (size_t)n * NHF;
    float m = -1e30f;
    for (int i = lane; i < items; i += 64) {
        int ii = i >> 2, hh = i & 3;
        int p = start + ii;
        int s = srcp[p];
        const float4* ea4 = (const float4*)(ea_perm + (size_t)p * F);
        const unsigned short* xsh = xsr + hh * F;
        const unsigned short* xdh = xd + (size_t)s * NHF + hh * F;
        float acc = 0.f;
#pragma unroll
        for (int q = 0; q < 8; q++) {
            float4 ev = ea4[q];
            ushort4 ua = *(const ushort4*)(xsh + q * 4);
            ushort4 ub = *(const ushort4*)(xdh + q * 4);
            acc += fmaxf(bf2f(ua.x) + bf2f(ub.x) + ev.x, 0.f) * wreg[q].x;
            acc += fmaxf(bf2f(ua.y) + bf2f(ub.y) + ev.y, 0.f) * wreg[q].y;
            acc += fmaxf(bf2f(ua.z) + bf2f(ub.z) + ev.z, 0.f) * wreg[q].z;
            acc += fmaxf(bf2f(ua.w) + bf2f(ub.w) + ev.w, 0.f) * wreg[q].w;
        }
        float l = acc + dbv;
        lg[wv][i] = l;
        m = fmaxf(m, l);
    }
#pragma unroll
    for (int d = 1; d < 64; d <<= 1) m = fmaxf(m, __shfl_xor(m, d));
    float ssum = 0.f;
    for (int i = lane; i < items; i += 64) ssum += __expf(lg[wv][i] - m);
#pragma unroll
    for (int d = 1; d < 64; d <<= 1) ssum += __shfl_xor(ssum, d);
    float inv = 1.f / (ssum + 1e-8f);
    for (int i = lane; i < items; i += 64) {
        int ii = i >> 2, hh = i & 3;
        int e = csr_e[start + ii];
        float a = __expf(lg[wv][i] - m) * inv;
        // alphaT[t*4+j], t=(e%EQ)*4+hh, j=e/EQ
        alphaT[(size_t)(e % EQ) * 16 + hh * 4 + (e / EQ)] = a;
    }
}

// ---- pull aggregation; alphaT float4/residue; bf16 payload gathers ----
__global__ __launch_bounds__(256) void k_msg_pull(const int* __restrict__ row_start,
        const int* __restrict__ counts, const int* __restrict__ csr_e,
        const unsigned short* __restrict__ xm, const unsigned short* __restrict__ em,
        const float* __restrict__ alphaT, const int* __restrict__ dst,
        float* __restrict__ aggr) {
    int m = blockIdx.x * 8 + (threadIdx.x >> 5);
    if (m >= N_NODES) return;
    int f = threadIdx.x & 31;
    int start = row_start[m];
    int deg = counts[m];
    float acc0 = 0.f, acc1 = 0.f;
    int ii = 0;
    for (; ii + 2 <= deg; ii += 2) {
        int r0 = csr_e[start + ii], r1 = csr_e[start + ii + 1];
        int q0 = r0 >> 2, h0 = (r0 & 3) * F;
        int q1 = r1 >> 2, h1 = (r1 & 3) * F;
        float4 a0 = *(const float4*)(alphaT + (size_t)r0 * 4);
        float4 a1 = *(const float4*)(alphaT + (size_t)r1 * 4);
#pragma unroll
        for (int j = 0; j < 4; j++) {
            int e0 = q0 + j * EQ, e1 = q1 + j * EQ;
            int d0 = dst[e0], d1 = dst[e1];
            float w0 = (j == 0) ? a0.x : (j == 1) ? a0.y : (j == 2) ? a0.z : a0.w;
            float w1 = (j == 0) ? a1.x : (j == 1) ? a1.y : (j == 2) ? a1.z : a1.w;
            acc0 += w0 * (bf2f(xm[(size_t)d0 * NHF + h0 + f]) + bf2f(em[(size_t)e0 * F + f]));
            acc1 += w1 * (bf2f(xm[(size_t)d1 * NHF + h1 + f]) + bf2f(em[(size_t)e1 * F + f]));
        }
    }
    if (ii < deg) {
        int r0 = csr_e[start + ii];
        int q0 = r0 >> 2, h0 = (r0 & 3) * F;
        float4 a0 = *(const float4*)(alphaT + (size_t)r0 * 4);
#pragma unroll
        for (int j = 0; j < 4; j++) {
            int e0 = q0 + j * EQ;
            int d0 = dst[e0];
            float w0 = (j == 0) ? a0.x : (j == 1) ? a0.y : (j == 2) ? a0.z : a0.w;
            acc0 += w0 * (bf2f(xm[(size_t)d0 * NHF + h0 + f]) + bf2f(em[(size_t)e0 * F + f]));
        }
    }
    aggr[(size_t)m * F + f] = acc0 + acc1;
}

// ---- h_out = relu(aggr + h@Wn + bn + atom_in); final: mean over heads ----
__global__ __launch_bounds__(128) void k_combine(const float* __restrict__ h,
        const float* __restrict__ aggr, const float* __restrict__ atom_in,
        const float* __restrict__ wn, const float* __restrict__ bn,
        float* __restrict__ hout, float* __restrict__ final_out, int is_final) {
    __shared__ float W[F * F];
    __shared__ float sm[NHF];
    for (int i = threadIdx.x; i < F * F; i += 128) W[i] = wn[i];
    __syncthreads();
    int n = blockIdx.x;
    int head = threadIdx.x >> 5, j = threadIdx.x & 31;
    const float* hr = h + (size_t)n * NHF + head * F;
    float acc = bn[j];
    for (int k = 0; k < F; k++) acc += hr[k] * W[k * F + j];
    int flat = n * H + head;
    float ag = (flat < N_NODES) ? aggr[(size_t)flat * F + j] : 0.f;
    size_t idx = (size_t)n * NHF + head * F + j;
    float v = ag + acc + atom_in[idx];
    v = fmaxf(v, 0.f);
    if (!is_final) {
        hout[idx] = v;
    } else {
        sm[threadIdx.x] = v;
        __syncthreads();
        if (threadIdx.x < F) {
            float o = 0.25f * (sm[threadIdx.x] + sm[F + threadIdx.x] +
                               sm[2 * F + threadIdx.x] + sm[3 * F + threadIdx.x]);
            final_out[(size_t)n * F + threadIdx.x] = o;
        }
    }
}

extern "C" void kernel_launch(void* const* d_in, const int* in_sizes, int n_in,
                              void* d_out, int out_size, void* d_ws, size_t ws_size,
                              hipStream_t stream) {
    const float* x         = (const float*)d_in[0];
    const float* edge_attr = (const float*)d_in[1];
    const int*   eidx      = (const int*)d_in[2];
    const int*   src       = eidx;
    const int*   dst       = eidx + N_EDGES;
    const float* atom_w    = (const float*)d_in[3];
    const float* atom_b    = (const float*)d_in[4];
    const float* asw = (const float*)d_in[5],  *asb = (const float*)d_in[6];
    const float* adw = (const float*)d_in[7],  *adb = (const float*)d_in[8];
    const float* aew = (const float*)d_in[9],  *aeb = (const float*)d_in[10];
    const float* dww = (const float*)d_in[11], *dwb = (const float*)d_in[12];
    const float* mdw = (const float*)d_in[13], *mdb = (const float*)d_in[14];
    const float* mew = (const float*)d_in[15], *meb = (const float*)d_in[16];
    const float* wnw = (const float*)d_in[17], *wnb = (const float*)d_in[18];
    float* out = (float*)d_out;

    float* ws = (float*)d_ws;
    size_t off = 0;
    float* atom_in = ws + off; off += (size_t)N_NODES * NHF;     // fp32
    float* hbuf    = ws + off; off += (size_t)N_NODES * NHF;     // fp32
    unsigned short* xs_bf = (unsigned short*)(ws + off); off += (size_t)N_NODES * NHF / 2;
    unsigned short* xd_bf = (unsigned short*)(ws + off); off += (size_t)N_NODES * NHF / 2;
    unsigned short* xm_bf = (unsigned short*)(ws + off); off += (size_t)N_NODES * NHF / 2;
    unsigned short* em_bf = (unsigned short*)(ws + off); off += (size_t)N_EDGES * F / 2;
    float* ea_perm = ws + off; off += (size_t)N_EDGES * F;       // fp32, csr order
    float* alphaT  = ws + off; off += (size_t)N_EDGES * H;
    float* aggr    = ws + off; off += (size_t)N_NODES * F;
    int* counts    = (int*)(ws + off); off += N_NODES;
    int* row_start = (int*)(ws + off); off += N_NODES;
    int* cursor    = (int*)(ws + off); off += N_NODES;
    int* excl      = (int*)(ws + off); off += N_NODES;
    int* bsum      = (int*)(ws + off); off += 128;
    int* csr_e     = (int*)(ws + off); off += N_EDGES;
    int* srcp      = (int*)(ws + off); off += N_EDGES;
    int* inv_pos   = (int*)(ws + off); off += N_EDGES;

    // ---- CSR build (dst is layer-invariant) ----
    hipMemsetAsync(counts, 0, N_NODES * sizeof(int), stream);
    k_hist <<<(N_EDGES + 255) / 256, 256, 0, stream>>>(dst, counts);
    k_scan1<<<N_SCAN_BLKS, SCAN_BLK, 0, stream>>>(counts, excl, bsum);
    k_scan2<<<1, 128, 0, stream>>>(bsum);
    k_scan3<<<N_SCAN_BLKS, SCAN_BLK, 0, stream>>>(excl, bsum, row_start, cursor);
    k_fill <<<(N_EDGES + 255) / 256, 256, 0, stream>>>(src, dst, cursor, csr_e,
                                                       srcp, inv_pos);

    k_atom<<<(N_NODES + 31) / 32, 256, 0, stream>>>(x, atom_w, atom_b, atom_in);

    for (int l = 0; l < 2; l++) {
        const float* hin  = (l == 0) ? atom_in : hbuf;
        float*       hout = hbuf;
        int is_final = (l == 1);
        k_nodelin3<<<(N_NODES * H) / 64, 256, 0, stream>>>(
            hin, asw + l * F * F, asb + l * F, adw + l * F * F, adb + l * F,
            mdw + l * F * F, mdb + l * F, xs_bf, xd_bf, xm_bf);
        k_edgepair<<<N_EDGES / 64, 256, 0, stream>>>(
            edge_attr, aew + l * F_EDGE * F, aeb + l * F,
            mew + l * F_EDGE * F, meb + l * F, inv_pos, ea_perm, em_bf);
        k_attn<<<(N_NODES + 3) / 4, 256, 0, stream>>>(
            ea_perm, xs_bf, xd_bf, srcp, row_start, counts, csr_e,
            dww + l * F, dwb + l, alphaT);
        k_msg_pull<<<(N_NODES + 7) / 8, 256, 0, stream>>>(row_start, counts, csr_e,
                                                          xm_bf, em_bf, alphaT,
                                                          dst, aggr);
        k_combine<<<N_NODES, 128, 0, stream>>>(hin, aggr, atom_in,
                                               wnw + l * F * F, wnb + l * F,
                                               hout, out, is_final);
    }
}

// Round 6
// 633.543 us; speedup vs baseline: 2.1044x; 1.1198x over previous
//
#include <hip/hip_runtime.h>

#define N_NODES 50000
#define N_EDGES 400000
#define EQ      100000   // N_EDGES/4
#define F_IN    128
#define F_EDGE  32
#define F       32
#define H       4
#define NHF     128   // H*F

#define SCAN_BLK 512
#define N_SCAN_BLKS ((N_NODES + SCAN_BLK - 1) / SCAN_BLK)   // 98

// ---- bf16 helpers (RNE) ----
__device__ __forceinline__ float bf2f(unsigned short u) {
    return __uint_as_float(((unsigned)u) << 16);
}
__device__ __forceinline__ unsigned short f2bf(float f) {
    unsigned u = __float_as_uint(f);
    return (unsigned short)((u + 0x7FFFu + ((u >> 16) & 1u)) >> 16);
}
__device__ __forceinline__ ushort4 pack4(float4 v) {
    return make_ushort4(f2bf(v.x), f2bf(v.y), f2bf(v.z), f2bf(v.w));
}

// ---- atom_in = relu(x @ atom_w + atom_b); 32 nodes/block ----
__global__ __launch_bounds__(256) void k_atom(const float* __restrict__ x,
                                              const float* __restrict__ w,
                                              const float* __restrict__ b,
                                              float* __restrict__ out) {
    __shared__ float wlds[F_IN * NHF];              // 64 KB
    __shared__ float xl[32 * F_IN];                 // 16 KB
    const float4* w4 = (const float4*)w;
    float4* wl4 = (float4*)wlds;
    for (int i = threadIdx.x; i < F_IN * NHF / 4; i += 256) wl4[i] = w4[i];
    int nb = blockIdx.x * 32;
    int nrows = min(32, N_NODES - nb);
    const float4* x4 = (const float4*)(x + (size_t)nb * F_IN);
    float4* xl4 = (float4*)xl;
    for (int i = threadIdx.x; i < nrows * F_IN / 4; i += 256) xl4[i] = x4[i];
    __syncthreads();
    int jg = threadIdx.x & 31;
    int nl = threadIdx.x >> 5;
    float4 bv = *(const float4*)(b + jg * 4);
    float4 acc[4] = {bv, bv, bv, bv};
    for (int k = 0; k < F_IN; k++) {
        float4 wv = *(const float4*)(wlds + k * NHF + jg * 4);
#pragma unroll
        for (int q = 0; q < 4; q++) {
            float xk = xl[(nl + 8 * q) * F_IN + k];
            acc[q].x += xk * wv.x; acc[q].y += xk * wv.y;
            acc[q].z += xk * wv.z; acc[q].w += xk * wv.w;
        }
    }
#pragma unroll
    for (int q = 0; q < 4; q++) {
        int n = nb + nl + 8 * q;
        if (n < N_NODES) {
            float4 a = acc[q];
            a.x = fmaxf(a.x, 0.f); a.y = fmaxf(a.y, 0.f);
            a.z = fmaxf(a.z, 0.f); a.w = fmaxf(a.w, 0.f);
            *(float4*)(out + (size_t)n * NHF + jg * 4) = a;
        }
    }
}

// ---- CSR build ----
__global__ __launch_bounds__(256) void k_hist(const int* __restrict__ dst,
                                              int* __restrict__ counts) {
    int e = blockIdx.x * 256 + threadIdx.x;
    if (e < N_EDGES) atomicAdd(counts + dst[e], 1);
}

__global__ __launch_bounds__(SCAN_BLK) void k_scan1(const int* __restrict__ counts,
        int* __restrict__ excl, int* __restrict__ bsum) {
    __shared__ int s[SCAN_BLK];
    int i = blockIdx.x * SCAN_BLK + threadIdx.x;
    int v = (i < N_NODES) ? counts[i] : 0;
    s[threadIdx.x] = v;
    __syncthreads();
    for (int d = 1; d < SCAN_BLK; d <<= 1) {
        int t = (threadIdx.x >= d) ? s[threadIdx.x - d] : 0;
        __syncthreads();
        s[threadIdx.x] += t;
        __syncthreads();
    }
    if (i < N_NODES) excl[i] = s[threadIdx.x] - v;
    if (threadIdx.x == SCAN_BLK - 1) bsum[blockIdx.x] = s[SCAN_BLK - 1];
}

__global__ __launch_bounds__(128) void k_scan2(int* __restrict__ bsum) {
    __shared__ int s[128];
    int v = (threadIdx.x < N_SCAN_BLKS) ? bsum[threadIdx.x] : 0;
    s[threadIdx.x] = v;
    __syncthreads();
    for (int d = 1; d < 128; d <<= 1) {
        int t = (threadIdx.x >= d) ? s[threadIdx.x - d] : 0;
        __syncthreads();
        s[threadIdx.x] += t;
        __syncthreads();
    }
    if (threadIdx.x < N_SCAN_BLKS) bsum[threadIdx.x] = s[threadIdx.x] - v;
}

__global__ __launch_bounds__(SCAN_BLK) void k_scan3(const int* __restrict__ excl,
        const int* __restrict__ bsum, int* __restrict__ row_start,
        int* __restrict__ cursor) {
    int i = blockIdx.x * SCAN_BLK + threadIdx.x;
    if (i < N_NODES) {
        int v = excl[i] + bsum[blockIdx.x];
        row_start[i] = v;
        cursor[i] = v;
    }
}

__global__ __launch_bounds__(256) void k_fill(const int* __restrict__ src,
        const int* __restrict__ dst, int* __restrict__ cursor,
        int* __restrict__ csr_e, int* __restrict__ srcp,
        int* __restrict__ inv_pos) {
    int e = blockIdx.x * 256 + threadIdx.x;
    if (e < N_EDGES) {
        int pos = atomicAdd(cursor + dst[e], 1);
        csr_e[pos] = e;
        srcp[pos] = src[e];
        inv_pos[e] = pos;
    }
}

// ---- xs,xd,xm = h @ {Ws,Wd,Wm} + b -> bf16 outputs ----
__global__ __launch_bounds__(256) void k_nodelin3(const float* __restrict__ h,
        const float* __restrict__ ws, const float* __restrict__ bs,
        const float* __restrict__ wd, const float* __restrict__ bd,
        const float* __restrict__ wm, const float* __restrict__ bm,
        unsigned short* __restrict__ xs, unsigned short* __restrict__ xd,
        unsigned short* __restrict__ xm) {
    __shared__ float Ws[F * F], Wd[F * F], Wm[F * F];
    __shared__ float hrt[F][64];
    for (int i = threadIdx.x; i < F * F; i += 256) {
        Ws[i] = ws[i]; Wd[i] = wd[i]; Wm[i] = wm[i];
    }
    int rbase = blockIdx.x * 64;
    for (int i = threadIdx.x; i < 512; i += 256) {
        int row = i >> 3, kq = i & 7;
        float4 v = *(const float4*)(h + (size_t)(rbase + row) * F + kq * 4);
        hrt[kq * 4 + 0][row] = v.x; hrt[kq * 4 + 1][row] = v.y;
        hrt[kq * 4 + 2][row] = v.z; hrt[kq * 4 + 3][row] = v.w;
    }
    __syncthreads();
    int rl = threadIdx.x >> 2;
    int jg = threadIdx.x & 3;
    float4 s0 = *(const float4*)(bs + jg * 8), s1 = *(const float4*)(bs + jg * 8 + 4);
    float4 d0 = *(const float4*)(bd + jg * 8), d1 = *(const float4*)(bd + jg * 8 + 4);
    float4 m0 = *(const float4*)(bm + jg * 8), m1 = *(const float4*)(bm + jg * 8 + 4);
    for (int k = 0; k < F; k++) {
        float hv = hrt[k][rl];
        float4 a, b2;
        a = *(const float4*)(Ws + k * F + jg * 8); b2 = *(const float4*)(Ws + k * F + jg * 8 + 4);
        s0.x += hv * a.x; s0.y += hv * a.y; s0.z += hv * a.z; s0.w += hv * a.w;
        s1.x += hv * b2.x; s1.y += hv * b2.y; s1.z += hv * b2.z; s1.w += hv * b2.w;
        a = *(const float4*)(Wd + k * F + jg * 8); b2 = *(const float4*)(Wd + k * F + jg * 8 + 4);
        d0.x += hv * a.x; d0.y += hv * a.y; d0.z += hv * a.z; d0.w += hv * a.w;
        d1.x += hv * b2.x; d1.y += hv * b2.y; d1.z += hv * b2.z; d1.w += hv * b2.w;
        a = *(const float4*)(Wm + k * F + jg * 8); b2 = *(const float4*)(Wm + k * F + jg * 8 + 4);
        m0.x += hv * a.x; m0.y += hv * a.y; m0.z += hv * a.z; m0.w += hv * a.w;
        m1.x += hv * b2.x; m1.y += hv * b2.y; m1.z += hv * b2.z; m1.w += hv * b2.w;
    }
    size_t o = (size_t)(rbase + rl) * F + jg * 8;
    *(ushort4*)(xs + o) = pack4(s0); *(ushort4*)(xs + o + 4) = pack4(s1);
    *(ushort4*)(xd + o) = pack4(d0); *(ushort4*)(xd + o + 4) = pack4(d1);
    *(ushort4*)(xm + o) = pack4(m0); *(ushort4*)(xm + o + 4) = pack4(m1);
}

// ---- fused edge linears: ea (bf16, scattered to csr order) + em (bf16,
// emX layout [q][j][f], q=e%EQ, j=e/EQ) ----
__global__ __launch_bounds__(256) void k_edgepair(const float* __restrict__ edge_attr,
        const float* __restrict__ aew, const float* __restrict__ aeb,
        const float* __restrict__ mew, const float* __restrict__ meb,
        const int* __restrict__ inv_pos, unsigned short* __restrict__ ea_csr,
        unsigned short* __restrict__ emX) {
    __shared__ float Wa[F_EDGE * F], Wm2[F_EDGE * F];    // 8 KB
    __shared__ float ert[F_EDGE][64];                    // 8 KB
    for (int i = threadIdx.x; i < F_EDGE * F; i += 256) {
        Wa[i] = aew[i]; Wm2[i] = mew[i];
    }
    int ebase = blockIdx.x * 64;
    for (int i = threadIdx.x; i < 512; i += 256) {
        int row = i >> 3, kq = i & 7;
        float4 v = *(const float4*)(edge_attr + (size_t)(ebase + row) * F_EDGE + kq * 4);
        ert[kq * 4 + 0][row] = v.x; ert[kq * 4 + 1][row] = v.y;
        ert[kq * 4 + 2][row] = v.z; ert[kq * 4 + 3][row] = v.w;
    }
    __syncthreads();
    int el = threadIdx.x >> 2;
    int jg = threadIdx.x & 3;
    float4 a0 = *(const float4*)(aeb + jg * 8), a1 = *(const float4*)(aeb + jg * 8 + 4);
    float4 m0 = *(const float4*)(meb + jg * 8), m1 = *(const float4*)(meb + jg * 8 + 4);
    for (int k = 0; k < F_EDGE; k++) {
        float ev = ert[k][el];
        float4 w0, w1;
        w0 = *(const float4*)(Wa + k * F + jg * 8); w1 = *(const float4*)(Wa + k * F + jg * 8 + 4);
        a0.x += ev * w0.x; a0.y += ev * w0.y; a0.z += ev * w0.z; a0.w += ev * w0.w;
        a1.x += ev * w1.x; a1.y += ev * w1.y; a1.z += ev * w1.z; a1.w += ev * w1.w;
        w0 = *(const float4*)(Wm2 + k * F + jg * 8); w1 = *(const float4*)(Wm2 + k * F + jg * 8 + 4);
        m0.x += ev * w0.x; m0.y += ev * w0.y; m0.z += ev * w0.z; m0.w += ev * w0.w;
        m1.x += ev * w1.x; m1.y += ev * w1.y; m1.z += ev * w1.z; m1.w += ev * w1.w;
    }
    int e = ebase + el;
    int p = inv_pos[e];
    size_t oa = (size_t)p * F + jg * 8;
    *(ushort4*)(ea_csr + oa) = pack4(a0);
    *(ushort4*)(ea_csr + oa + 4) = pack4(a1);
    int q = e % EQ, j = e / EQ;
    size_t om = (size_t)q * NHF + j * F + jg * 8;
    *(ushort4*)(emX + om) = pack4(m0);
    *(ushort4*)(emX + om + 4) = pack4(m1);
}

// ---- fused attention: one wave per dst node; logits + joint softmax +
// alphaT scatter (alphaT[q*16 + hh*4 + j]) ----
__global__ __launch_bounds__(256) void k_attn(const unsigned short* __restrict__ ea_csr,
        const unsigned short* __restrict__ xs, const unsigned short* __restrict__ xd,
        const int* __restrict__ srcp, const int* __restrict__ row_start,
        const int* __restrict__ counts, const int* __restrict__ csr_e,
        const float* __restrict__ dw, const float* __restrict__ db,
        float* __restrict__ alphaT) {
    __shared__ float lg[4][512];                    // 8 KB; items cap 512
    int wv = threadIdx.x >> 6, lane = threadIdx.x & 63;
    int n = blockIdx.x * 4 + wv;
    if (n >= N_NODES) return;
    int start = row_start[n];
    int items = counts[n] * 4;
    float4 wreg[8];
#pragma unroll
    for (int q = 0; q < 8; q++) wreg[q] = *(const float4*)(dw + q * 4);
    float dbv = db[0];
    const unsigned short* xsr = xs + (size_t)n * NHF;
    float m = -1e30f;
    for (int i = lane; i < items; i += 64) {
        int ii = i >> 2, hh = i & 3;
        int p = start + ii;
        int s = srcp[p];
        const unsigned short* ear = ea_csr + (size_t)p * F;
        const unsigned short* xsh = xsr + hh * F;
        const unsigned short* xdh = xd + (size_t)s * NHF + hh * F;
        float acc = 0.f;
#pragma unroll
        for (int q = 0; q < 8; q++) {
            ushort4 ue = *(const ushort4*)(ear + q * 4);
            ushort4 ua = *(const ushort4*)(xsh + q * 4);
            ushort4 ub = *(const ushort4*)(xdh + q * 4);
            acc += fmaxf(bf2f(ua.x) + bf2f(ub.x) + bf2f(ue.x), 0.f) * wreg[q].x;
            acc += fmaxf(bf2f(ua.y) + bf2f(ub.y) + bf2f(ue.y), 0.f) * wreg[q].y;
            acc += fmaxf(bf2f(ua.z) + bf2f(ub.z) + bf2f(ue.z), 0.f) * wreg[q].z;
            acc += fmaxf(bf2f(ua.w) + bf2f(ub.w) + bf2f(ue.w), 0.f) * wreg[q].w;
        }
        float l = acc + dbv;
        lg[wv][i] = l;
        m = fmaxf(m, l);
    }
#pragma unroll
    for (int d = 1; d < 64; d <<= 1) m = fmaxf(m, __shfl_xor(m, d));
    float ssum = 0.f;
    for (int i = lane; i < items; i += 64) ssum += __expf(lg[wv][i] - m);
#pragma unroll
    for (int d = 1; d < 64; d <<= 1) ssum += __shfl_xor(ssum, d);
    float inv = 1.f / (ssum + 1e-8f);
    for (int i = lane; i < items; i += 64) {
        int ii = i >> 2, hh = i & 3;
        int e = csr_e[start + ii];
        float a = __expf(lg[wv][i] - m) * inv;
        alphaT[(size_t)(e % EQ) * 16 + hh * 4 + (e / EQ)] = a;
    }
}

// ---- q-major message build: for q, residues r=4q+c (c=0..3) share edges
// e_j=q+jEQ. out_c = sum_j alpha[c][j]*(xm[dst[e_j]][c*32+f] + emX[q][j][f]).
// Written bf16 to csr slot inv_pos[4q+c] -> node pull becomes sequential. ----
__global__ __launch_bounds__(256) void k_msgq(const float* __restrict__ alphaT,
        const unsigned short* __restrict__ emX, const unsigned short* __restrict__ xm,
        const int* __restrict__ dst, const int* __restrict__ inv_pos,
        unsigned short* __restrict__ ems_csr) {
    int g = blockIdx.x * 8 + (threadIdx.x >> 5);
    if (g >= EQ) return;
    int f = threadIdx.x & 31;
    const float4* a4 = (const float4*)(alphaT + (size_t)g * 16);
    float4 ac[4] = {a4[0], a4[1], a4[2], a4[3]};    // ac[c] = alphas over j
    int4 dj = make_int4(dst[g], dst[g + EQ], dst[g + 2 * EQ], dst[g + 3 * EQ]);
    float out[4] = {0.f, 0.f, 0.f, 0.f};
#pragma unroll
    for (int j = 0; j < 4; j++) {
        int d = (j == 0) ? dj.x : (j == 1) ? dj.y : (j == 2) ? dj.z : dj.w;
        float emv = bf2f(emX[(size_t)g * NHF + j * F + f]);
        const unsigned short* xr = xm + (size_t)d * NHF + f;
#pragma unroll
        for (int c = 0; c < 4; c++) {
            float a = (j == 0) ? ac[c].x : (j == 1) ? ac[c].y
                    : (j == 2) ? ac[c].z : ac[c].w;
            out[c] += a * (bf2f(xr[c * F]) + emv);
        }
    }
    const int4 pos = *(const int4*)(inv_pos + (size_t)g * 4);
#pragma unroll
    for (int c = 0; c < 4; c++) {
        int p = (c == 0) ? pos.x : (c == 1) ? pos.y : (c == 2) ? pos.z : pos.w;
        ems_csr[(size_t)p * F + f] = f2bf(out[c]);
    }
}

// ---- h_out = relu(msgpull + h@Wn + bn + atom_in); final: mean over heads.
// Flat row m=4n+head receives csr-sequential ems_csr rows of dst-node m. ----
__global__ __launch_bounds__(128) void k_combine(const float* __restrict__ h,
        const unsigned short* __restrict__ ems_csr, const int* __restrict__ row_start,
        const int* __restrict__ counts, const float* __restrict__ atom_in,
        const float* __restrict__ wn, const float* __restrict__ bn,
        float* __restrict__ hout, float* __restrict__ final_out, int is_final) {
    __shared__ float W[F * F];
    __shared__ float sm[NHF];
    for (int i = threadIdx.x; i < F * F; i += 128) W[i] = wn[i];
    __syncthreads();
    int n = blockIdx.x;
    int head = threadIdx.x >> 5, j = threadIdx.x & 31;
    const float* hr = h + (size_t)n * NHF + head * F;
    float acc = bn[j];
    for (int k = 0; k < F; k++) acc += hr[k] * W[k * F + j];
    float ag = 0.f;
    int m = n * H + head;
    if (m < N_NODES) {
        int st = row_start[m], deg = counts[m];
        const unsigned short* er = ems_csr + (size_t)st * F + j;
        for (int p = 0; p < deg; p++) ag += bf2f(er[(size_t)p * F]);
    }
    size_t idx = (size_t)n * NHF + head * F + j;
    float v = ag + acc + atom_in[idx];
    v = fmaxf(v, 0.f);
    if (!is_final) {
        hout[idx] = v;
    } else {
        sm[threadIdx.x] = v;
        __syncthreads();
        if (threadIdx.x < F) {
            float o = 0.25f * (sm[threadIdx.x] + sm[F + threadIdx.x] +
                               sm[2 * F + threadIdx.x] + sm[3 * F + threadIdx.x]);
            final_out[(size_t)n * F + threadIdx.x] = o;
        }
    }
}

extern "C" void kernel_launch(void* const* d_in, const int* in_sizes, int n_in,
                              void* d_out, int out_size, void* d_ws, size_t ws_size,
                              hipStream_t stream) {
    const float* x         = (const float*)d_in[0];
    const float* edge_attr = (const float*)d_in[1];
    const int*   eidx      = (const int*)d_in[2];
    const int*   src       = eidx;
    const int*   dst       = eidx + N_EDGES;
    const float* atom_w    = (const float*)d_in[3];
    const float* atom_b    = (const float*)d_in[4];
    const float* asw = (const float*)d_in[5],  *asb = (const float*)d_in[6];
    const float* adw = (const float*)d_in[7],  *adb = (const float*)d_in[8];
    const float* aew = (const float*)d_in[9],  *aeb = (const float*)d_in[10];
    const float* dww = (const float*)d_in[11], *dwb = (const float*)d_in[12];
    const float* mdw = (const float*)d_in[13], *mdb = (const float*)d_in[14];
    const float* mew = (const float*)d_in[15], *meb = (const float*)d_in[16];
    const float* wnw = (const float*)d_in[17], *wnb = (const float*)d_in[18];
    float* out = (float*)d_out;

    float* ws = (float*)d_ws;
    size_t off = 0;
    float* atom_in = ws + off; off += (size_t)N_NODES * NHF;
    float* hbuf    = ws + off; off += (size_t)N_NODES * NHF;
    unsigned short* xs_bf  = (unsigned short*)(ws + off); off += (size_t)N_NODES * NHF / 2;
    unsigned short* xd_bf  = (unsigned short*)(ws + off); off += (size_t)N_NODES * NHF / 2;
    unsigned short* xm_bf  = (unsigned short*)(ws + off); off += (size_t)N_NODES * NHF / 2;
    unsigned short* ea_csr = (unsigned short*)(ws + off); off += (size_t)N_EDGES * F / 2;
    unsigned short* emX    = (unsigned short*)(ws + off); off += (size_t)N_EDGES * F / 2;
    unsigned short* ems    = (unsigned short*)(ws + off); off += (size_t)N_EDGES * F / 2;
    float* alphaT  = ws + off; off += (size_t)N_EDGES * H;
    int* counts    = (int*)(ws + off); off += N_NODES;
    int* row_start = (int*)(ws + off); off += N_NODES;
    int* cursor    = (int*)(ws + off); off += N_NODES;
    int* excl      = (int*)(ws + off); off += N_NODES;
    int* bsum      = (int*)(ws + off); off += 128;
    int* csr_e     = (int*)(ws + off); off += N_EDGES;
    int* srcp      = (int*)(ws + off); off += N_EDGES;
    int* inv_pos   = (int*)(ws + off); off += N_EDGES;

    // ---- CSR build (dst is layer-invariant) ----
    hipMemsetAsync(counts, 0, N_NODES * sizeof(int), stream);
    k_hist <<<(N_EDGES + 255) / 256, 256, 0, stream>>>(dst, counts);
    k_scan1<<<N_SCAN_BLKS, SCAN_BLK, 0, stream>>>(counts, excl, bsum);
    k_scan2<<<1, 128, 0, stream>>>(bsum);
    k_scan3<<<N_SCAN_BLKS, SCAN_BLK, 0, stream>>>(excl, bsum, row_start, cursor);
    k_fill <<<(N_EDGES + 255) / 256, 256, 0, stream>>>(src, dst, cursor, csr_e,
                                                       srcp, inv_pos);

    k_atom<<<(N_NODES + 31) / 32, 256, 0, stream>>>(x, atom_w, atom_b, atom_in);

    for (int l = 0; l < 2; l++) {
        const float* hin  = (l == 0) ? atom_in : hbuf;
        float*       hout = hbuf;
        int is_final = (l == 1);
        k_nodelin3<<<(N_NODES * H) / 64, 256, 0, stream>>>(
            hin, asw + l * F * F, asb + l * F, adw + l * F * F, adb + l * F,
            mdw + l * F * F, mdb + l * F, xs_bf, xd_bf, xm_bf);
        k_edgepair<<<N_EDGES / 64, 256, 0, stream>>>(
            edge_attr, aew + l * F_EDGE * F, aeb + l * F,
            mew + l * F_EDGE * F, meb + l * F, inv_pos, ea_csr, emX);
        k_attn<<<(N_NODES + 3) / 4, 256, 0, stream>>>(
            ea_csr, xs_bf, xd_bf, srcp, row_start, counts, csr_e,
            dww + l * F, dwb + l, alphaT);
        k_msgq<<<(EQ + 7) / 8, 256, 0, stream>>>(alphaT, emX, xm_bf, dst,
                                                 inv_pos, ems);
        k_combine<<<N_NODES, 128, 0, stream>>>(hin, ems, row_start, counts,
                                               atom_in, wnw + l * F * F,
                                               wnb + l * F, hout, out, is_final);
    }
}

// Round 7
// 583.354 us; speedup vs baseline: 2.2854x; 1.0860x over previous
//
#include <hip/hip_runtime.h>

#define N_NODES 50000
#define N_EDGES 400000
#define EQ      100000   // N_EDGES/4
#define F_IN    128
#define F_EDGE  32
#define F       32
#define H       4
#define NHF     128   // H*F

#define SCAN_BLK 512
#define N_SCAN_BLKS ((N_NODES + SCAN_BLK - 1) / SCAN_BLK)   // 98

// ---- bf16 helpers (RNE) ----
__device__ __forceinline__ float bf2f(unsigned short u) {
    return __uint_as_float(((unsigned)u) << 16);
}
__device__ __forceinline__ unsigned short f2bf(float f) {
    unsigned u = __float_as_uint(f);
    return (unsigned short)((u + 0x7FFFu + ((u >> 16) & 1u)) >> 16);
}
__device__ __forceinline__ ushort4 pack4(float4 v) {
    return make_ushort4(f2bf(v.x), f2bf(v.y), f2bf(v.z), f2bf(v.w));
}

// ---- atom_in = relu(x @ atom_w + atom_b); 32 nodes/block ----
__global__ __launch_bounds__(256) void k_atom(const float* __restrict__ x,
                                              const float* __restrict__ w,
                                              const float* __restrict__ b,
                                              float* __restrict__ out) {
    __shared__ float wlds[F_IN * NHF];              // 64 KB
    __shared__ float xl[32 * F_IN];                 // 16 KB
    const float4* w4 = (const float4*)w;
    float4* wl4 = (float4*)wlds;
    for (int i = threadIdx.x; i < F_IN * NHF / 4; i += 256) wl4[i] = w4[i];
    int nb = blockIdx.x * 32;
    int nrows = min(32, N_NODES - nb);
    const float4* x4 = (const float4*)(x + (size_t)nb * F_IN);
    float4* xl4 = (float4*)xl;
    for (int i = threadIdx.x; i < nrows * F_IN / 4; i += 256) xl4[i] = x4[i];
    __syncthreads();
    int jg = threadIdx.x & 31;
    int nl = threadIdx.x >> 5;
    float4 bv = *(const float4*)(b + jg * 4);
    float4 acc[4] = {bv, bv, bv, bv};
    for (int k = 0; k < F_IN; k++) {
        float4 wv = *(const float4*)(wlds + k * NHF + jg * 4);
#pragma unroll
        for (int q = 0; q < 4; q++) {
            float xk = xl[(nl + 8 * q) * F_IN + k];
            acc[q].x += xk * wv.x; acc[q].y += xk * wv.y;
            acc[q].z += xk * wv.z; acc[q].w += xk * wv.w;
        }
    }
#pragma unroll
    for (int q = 0; q < 4; q++) {
        int n = nb + nl + 8 * q;
        if (n < N_NODES) {
            float4 a = acc[q];
            a.x = fmaxf(a.x, 0.f); a.y = fmaxf(a.y, 0.f);
            a.z = fmaxf(a.z, 0.f); a.w = fmaxf(a.w, 0.f);
            *(float4*)(out + (size_t)n * NHF + jg * 4) = a;
        }
    }
}

// ---- CSR build ----
__global__ __launch_bounds__(256) void k_hist(const int* __restrict__ dst,
                                              int* __restrict__ counts) {
    int e = blockIdx.x * 256 + threadIdx.x;
    if (e < N_EDGES) atomicAdd(counts + dst[e], 1);
}

__global__ __launch_bounds__(SCAN_BLK) void k_scan1(const int* __restrict__ counts,
        int* __restrict__ excl, int* __restrict__ bsum) {
    __shared__ int s[SCAN_BLK];
    int i = blockIdx.x * SCAN_BLK + threadIdx.x;
    int v = (i < N_NODES) ? counts[i] : 0;
    s[threadIdx.x] = v;
    __syncthreads();
    for (int d = 1; d < SCAN_BLK; d <<= 1) {
        int t = (threadIdx.x >= d) ? s[threadIdx.x - d] : 0;
        __syncthreads();
        s[threadIdx.x] += t;
        __syncthreads();
    }
    if (i < N_NODES) excl[i] = s[threadIdx.x] - v;
    if (threadIdx.x == SCAN_BLK - 1) bsum[blockIdx.x] = s[SCAN_BLK - 1];
}

__global__ __launch_bounds__(128) void k_scan2(int* __restrict__ bsum) {
    __shared__ int s[128];
    int v = (threadIdx.x < N_SCAN_BLKS) ? bsum[threadIdx.x] : 0;
    s[threadIdx.x] = v;
    __syncthreads();
    for (int d = 1; d < 128; d <<= 1) {
        int t = (threadIdx.x >= d) ? s[threadIdx.x - d] : 0;
        __syncthreads();
        s[threadIdx.x] += t;
        __syncthreads();
    }
    if (threadIdx.x < N_SCAN_BLKS) bsum[threadIdx.x] = s[threadIdx.x] - v;
}

__global__ __launch_bounds__(SCAN_BLK) void k_scan3(const int* __restrict__ excl,
        const int* __restrict__ bsum, int* __restrict__ row_start,
        int* __restrict__ cursor) {
    int i = blockIdx.x * SCAN_BLK + threadIdx.x;
    if (i < N_NODES) {
        int v = excl[i] + bsum[blockIdx.x];
        row_start[i] = v;
        cursor[i] = v;
    }
}

__global__ __launch_bounds__(256) void k_fill(const int* __restrict__ src,
        const int* __restrict__ dst, int* __restrict__ cursor,
        int* __restrict__ csr_e, int* __restrict__ srcp,
        int* __restrict__ inv_pos) {
    int e = blockIdx.x * 256 + threadIdx.x;
    if (e < N_EDGES) {
        int pos = atomicAdd(cursor + dst[e], 1);
        csr_e[pos] = e;
        srcp[pos] = src[e];
        inv_pos[e] = pos;
    }
}

// ---- xs,xd,xm = h @ {Ws,Wd,Wm} + b -> bf16 outputs ----
__global__ __launch_bounds__(256) void k_nodelin3(const float* __restrict__ h,
        const float* __restrict__ ws, const float* __restrict__ bs,
        const float* __restrict__ wd, const float* __restrict__ bd,
        const float* __restrict__ wm, const float* __restrict__ bm,
        unsigned short* __restrict__ xs, unsigned short* __restrict__ xd,
        unsigned short* __restrict__ xm) {
    __shared__ float Ws[F * F], Wd[F * F], Wm[F * F];
    __shared__ float hrt[F][64];
    for (int i = threadIdx.x; i < F * F; i += 256) {
        Ws[i] = ws[i]; Wd[i] = wd[i]; Wm[i] = wm[i];
    }
    int rbase = blockIdx.x * 64;
    for (int i = threadIdx.x; i < 512; i += 256) {
        int row = i >> 3, kq = i & 7;
        float4 v = *(const float4*)(h + (size_t)(rbase + row) * F + kq * 4);
        hrt[kq * 4 + 0][row] = v.x; hrt[kq * 4 + 1][row] = v.y;
        hrt[kq * 4 + 2][row] = v.z; hrt[kq * 4 + 3][row] = v.w;
    }
    __syncthreads();
    int rl = threadIdx.x >> 2;
    int jg = threadIdx.x & 3;
    float4 s0 = *(const float4*)(bs + jg * 8), s1 = *(const float4*)(bs + jg * 8 + 4);
    float4 d0 = *(const float4*)(bd + jg * 8), d1 = *(const float4*)(bd + jg * 8 + 4);
    float4 m0 = *(const float4*)(bm + jg * 8), m1 = *(const float4*)(bm + jg * 8 + 4);
    for (int k = 0; k < F; k++) {
        float hv = hrt[k][rl];
        float4 a, b2;
        a = *(const float4*)(Ws + k * F + jg * 8); b2 = *(const float4*)(Ws + k * F + jg * 8 + 4);
        s0.x += hv * a.x; s0.y += hv * a.y; s0.z += hv * a.z; s0.w += hv * a.w;
        s1.x += hv * b2.x; s1.y += hv * b2.y; s1.z += hv * b2.z; s1.w += hv * b2.w;
        a = *(const float4*)(Wd + k * F + jg * 8); b2 = *(const float4*)(Wd + k * F + jg * 8 + 4);
        d0.x += hv * a.x; d0.y += hv * a.y; d0.z += hv * a.z; d0.w += hv * a.w;
        d1.x += hv * b2.x; d1.y += hv * b2.y; d1.z += hv * b2.z; d1.w += hv * b2.w;
        a = *(const float4*)(Wm + k * F + jg * 8); b2 = *(const float4*)(Wm + k * F + jg * 8 + 4);
        m0.x += hv * a.x; m0.y += hv * a.y; m0.z += hv * a.z; m0.w += hv * a.w;
        m1.x += hv * b2.x; m1.y += hv * b2.y; m1.z += hv * b2.z; m1.w += hv * b2.w;
    }
    size_t o = (size_t)(rbase + rl) * F + jg * 8;
    *(ushort4*)(xs + o) = pack4(s0); *(ushort4*)(xs + o + 4) = pack4(s1);
    *(ushort4*)(xd + o) = pack4(d0); *(ushort4*)(xd + o + 4) = pack4(d1);
    *(ushort4*)(xm + o) = pack4(m0); *(ushort4*)(xm + o + 4) = pack4(m1);
}

// ---- fused edge linears: ea (bf16, csr order) + em (bf16, [q][j][f]) ----
__global__ __launch_bounds__(256) void k_edgepair(const float* __restrict__ edge_attr,
        const float* __restrict__ aew, const float* __restrict__ aeb,
        const float* __restrict__ mew, const float* __restrict__ meb,
        const int* __restrict__ inv_pos, unsigned short* __restrict__ ea_csr,
        unsigned short* __restrict__ emX) {
    __shared__ float Wa[F_EDGE * F], Wm2[F_EDGE * F];    // 8 KB
    __shared__ float ert[F_EDGE][64];                    // 8 KB
    for (int i = threadIdx.x; i < F_EDGE * F; i += 256) {
        Wa[i] = aew[i]; Wm2[i] = mew[i];
    }
    int ebase = blockIdx.x * 64;
    for (int i = threadIdx.x; i < 512; i += 256) {
        int row = i >> 3, kq = i & 7;
        float4 v = *(const float4*)(edge_attr + (size_t)(ebase + row) * F_EDGE + kq * 4);
        ert[kq * 4 + 0][row] = v.x; ert[kq * 4 + 1][row] = v.y;
        ert[kq * 4 + 2][row] = v.z; ert[kq * 4 + 3][row] = v.w;
    }
    __syncthreads();
    int el = threadIdx.x >> 2;
    int jg = threadIdx.x & 3;
    float4 a0 = *(const float4*)(aeb + jg * 8), a1 = *(const float4*)(aeb + jg * 8 + 4);
    float4 m0 = *(const float4*)(meb + jg * 8), m1 = *(const float4*)(meb + jg * 8 + 4);
    for (int k = 0; k < F_EDGE; k++) {
        float ev = ert[k][el];
        float4 w0, w1;
        w0 = *(const float4*)(Wa + k * F + jg * 8); w1 = *(const float4*)(Wa + k * F + jg * 8 + 4);
        a0.x += ev * w0.x; a0.y += ev * w0.y; a0.z += ev * w0.z; a0.w += ev * w0.w;
        a1.x += ev * w1.x; a1.y += ev * w1.y; a1.z += ev * w1.z; a1.w += ev * w1.w;
        w0 = *(const float4*)(Wm2 + k * F + jg * 8); w1 = *(const float4*)(Wm2 + k * F + jg * 8 + 4);
        m0.x += ev * w0.x; m0.y += ev * w0.y; m0.z += ev * w0.z; m0.w += ev * w0.w;
        m1.x += ev * w1.x; m1.y += ev * w1.y; m1.z += ev * w1.z; m1.w += ev * w1.w;
    }
    int e = ebase + el;
    int p = inv_pos[e];
    size_t oa = (size_t)p * F + jg * 8;
    *(ushort4*)(ea_csr + oa) = pack4(a0);
    *(ushort4*)(ea_csr + oa + 4) = pack4(a1);
    int q = e % EQ, j = e / EQ;
    size_t om = (size_t)q * NHF + j * F + jg * 8;
    *(ushort4*)(emX + om) = pack4(m0);
    *(ushort4*)(emX + om + 4) = pack4(m1);
}

// ---- fused attention: one wave per dst node; logits + joint softmax ----
__global__ __launch_bounds__(256) void k_attn(const unsigned short* __restrict__ ea_csr,
        const unsigned short* __restrict__ xs, const unsigned short* __restrict__ xd,
        const int* __restrict__ srcp, const int* __restrict__ row_start,
        const int* __restrict__ counts, const int* __restrict__ csr_e,
        const float* __restrict__ dw, const float* __restrict__ db,
        float* __restrict__ alphaT) {
    __shared__ float lg[4][512];                    // 8 KB; items cap 512
    int wv = threadIdx.x >> 6, lane = threadIdx.x & 63;
    int n = blockIdx.x * 4 + wv;
    if (n >= N_NODES) return;
    int start = row_start[n];
    int items = counts[n] * 4;
    float4 wreg[8];
#pragma unroll
    for (int q = 0; q < 8; q++) wreg[q] = *(const float4*)(dw + q * 4);
    float dbv = db[0];
    const unsigned short* xsr = xs + (size_t)n * NHF;
    float m = -1e30f;
    for (int i = lane; i < items; i += 64) {
        int ii = i >> 2, hh = i & 3;
        int p = start + ii;
        int s = srcp[p];
        const unsigned short* ear = ea_csr + (size_t)p * F;
        const unsigned short* xsh = xsr + hh * F;
        const unsigned short* xdh = xd + (size_t)s * NHF + hh * F;
        float acc = 0.f;
#pragma unroll
        for (int q = 0; q < 8; q++) {
            ushort4 ue = *(const ushort4*)(ear + q * 4);
            ushort4 ua = *(const ushort4*)(xsh + q * 4);
            ushort4 ub = *(const ushort4*)(xdh + q * 4);
            acc += fmaxf(bf2f(ua.x) + bf2f(ub.x) + bf2f(ue.x), 0.f) * wreg[q].x;
            acc += fmaxf(bf2f(ua.y) + bf2f(ub.y) + bf2f(ue.y), 0.f) * wreg[q].y;
            acc += fmaxf(bf2f(ua.z) + bf2f(ub.z) + bf2f(ue.z), 0.f) * wreg[q].z;
            acc += fmaxf(bf2f(ua.w) + bf2f(ub.w) + bf2f(ue.w), 0.f) * wreg[q].w;
        }
        float l = acc + dbv;
        lg[wv][i] = l;
        m = fmaxf(m, l);
    }
#pragma unroll
    for (int d = 1; d < 64; d <<= 1) m = fmaxf(m, __shfl_xor(m, d));
    float ssum = 0.f;
    for (int i = lane; i < items; i += 64) ssum += __expf(lg[wv][i] - m);
#pragma unroll
    for (int d = 1; d < 64; d <<= 1) ssum += __shfl_xor(ssum, d);
    float inv = 1.f / (ssum + 1e-8f);
    for (int i = lane; i < items; i += 64) {
        int ii = i >> 2, hh = i & 3;
        int e = csr_e[start + ii];
        float a = __expf(lg[wv][i] - m) * inv;
        alphaT[(size_t)(e % EQ) * 16 + hh * 4 + (e / EQ)] = a;
    }
}

// ---- q-major message build (see R6 notes) ----
__global__ __launch_bounds__(256) void k_msgq(const float* __restrict__ alphaT,
        const unsigned short* __restrict__ emX, const unsigned short* __restrict__ xm,
        const int* __restrict__ dst, const int* __restrict__ inv_pos,
        unsigned short* __restrict__ ems_csr) {
    int g = blockIdx.x * 8 + (threadIdx.x >> 5);
    if (g >= EQ) return;
    int f = threadIdx.x & 31;
    const float4* a4 = (const float4*)(alphaT + (size_t)g * 16);
    float4 ac[4] = {a4[0], a4[1], a4[2], a4[3]};    // ac[c] = alphas over j
    int4 dj = make_int4(dst[g], dst[g + EQ], dst[g + 2 * EQ], dst[g + 3 * EQ]);
    float out[4] = {0.f, 0.f, 0.f, 0.f};
#pragma unroll
    for (int j = 0; j < 4; j++) {
        int d = (j == 0) ? dj.x : (j == 1) ? dj.y : (j == 2) ? dj.z : dj.w;
        float emv = bf2f(emX[(size_t)g * NHF + j * F + f]);
        const unsigned short* xr = xm + (size_t)d * NHF + f;
#pragma unroll
        for (int c = 0; c < 4; c++) {
            float a = (j == 0) ? ac[c].x : (j == 1) ? ac[c].y
                    : (j == 2) ? ac[c].z : ac[c].w;
            out[c] += a * (bf2f(xr[c * F]) + emv);
        }
    }
    const int4 pos = *(const int4*)(inv_pos + (size_t)g * 4);
#pragma unroll
    for (int c = 0; c < 4; c++) {
        int p = (c == 0) ? pos.x : (c == 1) ? pos.y : (c == 2) ? pos.z : pos.w;
        ems_csr[(size_t)p * F + f] = f2bf(out[c]);
    }
}

// ---- combine, retiled: 64 flat rows (16 nodes)/block; h transposed in LDS,
// W loaded once/block, ems_csr pulled via 16B loads, coalesced epilogue ----
__global__ __launch_bounds__(256) void k_combine(const float* __restrict__ h,
        const unsigned short* __restrict__ ems_csr, const int* __restrict__ row_start,
        const int* __restrict__ counts, const float* __restrict__ atom_in,
        const float* __restrict__ wn, const float* __restrict__ bn,
        float* __restrict__ hout, float* __restrict__ final_out, int is_final) {
    __shared__ float W[F * F];                           // 4 KB
    __shared__ float hrt[F][64];                         // 8 KB
    __shared__ float smv[64][F + 4];                     // 9 KB (final epilogue)
    for (int i = threadIdx.x; i < F * F; i += 256) W[i] = wn[i];
    int rbase = blockIdx.x * 64;
    for (int i = threadIdx.x; i < 512; i += 256) {
        int row = i >> 3, kq = i & 7;
        float4 v = *(const float4*)(h + (size_t)(rbase + row) * F + kq * 4);
        hrt[kq * 4 + 0][row] = v.x; hrt[kq * 4 + 1][row] = v.y;
        hrt[kq * 4 + 2][row] = v.z; hrt[kq * 4 + 3][row] = v.w;
    }
    __syncthreads();
    int rl = threadIdx.x >> 2;                           // flat row local 0..63
    int jg = threadIdx.x & 3;                            // 8-col group
    float4 a0 = *(const float4*)(bn + jg * 8);
    float4 a1 = *(const float4*)(bn + jg * 8 + 4);
    for (int k = 0; k < F; k++) {
        float hv = hrt[k][rl];
        float4 w0 = *(const float4*)(W + k * F + jg * 8);
        float4 w1 = *(const float4*)(W + k * F + jg * 8 + 4);
        a0.x += hv * w0.x; a0.y += hv * w0.y; a0.z += hv * w0.z; a0.w += hv * w0.w;
        a1.x += hv * w1.x; a1.y += hv * w1.y; a1.z += hv * w1.z; a1.w += hv * w1.w;
    }
    int m = rbase + rl;                                  // flat row of (N*H,F)
    float4 g0 = make_float4(0.f, 0.f, 0.f, 0.f);
    float4 g1 = make_float4(0.f, 0.f, 0.f, 0.f);
    if (m < N_NODES) {                                   // rows >= N get no msgs
        int st = row_start[m], deg = counts[m];
        const unsigned short* er = ems_csr + (size_t)st * F + jg * 8;
        int p = 0;
        for (; p + 2 <= deg; p += 2) {
            ushort4 u0 = *(const ushort4*)(er);
            ushort4 u1 = *(const ushort4*)(er + 4);
            ushort4 v0 = *(const ushort4*)(er + F);
            ushort4 v1 = *(const ushort4*)(er + F + 4);
            g0.x += bf2f(u0.x) + bf2f(v0.x); g0.y += bf2f(u0.y) + bf2f(v0.y);
            g0.z += bf2f(u0.z) + bf2f(v0.z); g0.w += bf2f(u0.w) + bf2f(v0.w);
            g1.x += bf2f(u1.x) + bf2f(v1.x); g1.y += bf2f(u1.y) + bf2f(v1.y);
            g1.z += bf2f(u1.z) + bf2f(v1.z); g1.w += bf2f(u1.w) + bf2f(v1.w);
            er += 2 * F;
        }
        if (p < deg) {
            ushort4 u0 = *(const ushort4*)(er);
            ushort4 u1 = *(const ushort4*)(er + 4);
            g0.x += bf2f(u0.x); g0.y += bf2f(u0.y);
            g0.z += bf2f(u0.z); g0.w += bf2f(u0.w);
            g1.x += bf2f(u1.x); g1.y += bf2f(u1.y);
            g1.z += bf2f(u1.z); g1.w += bf2f(u1.w);
        }
    }
    size_t idx = (size_t)m * F + jg * 8;                 // == n*NHF+head*F+jg*8
    float4 t0 = *(const float4*)(atom_in + idx);
    float4 t1 = *(const float4*)(atom_in + idx + 4);
    float4 v0, v1;
    v0.x = fmaxf(a0.x + g0.x + t0.x, 0.f); v0.y = fmaxf(a0.y + g0.y + t0.y, 0.f);
    v0.z = fmaxf(a0.z + g0.z + t0.z, 0.f); v0.w = fmaxf(a0.w + g0.w + t0.w, 0.f);
    v1.x = fmaxf(a1.x + g1.x + t1.x, 0.f); v1.y = fmaxf(a1.y + g1.y + t1.y, 0.f);
    v1.z = fmaxf(a1.z + g1.z + t1.z, 0.f); v1.w = fmaxf(a1.w + g1.w + t1.w, 0.f);
    if (!is_final) {
        *(float4*)(hout + idx) = v0;
        *(float4*)(hout + idx + 4) = v1;
    } else {
        *(float4*)(&smv[rl][jg * 8]) = v0;
        *(float4*)(&smv[rl][jg * 8 + 4]) = v1;
        __syncthreads();
#pragma unroll
        for (int it = 0; it < 2; it++) {
            int oi = threadIdx.x + it * 256;
            int nl = oi >> 5, f = oi & 31;               // node-local, feature
            float o = 0.25f * (smv[nl * 4 + 0][f] + smv[nl * 4 + 1][f] +
                               smv[nl * 4 + 2][f] + smv[nl * 4 + 3][f]);
            final_out[((size_t)(rbase >> 2) + nl) * F + f] = o;
        }
    }
}

extern "C" void kernel_launch(void* const* d_in, const int* in_sizes, int n_in,
                              void* d_out, int out_size, void* d_ws, size_t ws_size,
                              hipStream_t stream) {
    const float* x         = (const float*)d_in[0];
    const float* edge_attr = (const float*)d_in[1];
    const int*   eidx      = (const int*)d_in[2];
    const int*   src       = eidx;
    const int*   dst       = eidx + N_EDGES;
    const float* atom_w    = (const float*)d_in[3];
    const float* atom_b    = (const float*)d_in[4];
    const float* asw = (const float*)d_in[5],  *asb = (const float*)d_in[6];
    const float* adw = (const float*)d_in[7],  *adb = (const float*)d_in[8];
    const float* aew = (const float*)d_in[9],  *aeb = (const float*)d_in[10];
    const float* dww = (const float*)d_in[11], *dwb = (const float*)d_in[12];
    const float* mdw = (const float*)d_in[13], *mdb = (const float*)d_in[14];
    const float* mew = (const float*)d_in[15], *meb = (const float*)d_in[16];
    const float* wnw = (const float*)d_in[17], *wnb = (const float*)d_in[18];
    float* out = (float*)d_out;

    float* ws = (float*)d_ws;
    size_t off = 0;
    float* atom_in = ws + off; off += (size_t)N_NODES * NHF;
    float* hbuf    = ws + off; off += (size_t)N_NODES * NHF;
    unsigned short* xs_bf  = (unsigned short*)(ws + off); off += (size_t)N_NODES * NHF / 2;
    unsigned short* xd_bf  = (unsigned short*)(ws + off); off += (size_t)N_NODES * NHF / 2;
    unsigned short* xm_bf  = (unsigned short*)(ws + off); off += (size_t)N_NODES * NHF / 2;
    unsigned short* ea_csr = (unsigned short*)(ws + off); off += (size_t)N_EDGES * F / 2;
    unsigned short* emX    = (unsigned short*)(ws + off); off += (size_t)N_EDGES * F / 2;
    unsigned short* ems    = (unsigned short*)(ws + off); off += (size_t)N_EDGES * F / 2;
    float* alphaT  = ws + off; off += (size_t)N_EDGES * H;
    int* counts    = (int*)(ws + off); off += N_NODES;
    int* row_start = (int*)(ws + off); off += N_NODES;
    int* cursor    = (int*)(ws + off); off += N_NODES;
    int* excl      = (int*)(ws + off); off += N_NODES;
    int* bsum      = (int*)(ws + off); off += 128;
    int* csr_e     = (int*)(ws + off); off += N_EDGES;
    int* srcp      = (int*)(ws + off); off += N_EDGES;
    int* inv_pos   = (int*)(ws + off); off += N_EDGES;

    // ---- CSR build (dst is layer-invariant) ----
    hipMemsetAsync(counts, 0, N_NODES * sizeof(int), stream);
    k_hist <<<(N_EDGES + 255) / 256, 256, 0, stream>>>(dst, counts);
    k_scan1<<<N_SCAN_BLKS, SCAN_BLK, 0, stream>>>(counts, excl, bsum);
    k_scan2<<<1, 128, 0, stream>>>(bsum);
    k_scan3<<<N_SCAN_BLKS, SCAN_BLK, 0, stream>>>(excl, bsum, row_start, cursor);
    k_fill <<<(N_EDGES + 255) / 256, 256, 0, stream>>>(src, dst, cursor, csr_e,
                                                       srcp, inv_pos);

    k_atom<<<(N_NODES + 31) / 32, 256, 0, stream>>>(x, atom_w, atom_b, atom_in);

    for (int l = 0; l < 2; l++) {
        const float* hin  = (l == 0) ? atom_in : hbuf;
        float*       hout = hbuf;
        int is_final = (l == 1);
        k_nodelin3<<<(N_NODES * H) / 64, 256, 0, stream>>>(
            hin, asw + l * F * F, asb + l * F, adw + l * F * F, adb + l * F,
            mdw + l * F * F, mdb + l * F, xs_bf, xd_bf, xm_bf);
        k_edgepair<<<N_EDGES / 64, 256, 0, stream>>>(
            edge_attr, aew + l * F_EDGE * F, aeb + l * F,
            mew + l * F_EDGE * F, meb + l * F, inv_pos, ea_csr, emX);
        k_attn<<<(N_NODES + 3) / 4, 256, 0, stream>>>(
            ea_csr, xs_bf, xd_bf, srcp, row_start, counts, csr_e,
            dww + l * F, dwb + l, alphaT);
        k_msgq<<<(EQ + 7) / 8, 256, 0, stream>>>(alphaT, emX, xm_bf, dst,
                                                 inv_pos, ems);
        k_combine<<<(N_NODES * H) / 64, 256, 0, stream>>>(
            hin, ems, row_start, counts, atom_in, wnw + l * F * F,
            wnb + l * F, hout, out, is_final);
    }
}

// Round 8
// 552.722 us; speedup vs baseline: 2.4121x; 1.0554x over previous
//
#include <hip/hip_runtime.h>

#define N_NODES 50000
#define N_EDGES 400000
#define EQ      100000   // N_EDGES/4
#define N_TILES 25000    // N_EDGES/16
#define F_IN    128
#define F_EDGE  32
#define F       32
#define H       4
#define NHF     128   // H*F

#define SCAN_BLK 512
#define N_SCAN_BLKS ((N_NODES + SCAN_BLK - 1) / SCAN_BLK)   // 98

typedef __attribute__((ext_vector_type(8))) short bf16x8;
typedef __attribute__((ext_vector_type(4))) float f32x4;

// ---- bf16 helpers (RNE) ----
__device__ __forceinline__ float bf2f(unsigned short u) {
    return __uint_as_float(((unsigned)u) << 16);
}
__device__ __forceinline__ unsigned short f2bf(float f) {
    unsigned u = __float_as_uint(f);
    return (unsigned short)((u + 0x7FFFu + ((u >> 16) & 1u)) >> 16);
}
__device__ __forceinline__ ushort4 pack4(float4 v) {
    return make_ushort4(f2bf(v.x), f2bf(v.y), f2bf(v.z), f2bf(v.w));
}

// ---- atom_in = relu(x @ atom_w + atom_b); 32 nodes/block ----
__global__ __launch_bounds__(256) void k_atom(const float* __restrict__ x,
                                              const float* __restrict__ w,
                                              const float* __restrict__ b,
                                              float* __restrict__ out) {
    __shared__ float wlds[F_IN * NHF];              // 64 KB
    __shared__ float xl[32 * F_IN];                 // 16 KB
    const float4* w4 = (const float4*)w;
    float4* wl4 = (float4*)wlds;
    for (int i = threadIdx.x; i < F_IN * NHF / 4; i += 256) wl4[i] = w4[i];
    int nb = blockIdx.x * 32;
    int nrows = min(32, N_NODES - nb);
    const float4* x4 = (const float4*)(x + (size_t)nb * F_IN);
    float4* xl4 = (float4*)xl;
    for (int i = threadIdx.x; i < nrows * F_IN / 4; i += 256) xl4[i] = x4[i];
    __syncthreads();
    int jg = threadIdx.x & 31;
    int nl = threadIdx.x >> 5;
    float4 bv = *(const float4*)(b + jg * 4);
    float4 acc[4] = {bv, bv, bv, bv};
    for (int k = 0; k < F_IN; k++) {
        float4 wv = *(const float4*)(wlds + k * NHF + jg * 4);
#pragma unroll
        for (int q = 0; q < 4; q++) {
            float xk = xl[(nl + 8 * q) * F_IN + k];
            acc[q].x += xk * wv.x; acc[q].y += xk * wv.y;
            acc[q].z += xk * wv.z; acc[q].w += xk * wv.w;
        }
    }
#pragma unroll
    for (int q = 0; q < 4; q++) {
        int n = nb + nl + 8 * q;
        if (n < N_NODES) {
            float4 a = acc[q];
            a.x = fmaxf(a.x, 0.f); a.y = fmaxf(a.y, 0.f);
            a.z = fmaxf(a.z, 0.f); a.w = fmaxf(a.w, 0.f);
            *(float4*)(out + (size_t)n * NHF + jg * 4) = a;
        }
    }
}

// ---- CSR build ----
__global__ __launch_bounds__(256) void k_hist(const int* __restrict__ dst,
                                              int* __restrict__ counts) {
    int e = blockIdx.x * 256 + threadIdx.x;
    if (e < N_EDGES) atomicAdd(counts + dst[e], 1);
}

__global__ __launch_bounds__(SCAN_BLK) void k_scan1(const int* __restrict__ counts,
        int* __restrict__ excl, int* __restrict__ bsum) {
    __shared__ int s[SCAN_BLK];
    int i = blockIdx.x * SCAN_BLK + threadIdx.x;
    int v = (i < N_NODES) ? counts[i] : 0;
    s[threadIdx.x] = v;
    __syncthreads();
    for (int d = 1; d < SCAN_BLK; d <<= 1) {
        int t = (threadIdx.x >= d) ? s[threadIdx.x - d] : 0;
        __syncthreads();
        s[threadIdx.x] += t;
        __syncthreads();
    }
    if (i < N_NODES) excl[i] = s[threadIdx.x] - v;
    if (threadIdx.x == SCAN_BLK - 1) bsum[blockIdx.x] = s[SCAN_BLK - 1];
}

__global__ __launch_bounds__(128) void k_scan2(int* __restrict__ bsum) {
    __shared__ int s[128];
    int v = (threadIdx.x < N_SCAN_BLKS) ? bsum[threadIdx.x] : 0;
    s[threadIdx.x] = v;
    __syncthreads();
    for (int d = 1; d < 128; d <<= 1) {
        int t = (threadIdx.x >= d) ? s[threadIdx.x - d] : 0;
        __syncthreads();
        s[threadIdx.x] += t;
        __syncthreads();
    }
    if (threadIdx.x < N_SCAN_BLKS) bsum[threadIdx.x] = s[threadIdx.x] - v;
}

__global__ __launch_bounds__(SCAN_BLK) void k_scan3(const int* __restrict__ excl,
        const int* __restrict__ bsum, int* __restrict__ row_start,
        int* __restrict__ cursor) {
    int i = blockIdx.x * SCAN_BLK + threadIdx.x;
    if (i < N_NODES) {
        int v = excl[i] + bsum[blockIdx.x];
        row_start[i] = v;
        cursor[i] = v;
    }
}

__global__ __launch_bounds__(256) void k_fill(const int* __restrict__ src,
        const int* __restrict__ dst, int* __restrict__ cursor,
        int* __restrict__ csr_e, int* __restrict__ srcp,
        int* __restrict__ inv_pos) {
    int e = blockIdx.x * 256 + threadIdx.x;
    if (e < N_EDGES) {
        int pos = atomicAdd(cursor + dst[e], 1);
        csr_e[pos] = e;
        srcp[pos] = src[e];
        inv_pos[e] = pos;
    }
}

// ---- edge_attr fp32 -> bf16 in MFMA A-fragment tile layout:
// eaA[tile][lane][j] = edge_attr[tile*16 + (lane&15)][(lane>>4)*8 + j] ----
__global__ __launch_bounds__(256) void k_cast(const float* __restrict__ edge_attr,
                                              unsigned short* __restrict__ eaA) {
    int t = blockIdx.x * 256 + threadIdx.x;         // over N_TILES*64
    int tile = t >> 6, lane = t & 63;
    int m = lane & 15, kq = lane >> 4;
    const float4* s = (const float4*)(edge_attr + ((size_t)tile * 16 + m) * F_EDGE + kq * 8);
    float4 v0 = s[0], v1 = s[1];
    *(ushort4*)(eaA + (size_t)t * 8)     = pack4(v0);
    *(ushort4*)(eaA + (size_t)t * 8 + 4) = pack4(v1);
}

// ---- MFMA edge linears: ea = E@Wa+ba (csr order), em = E@Wm+bm ([q][j][f]).
// 4 waves/block, 4 tiles (16 edges each) per wave. B-frags in registers. ----
__global__ __launch_bounds__(256) void k_edgepair(const unsigned short* __restrict__ eaA,
        const float* __restrict__ aew, const float* __restrict__ aeb,
        const float* __restrict__ mew, const float* __restrict__ meb,
        const int* __restrict__ inv_pos, unsigned short* __restrict__ ea_csr,
        unsigned short* __restrict__ emX) {
    __shared__ unsigned short stg[4][2][16][40];    // [wave][matrix][row][32+8 pad]
    int wv = threadIdx.x >> 6, lane = threadIdx.x & 63;
    int nn = lane & 15, kq = lane >> 4;
    // B fragments: B[k=(kq*8+j)][n] ; n = nn (lo half) or nn+16 (hi half)
    bf16x8 Ba0, Ba1, Bm0, Bm1;
#pragma unroll
    for (int j = 0; j < 8; j++) {
        int k = kq * 8 + j;
        Ba0[j] = (short)f2bf(aew[k * F + nn]);
        Ba1[j] = (short)f2bf(aew[k * F + 16 + nn]);
        Bm0[j] = (short)f2bf(mew[k * F + nn]);
        Bm1[j] = (short)f2bf(mew[k * F + 16 + nn]);
    }
    float ba0 = aeb[nn], ba1 = aeb[16 + nn];
    float bm0 = meb[nn], bm1 = meb[16 + nn];
    for (int tt = 0; tt < 4; tt++) {
        int tile = blockIdx.x * 16 + wv * 4 + tt;   // wave-uniform guard
        if (tile >= N_TILES) break;
        bf16x8 A = *(const bf16x8*)(eaA + ((size_t)tile * 64 + lane) * 8);
        f32x4 c0 = {ba0, ba0, ba0, ba0};
        f32x4 c1 = {ba1, ba1, ba1, ba1};
        f32x4 c2 = {bm0, bm0, bm0, bm0};
        f32x4 c3 = {bm1, bm1, bm1, bm1};
        c0 = __builtin_amdgcn_mfma_f32_16x16x32_bf16(A, Ba0, c0, 0, 0, 0);
        c1 = __builtin_amdgcn_mfma_f32_16x16x32_bf16(A, Ba1, c1, 0, 0, 0);
        c2 = __builtin_amdgcn_mfma_f32_16x16x32_bf16(A, Bm0, c2, 0, 0, 0);
        c3 = __builtin_amdgcn_mfma_f32_16x16x32_bf16(A, Bm1, c3, 0, 0, 0);
        // C layout: col = lane&15, row = (lane>>4)*4 + reg  [verified m89]
#pragma unroll
        for (int r = 0; r < 4; r++) {
            int row = kq * 4 + r;
            stg[wv][0][row][nn]      = f2bf(c0[r]);
            stg[wv][0][row][nn + 16] = f2bf(c1[r]);
            stg[wv][1][row][nn]      = f2bf(c2[r]);
            stg[wv][1][row][nn + 16] = f2bf(c3[r]);
        }
        __builtin_amdgcn_s_waitcnt(0);              // LDS writes visible wave-wide
        // writeback: it=0 -> ea rows (csr scatter), it=1 -> em rows ([q][j][f])
#pragma unroll
        for (int it = 0; it < 2; it++) {
            int rg = (it == 0) ? (lane >> 2) : (16 + (lane >> 2));
            int seg = lane & 3;
            int mat = rg >> 4, r = rg & 15;
            int e = tile * 16 + r;
            uint4 v = *(uint4*)&stg[wv][mat][r][seg * 8];
            if (mat == 0) {
                int p = inv_pos[e];
                *(uint4*)(ea_csr + (size_t)p * F + seg * 8) = v;
            } else {
                int q = e % EQ, j = e / EQ;
                *(uint4*)(emX + (size_t)q * NHF + j * F + seg * 8) = v;
            }
        }
    }
}

// ---- xs,xd,xm = h @ {Ws,Wd,Wm} + b -> bf16 outputs ----
__global__ __launch_bounds__(256) void k_nodelin3(const float* __restrict__ h,
        const float* __restrict__ ws, const float* __restrict__ bs,
        const float* __restrict__ wd, const float* __restrict__ bd,
        const float* __restrict__ wm, const float* __restrict__ bm,
        unsigned short* __restrict__ xs, unsigned short* __restrict__ xd,
        unsigned short* __restrict__ xm) {
    __shared__ float Ws[F * F], Wd[F * F], Wm[F * F];
    __shared__ float hrt[F][64];
    for (int i = threadIdx.x; i < F * F; i += 256) {
        Ws[i] = ws[i]; Wd[i] = wd[i]; Wm[i] = wm[i];
    }
    int rbase = blockIdx.x * 64;
    for (int i = threadIdx.x; i < 512; i += 256) {
        int row = i >> 3, kq = i & 7;
        float4 v = *(const float4*)(h + (size_t)(rbase + row) * F + kq * 4);
        hrt[kq * 4 + 0][row] = v.x; hrt[kq * 4 + 1][row] = v.y;
        hrt[kq * 4 + 2][row] = v.z; hrt[kq * 4 + 3][row] = v.w;
    }
    __syncthreads();
    int rl = threadIdx.x >> 2;
    int jg = threadIdx.x & 3;
    float4 s0 = *(const float4*)(bs + jg * 8), s1 = *(const float4*)(bs + jg * 8 + 4);
    float4 d0 = *(const float4*)(bd + jg * 8), d1 = *(const float4*)(bd + jg * 8 + 4);
    float4 m0 = *(const float4*)(bm + jg * 8), m1 = *(const float4*)(bm + jg * 8 + 4);
    for (int k = 0; k < F; k++) {
        float hv = hrt[k][rl];
        float4 a, b2;
        a = *(const float4*)(Ws + k * F + jg * 8); b2 = *(const float4*)(Ws + k * F + jg * 8 + 4);
        s0.x += hv * a.x; s0.y += hv * a.y; s0.z += hv * a.z; s0.w += hv * a.w;
        s1.x += hv * b2.x; s1.y += hv * b2.y; s1.z += hv * b2.z; s1.w += hv * b2.w;
        a = *(const float4*)(Wd + k * F + jg * 8); b2 = *(const float4*)(Wd + k * F + jg * 8 + 4);
        d0.x += hv * a.x; d0.y += hv * a.y; d0.z += hv * a.z; d0.w += hv * a.w;
        d1.x += hv * b2.x; d1.y += hv * b2.y; d1.z += hv * b2.z; d1.w += hv * b2.w;
        a = *(const float4*)(Wm + k * F + jg * 8); b2 = *(const float4*)(Wm + k * F + jg * 8 + 4);
        m0.x += hv * a.x; m0.y += hv * a.y; m0.z += hv * a.z; m0.w += hv * a.w;
        m1.x += hv * b2.x; m1.y += hv * b2.y; m1.z += hv * b2.z; m1.w += hv * b2.w;
    }
    size_t o = (size_t)(rbase + rl) * F + jg * 8;
    *(ushort4*)(xs + o) = pack4(s0); *(ushort4*)(xs + o + 4) = pack4(s1);
    *(ushort4*)(xd + o) = pack4(d0); *(ushort4*)(xd + o + 4) = pack4(d1);
    *(ushort4*)(xm + o) = pack4(m0); *(ushort4*)(xm + o + 4) = pack4(m1);
}

// ---- fused attention: one wave per dst node; logits + joint softmax ----
__global__ __launch_bounds__(256) void k_attn(const unsigned short* __restrict__ ea_csr,
        const unsigned short* __restrict__ xs, const unsigned short* __restrict__ xd,
        const int* __restrict__ srcp, const int* __restrict__ row_start,
        const int* __restrict__ counts, const int* __restrict__ csr_e,
        const float* __restrict__ dw, const float* __restrict__ db,
        float* __restrict__ alphaT) {
    __shared__ float lg[4][512];                    // 8 KB; items cap 512
    int wv = threadIdx.x >> 6, lane = threadIdx.x & 63;
    int n = blockIdx.x * 4 + wv;
    if (n >= N_NODES) return;
    int start = row_start[n];
    int items = counts[n] * 4;
    float4 wreg[8];
#pragma unroll
    for (int q = 0; q < 8; q++) wreg[q] = *(const float4*)(dw + q * 4);
    float dbv = db[0];
    const unsigned short* xsr = xs + (size_t)n * NHF;
    float m = -1e30f;
    for (int i = lane; i < items; i += 64) {
        int ii = i >> 2, hh = i & 3;
        int p = start + ii;
        int s = srcp[p];
        const unsigned short* ear = ea_csr + (size_t)p * F;
        const unsigned short* xsh = xsr + hh * F;
        const unsigned short* xdh = xd + (size_t)s * NHF + hh * F;
        float acc = 0.f;
#pragma unroll
        for (int q = 0; q < 8; q++) {
            ushort4 ue = *(const ushort4*)(ear + q * 4);
            ushort4 ua = *(const ushort4*)(xsh + q * 4);
            ushort4 ub = *(const ushort4*)(xdh + q * 4);
            acc += fmaxf(bf2f(ua.x) + bf2f(ub.x) + bf2f(ue.x), 0.f) * wreg[q].x;
            acc += fmaxf(bf2f(ua.y) + bf2f(ub.y) + bf2f(ue.y), 0.f) * wreg[q].y;
            acc += fmaxf(bf2f(ua.z) + bf2f(ub.z) + bf2f(ue.z), 0.f) * wreg[q].z;
            acc += fmaxf(bf2f(ua.w) + bf2f(ub.w) + bf2f(ue.w), 0.f) * wreg[q].w;
        }
        float l = acc + dbv;
        lg[wv][i] = l;
        m = fmaxf(m, l);
    }
#pragma unroll
    for (int d = 1; d < 64; d <<= 1) m = fmaxf(m, __shfl_xor(m, d));
    float ssum = 0.f;
    for (int i = lane; i < items; i += 64) ssum += __expf(lg[wv][i] - m);
#pragma unroll
    for (int d = 1; d < 64; d <<= 1) ssum += __shfl_xor(ssum, d);
    float inv = 1.f / (ssum + 1e-8f);
    for (int i = lane; i < items; i += 64) {
        int ii = i >> 2, hh = i & 3;
        int e = csr_e[start + ii];
        float a = __expf(lg[wv][i] - m) * inv;
        alphaT[(size_t)(e % EQ) * 16 + hh * 4 + (e / EQ)] = a;
    }
}

// ---- q-major message build ----
__global__ __launch_bounds__(256) void k_msgq(const float* __restrict__ alphaT,
        const unsigned short* __restrict__ emX, const unsigned short* __restrict__ xm,
        const int* __restrict__ dst, const int* __restrict__ inv_pos,
        unsigned short* __restrict__ ems_csr) {
    int g = blockIdx.x * 8 + (threadIdx.x >> 5);
    if (g >= EQ) return;
    int f = threadIdx.x & 31;
    const float4* a4 = (const float4*)(alphaT + (size_t)g * 16);
    float4 ac[4] = {a4[0], a4[1], a4[2], a4[3]};    // ac[c] = alphas over j
    int4 dj = make_int4(dst[g], dst[g + EQ], dst[g + 2 * EQ], dst[g + 3 * EQ]);
    float out[4] = {0.f, 0.f, 0.f, 0.f};
#pragma unroll
    for (int j = 0; j < 4; j++) {
        int d = (j == 0) ? dj.x : (j == 1) ? dj.y : (j == 2) ? dj.z : dj.w;
        float emv = bf2f(emX[(size_t)g * NHF + j * F + f]);
        const unsigned short* xr = xm + (size_t)d * NHF + f;
#pragma unroll
        for (int c = 0; c < 4; c++) {
            float a = (j == 0) ? ac[c].x : (j == 1) ? ac[c].y
                    : (j == 2) ? ac[c].z : ac[c].w;
            out[c] += a * (bf2f(xr[c * F]) + emv);
        }
    }
    const int4 pos = *(const int4*)(inv_pos + (size_t)g * 4);
#pragma unroll
    for (int c = 0; c < 4; c++) {
        int p = (c == 0) ? pos.x : (c == 1) ? pos.y : (c == 2) ? pos.z : pos.w;
        ems_csr[(size_t)p * F + f] = f2bf(out[c]);
    }
}

// ---- combine, retiled: 64 flat rows (16 nodes)/block ----
__global__ __launch_bounds__(256) void k_combine(const float* __restrict__ h,
        const unsigned short* __restrict__ ems_csr, const int* __restrict__ row_start,
        const int* __restrict__ counts, const float* __restrict__ atom_in,
        const float* __restrict__ wn, const float* __restrict__ bn,
        float* __restrict__ hout, float* __restrict__ final_out, int is_final) {
    __shared__ float W[F * F];                           // 4 KB
    __shared__ float hrt[F][64];                         // 8 KB
    __shared__ float smv[64][F + 4];                     // 9 KB (final epilogue)
    for (int i = threadIdx.x; i < F * F; i += 256) W[i] = wn[i];
    int rbase = blockIdx.x * 64;
    for (int i = threadIdx.x; i < 512; i += 256) {
        int row = i >> 3, kq = i & 7;
        float4 v = *(const float4*)(h + (size_t)(rbase + row) * F + kq * 4);
        hrt[kq * 4 + 0][row] = v.x; hrt[kq * 4 + 1][row] = v.y;
        hrt[kq * 4 + 2][row] = v.z; hrt[kq * 4 + 3][row] = v.w;
    }
    __syncthreads();
    int rl = threadIdx.x >> 2;                           // flat row local 0..63
    int jg = threadIdx.x & 3;                            // 8-col group
    float4 a0 = *(const float4*)(bn + jg * 8);
    float4 a1 = *(const float4*)(bn + jg * 8 + 4);
    for (int k = 0; k < F; k++) {
        float hv = hrt[k][rl];
        float4 w0 = *(const float4*)(W + k * F + jg * 8);
        float4 w1 = *(const float4*)(W + k * F + jg * 8 + 4);
        a0.x += hv * w0.x; a0.y += hv * w0.y; a0.z += hv * w0.z; a0.w += hv * w0.w;
        a1.x += hv * w1.x; a1.y += hv * w1.y; a1.z += hv * w1.z; a1.w += hv * w1.w;
    }
    int m = rbase + rl;                                  // flat row of (N*H,F)
    float4 g0 = make_float4(0.f, 0.f, 0.f, 0.f);
    float4 g1 = make_float4(0.f, 0.f, 0.f, 0.f);
    if (m < N_NODES) {                                   // rows >= N get no msgs
        int st = row_start[m], deg = counts[m];
        const unsigned short* er = ems_csr + (size_t)st * F + jg * 8;
        int p = 0;
        for (; p + 2 <= deg; p += 2) {
            ushort4 u0 = *(const ushort4*)(er);
            ushort4 u1 = *(const ushort4*)(er + 4);
            ushort4 v0 = *(const ushort4*)(er + F);
            ushort4 v1 = *(const ushort4*)(er + F + 4);
            g0.x += bf2f(u0.x) + bf2f(v0.x); g0.y += bf2f(u0.y) + bf2f(v0.y);
            g0.z += bf2f(u0.z) + bf2f(v0.z); g0.w += bf2f(u0.w) + bf2f(v0.w);
            g1.x += bf2f(u1.x) + bf2f(v1.x); g1.y += bf2f(u1.y) + bf2f(v1.y);
            g1.z += bf2f(u1.z) + bf2f(v1.z); g1.w += bf2f(u1.w) + bf2f(v1.w);
            er += 2 * F;
        }
        if (p < deg) {
            ushort4 u0 = *(const ushort4*)(er);
            ushort4 u1 = *(const ushort4*)(er + 4);
            g0.x += bf2f(u0.x); g0.y += bf2f(u0.y);
            g0.z += bf2f(u0.z); g0.w += bf2f(u0.w);
            g1.x += bf2f(u1.x); g1.y += bf2f(u1.y);
            g1.z += bf2f(u1.z); g1.w += bf2f(u1.w);
        }
    }
    size_t idx = (size_t)m * F + jg * 8;                 // == n*NHF+head*F+jg*8
    float4 t0 = *(const float4*)(atom_in + idx);
    float4 t1 = *(const float4*)(atom_in + idx + 4);
    float4 v0, v1;
    v0.x = fmaxf(a0.x + g0.x + t0.x, 0.f); v0.y = fmaxf(a0.y + g0.y + t0.y, 0.f);
    v0.z = fmaxf(a0.z + g0.z + t0.z, 0.f); v0.w = fmaxf(a0.w + g0.w + t0.w, 0.f);
    v1.x = fmaxf(a1.x + g1.x + t1.x, 0.f); v1.y = fmaxf(a1.y + g1.y + t1.y, 0.f);
    v1.z = fmaxf(a1.z + g1.z + t1.z, 0.f); v1.w = fmaxf(a1.w + g1.w + t1.w, 0.f);
    if (!is_final) {
        *(float4*)(hout + idx) = v0;
        *(float4*)(hout + idx + 4) = v1;
    } else {
        *(float4*)(&smv[rl][jg * 8]) = v0;
        *(float4*)(&smv[rl][jg * 8 + 4]) = v1;
        __syncthreads();
#pragma unroll
        for (int it = 0; it < 2; it++) {
            int oi = threadIdx.x + it * 256;
            int nl = oi >> 5, f = oi & 31;               // node-local, feature
            float o = 0.25f * (smv[nl * 4 + 0][f] + smv[nl * 4 + 1][f] +
                               smv[nl * 4 + 2][f] + smv[nl * 4 + 3][f]);
            final_out[((size_t)(rbase >> 2) + nl) * F + f] = o;
        }
    }
}

extern "C" void kernel_launch(void* const* d_in, const int* in_sizes, int n_in,
                              void* d_out, int out_size, void* d_ws, size_t ws_size,
                              hipStream_t stream) {
    const float* x         = (const float*)d_in[0];
    const float* edge_attr = (const float*)d_in[1];
    const int*   eidx      = (const int*)d_in[2];
    const int*   src       = eidx;
    const int*   dst       = eidx + N_EDGES;
    const float* atom_w    = (const float*)d_in[3];
    const float* atom_b    = (const float*)d_in[4];
    const float* asw = (const float*)d_in[5],  *asb = (const float*)d_in[6];
    const float* adw = (const float*)d_in[7],  *adb = (const float*)d_in[8];
    const float* aew = (const float*)d_in[9],  *aeb = (const float*)d_in[10];
    const float* dww = (const float*)d_in[11], *dwb = (const float*)d_in[12];
    const float* mdw = (const float*)d_in[13], *mdb = (const float*)d_in[14];
    const float* mew = (const float*)d_in[15], *meb = (const float*)d_in[16];
    const float* wnw = (const float*)d_in[17], *wnb = (const float*)d_in[18];
    float* out = (float*)d_out;

    float* ws = (float*)d_ws;
    size_t off = 0;
    float* atom_in = ws + off; off += (size_t)N_NODES * NHF;
    float* hbuf    = ws + off; off += (size_t)N_NODES * NHF;
    unsigned short* xs_bf  = (unsigned short*)(ws + off); off += (size_t)N_NODES * NHF / 2;
    unsigned short* xd_bf  = (unsigned short*)(ws + off); off += (size_t)N_NODES * NHF / 2;
    unsigned short* xm_bf  = (unsigned short*)(ws + off); off += (size_t)N_NODES * NHF / 2;
    unsigned short* ea_csr = (unsigned short*)(ws + off); off += (size_t)N_EDGES * F / 2;
    unsigned short* emX    = (unsigned short*)(ws + off); off += (size_t)N_EDGES * F / 2;
    unsigned short* ems    = (unsigned short*)(ws + off); off += (size_t)N_EDGES * F / 2;
    unsigned short* eaA    = (unsigned short*)(ws + off); off += (size_t)N_EDGES * F_EDGE / 2;
    float* alphaT  = ws + off; off += (size_t)N_EDGES * H;
    int* counts    = (int*)(ws + off); off += N_NODES;
    int* row_start = (int*)(ws + off); off += N_NODES;
    int* cursor    = (int*)(ws + off); off += N_NODES;
    int* excl      = (int*)(ws + off); off += N_NODES;
    int* bsum      = (int*)(ws + off); off += 128;
    int* csr_e     = (int*)(ws + off); off += N_EDGES;
    int* srcp      = (int*)(ws + off); off += N_EDGES;
    int* inv_pos   = (int*)(ws + off); off += N_EDGES;

    // ---- CSR build (dst is layer-invariant) ----
    hipMemsetAsync(counts, 0, N_NODES * sizeof(int), stream);
    k_hist <<<(N_EDGES + 255) / 256, 256, 0, stream>>>(dst, counts);
    k_scan1<<<N_SCAN_BLKS, SCAN_BLK, 0, stream>>>(counts, excl, bsum);
    k_scan2<<<1, 128, 0, stream>>>(bsum);
    k_scan3<<<N_SCAN_BLKS, SCAN_BLK, 0, stream>>>(excl, bsum, row_start, cursor);
    k_fill <<<(N_EDGES + 255) / 256, 256, 0, stream>>>(src, dst, cursor, csr_e,
                                                       srcp, inv_pos);
    k_cast <<<(N_TILES * 64) / 256, 256, 0, stream>>>(edge_attr, eaA);

    k_atom<<<(N_NODES + 31) / 32, 256, 0, stream>>>(x, atom_w, atom_b, atom_in);

    for (int l = 0; l < 2; l++) {
        const float* hin  = (l == 0) ? atom_in : hbuf;
        float*       hout = hbuf;
        int is_final = (l == 1);
        k_nodelin3<<<(N_NODES * H) / 64, 256, 0, stream>>>(
            hin, asw + l * F * F, asb + l * F, adw + l * F * F, adb + l * F,
            mdw + l * F * F, mdb + l * F, xs_bf, xd_bf, xm_bf);
        k_edgepair<<<(N_TILES + 15) / 16, 256, 0, stream>>>(
            eaA, aew + l * F_EDGE * F, aeb + l * F,
            mew + l * F_EDGE * F, meb + l * F, inv_pos, ea_csr, emX);
        k_attn<<<(N_NODES + 3) / 4, 256, 0, stream>>>(
            ea_csr, xs_bf, xd_bf, srcp, row_start, counts, csr_e,
            dww + l * F, dwb + l, alphaT);
        k_msgq<<<(EQ + 7) / 8, 256, 0, stream>>>(alphaT, emX, xm_bf, dst,
                                                 inv_pos, ems);
        k_combine<<<(N_NODES * H) / 64, 256, 0, stream>>>(
            hin, ems, row_start, counts, atom_in, wnw + l * F * F,
            wnb + l * F, hout, out, is_final);
    }
}

// Round 9
// 533.524 us; speedup vs baseline: 2.4989x; 1.0360x over previous
//
#include <hip/hip_runtime.h>

#define N_NODES 50000
#define N_EDGES 400000
#define EQ      100000   // N_EDGES/4
#define N_TILES 25000    // N_EDGES/16
#define F_IN    128
#define F_EDGE  32
#define F       32
#define H       4
#define NHF     128   // H*F

#define SCAN_BLK 512
#define N_SCAN_BLKS ((N_NODES + SCAN_BLK - 1) / SCAN_BLK)   // 98

typedef __attribute__((ext_vector_type(8))) short bf16x8;
typedef __attribute__((ext_vector_type(4))) float f32x4;

// ---- bf16 helpers (RNE) ----
__device__ __forceinline__ float bf2f(unsigned short u) {
    return __uint_as_float(((unsigned)u) << 16);
}
__device__ __forceinline__ unsigned short f2bf(float f) {
    unsigned u = __float_as_uint(f);
    return (unsigned short)((u + 0x7FFFu + ((u >> 16) & 1u)) >> 16);
}
__device__ __forceinline__ ushort4 pack4(float4 v) {
    return make_ushort4(f2bf(v.x), f2bf(v.y), f2bf(v.z), f2bf(v.w));
}

// ---- atom_in = relu(x @ atom_w + atom_b) via MFMA. 4 waves/block, 16
// node-rows/wave, W bf16 transposed [n][k] in LDS (+8 pad = conflict-free
// b128 B-frag reads). A packed from fp32 x on the fly. ----
__global__ __launch_bounds__(256) void k_atom(const float* __restrict__ x,
                                              const float* __restrict__ w,
                                              const float* __restrict__ b,
                                              float* __restrict__ out) {
    __shared__ unsigned short Wt[NHF][F_IN + 8];    // [n][k], 34 KB
    for (int i = threadIdx.x; i < F_IN * NHF / 4; i += 256) {
        int k = i >> 5, ng = i & 31;                // 4 consecutive n per thread
        float4 v = *(const float4*)(w + (size_t)k * NHF + ng * 4);
        Wt[ng * 4 + 0][k] = f2bf(v.x); Wt[ng * 4 + 1][k] = f2bf(v.y);
        Wt[ng * 4 + 2][k] = f2bf(v.z); Wt[ng * 4 + 3][k] = f2bf(v.w);
    }
    __syncthreads();
    int wv = threadIdx.x >> 6, lane = threadIdx.x & 63;
    int nn = lane & 15, kq = lane >> 4;
    int nbase = blockIdx.x * 64 + wv * 16;          // 16-row tiles; N%16==0
    if (nbase >= N_NODES) return;
    f32x4 acc[8];
#pragma unroll
    for (int nt = 0; nt < 8; nt++) {
        float bv = b[nt * 16 + nn];
        acc[nt] = (f32x4){bv, bv, bv, bv};
    }
    const float* xr = x + (size_t)(nbase + nn) * F_IN + kq * 8;
#pragma unroll
    for (int kk = 0; kk < 4; kk++) {
        float4 v0 = *(const float4*)(xr + kk * 32);
        float4 v1 = *(const float4*)(xr + kk * 32 + 4);
        bf16x8 A;
        A[0] = (short)f2bf(v0.x); A[1] = (short)f2bf(v0.y);
        A[2] = (short)f2bf(v0.z); A[3] = (short)f2bf(v0.w);
        A[4] = (short)f2bf(v1.x); A[5] = (short)f2bf(v1.y);
        A[6] = (short)f2bf(v1.z); A[7] = (short)f2bf(v1.w);
        int kb = kk * 32 + kq * 8;
#pragma unroll
        for (int nt = 0; nt < 8; nt++) {
            bf16x8 B = *(const bf16x8*)(&Wt[nt * 16 + nn][kb]);
            acc[nt] = __builtin_amdgcn_mfma_f32_16x16x32_bf16(A, B, acc[nt], 0, 0, 0);
        }
    }
    // C layout: col = lane&15 (=nn), row = kq*4 + r  [verified m89]
#pragma unroll
    for (int nt = 0; nt < 8; nt++) {
#pragma unroll
        for (int r = 0; r < 4; r++) {
            int row = nbase + kq * 4 + r;
            out[(size_t)row * NHF + nt * 16 + nn] = fmaxf(acc[nt][r], 0.f);
        }
    }
}

// ---- CSR build ----
__global__ __launch_bounds__(256) void k_hist(const int* __restrict__ dst,
                                              int* __restrict__ counts) {
    int e = blockIdx.x * 256 + threadIdx.x;
    if (e < N_EDGES) atomicAdd(counts + dst[e], 1);
}

__global__ __launch_bounds__(SCAN_BLK) void k_scan1(const int* __restrict__ counts,
        int* __restrict__ excl, int* __restrict__ bsum) {
    __shared__ int s[SCAN_BLK];
    int i = blockIdx.x * SCAN_BLK + threadIdx.x;
    int v = (i < N_NODES) ? counts[i] : 0;
    s[threadIdx.x] = v;
    __syncthreads();
    for (int d = 1; d < SCAN_BLK; d <<= 1) {
        int t = (threadIdx.x >= d) ? s[threadIdx.x - d] : 0;
        __syncthreads();
        s[threadIdx.x] += t;
        __syncthreads();
    }
    if (i < N_NODES) excl[i] = s[threadIdx.x] - v;
    if (threadIdx.x == SCAN_BLK - 1) bsum[blockIdx.x] = s[SCAN_BLK - 1];
}

__global__ __launch_bounds__(128) void k_scan2(int* __restrict__ bsum) {
    __shared__ int s[128];
    int v = (threadIdx.x < N_SCAN_BLKS) ? bsum[threadIdx.x] : 0;
    s[threadIdx.x] = v;
    __syncthreads();
    for (int d = 1; d < 128; d <<= 1) {
        int t = (threadIdx.x >= d) ? s[threadIdx.x - d] : 0;
        __syncthreads();
        s[threadIdx.x] += t;
        __syncthreads();
    }
    if (threadIdx.x < N_SCAN_BLKS) bsum[threadIdx.x] = s[threadIdx.x] - v;
}

__global__ __launch_bounds__(SCAN_BLK) void k_scan3(const int* __restrict__ excl,
        const int* __restrict__ bsum, int* __restrict__ row_start,
        int* __restrict__ cursor) {
    int i = blockIdx.x * SCAN_BLK + threadIdx.x;
    if (i < N_NODES) {
        int v = excl[i] + bsum[blockIdx.x];
        row_start[i] = v;
        cursor[i] = v;
    }
}

__global__ __launch_bounds__(256) void k_fill(const int* __restrict__ src,
        const int* __restrict__ dst, int* __restrict__ cursor,
        int* __restrict__ csr_e, int* __restrict__ srcp,
        int* __restrict__ inv_pos) {
    int e = blockIdx.x * 256 + threadIdx.x;
    if (e < N_EDGES) {
        int pos = atomicAdd(cursor + dst[e], 1);
        csr_e[pos] = e;
        srcp[pos] = src[e];
        inv_pos[e] = pos;
    }
}

// ---- edge_attr fp32 -> bf16 in MFMA A-fragment tile layout ----
__global__ __launch_bounds__(256) void k_cast(const float* __restrict__ edge_attr,
                                              unsigned short* __restrict__ eaA) {
    int t = blockIdx.x * 256 + threadIdx.x;         // over N_TILES*64
    int tile = t >> 6, lane = t & 63;
    int m = lane & 15, kq = lane >> 4;
    const float4* s = (const float4*)(edge_attr + ((size_t)tile * 16 + m) * F_EDGE + kq * 8);
    float4 v0 = s[0], v1 = s[1];
    *(ushort4*)(eaA + (size_t)t * 8)     = pack4(v0);
    *(ushort4*)(eaA + (size_t)t * 8 + 4) = pack4(v1);
}

// ---- MFMA edge linears: ea = E@Wa+ba (csr order), em = E@Wm+bm ([q][j][f]) ----
__global__ __launch_bounds__(256) void k_edgepair(const unsigned short* __restrict__ eaA,
        const float* __restrict__ aew, const float* __restrict__ aeb,
        const float* __restrict__ mew, const float* __restrict__ meb,
        const int* __restrict__ inv_pos, unsigned short* __restrict__ ea_csr,
        unsigned short* __restrict__ emX) {
    __shared__ unsigned short stg[4][2][16][40];    // [wave][matrix][row][32+8 pad]
    int wv = threadIdx.x >> 6, lane = threadIdx.x & 63;
    int nn = lane & 15, kq = lane >> 4;
    bf16x8 Ba0, Ba1, Bm0, Bm1;
#pragma unroll
    for (int j = 0; j < 8; j++) {
        int k = kq * 8 + j;
        Ba0[j] = (short)f2bf(aew[k * F + nn]);
        Ba1[j] = (short)f2bf(aew[k * F + 16 + nn]);
        Bm0[j] = (short)f2bf(mew[k * F + nn]);
        Bm1[j] = (short)f2bf(mew[k * F + 16 + nn]);
    }
    float ba0 = aeb[nn], ba1 = aeb[16 + nn];
    float bm0 = meb[nn], bm1 = meb[16 + nn];
    for (int tt = 0; tt < 4; tt++) {
        int tile = blockIdx.x * 16 + wv * 4 + tt;   // wave-uniform guard
        if (tile >= N_TILES) break;
        bf16x8 A = *(const bf16x8*)(eaA + ((size_t)tile * 64 + lane) * 8);
        f32x4 c0 = {ba0, ba0, ba0, ba0};
        f32x4 c1 = {ba1, ba1, ba1, ba1};
        f32x4 c2 = {bm0, bm0, bm0, bm0};
        f32x4 c3 = {bm1, bm1, bm1, bm1};
        c0 = __builtin_amdgcn_mfma_f32_16x16x32_bf16(A, Ba0, c0, 0, 0, 0);
        c1 = __builtin_amdgcn_mfma_f32_16x16x32_bf16(A, Ba1, c1, 0, 0, 0);
        c2 = __builtin_amdgcn_mfma_f32_16x16x32_bf16(A, Bm0, c2, 0, 0, 0);
        c3 = __builtin_amdgcn_mfma_f32_16x16x32_bf16(A, Bm1, c3, 0, 0, 0);
#pragma unroll
        for (int r = 0; r < 4; r++) {
            int row = kq * 4 + r;
            stg[wv][0][row][nn]      = f2bf(c0[r]);
            stg[wv][0][row][nn + 16] = f2bf(c1[r]);
            stg[wv][1][row][nn]      = f2bf(c2[r]);
            stg[wv][1][row][nn + 16] = f2bf(c3[r]);
        }
        __builtin_amdgcn_s_waitcnt(0);
#pragma unroll
        for (int it = 0; it < 2; it++) {
            int rg = (it == 0) ? (lane >> 2) : (16 + (lane >> 2));
            int seg = lane & 3;
            int mat = rg >> 4, r = rg & 15;
            int e = tile * 16 + r;
            uint4 v = *(uint4*)&stg[wv][mat][r][seg * 8];
            if (mat == 0) {
                int p = inv_pos[e];
                *(uint4*)(ea_csr + (size_t)p * F + seg * 8) = v;
            } else {
                int q = e % EQ, j = e / EQ;
                *(uint4*)(emX + (size_t)q * NHF + j * F + seg * 8) = v;
            }
        }
    }
}

// ---- xs,xd,xm = h @ {Ws,Wd,Wm} + b -> bf16 outputs ----
__global__ __launch_bounds__(256) void k_nodelin3(const float* __restrict__ h,
        const float* __restrict__ ws, const float* __restrict__ bs,
        const float* __restrict__ wd, const float* __restrict__ bd,
        const float* __restrict__ wm, const float* __restrict__ bm,
        unsigned short* __restrict__ xs, unsigned short* __restrict__ xd,
        unsigned short* __restrict__ xm) {
    __shared__ float Ws[F * F], Wd[F * F], Wm[F * F];
    __shared__ float hrt[F][64];
    for (int i = threadIdx.x; i < F * F; i += 256) {
        Ws[i] = ws[i]; Wd[i] = wd[i]; Wm[i] = wm[i];
    }
    int rbase = blockIdx.x * 64;
    for (int i = threadIdx.x; i < 512; i += 256) {
        int row = i >> 3, kq = i & 7;
        float4 v = *(const float4*)(h + (size_t)(rbase + row) * F + kq * 4);
        hrt[kq * 4 + 0][row] = v.x; hrt[kq * 4 + 1][row] = v.y;
        hrt[kq * 4 + 2][row] = v.z; hrt[kq * 4 + 3][row] = v.w;
    }
    __syncthreads();
    int rl = threadIdx.x >> 2;
    int jg = threadIdx.x & 3;
    float4 s0 = *(const float4*)(bs + jg * 8), s1 = *(const float4*)(bs + jg * 8 + 4);
    float4 d0 = *(const float4*)(bd + jg * 8), d1 = *(const float4*)(bd + jg * 8 + 4);
    float4 m0 = *(const float4*)(bm + jg * 8), m1 = *(const float4*)(bm + jg * 8 + 4);
    for (int k = 0; k < F; k++) {
        float hv = hrt[k][rl];
        float4 a, b2;
        a = *(const float4*)(Ws + k * F + jg * 8); b2 = *(const float4*)(Ws + k * F + jg * 8 + 4);
        s0.x += hv * a.x; s0.y += hv * a.y; s0.z += hv * a.z; s0.w += hv * a.w;
        s1.x += hv * b2.x; s1.y += hv * b2.y; s1.z += hv * b2.z; s1.w += hv * b2.w;
        a = *(const float4*)(Wd + k * F + jg * 8); b2 = *(const float4*)(Wd + k * F + jg * 8 + 4);
        d0.x += hv * a.x; d0.y += hv * a.y; d0.z += hv * a.z; d0.w += hv * a.w;
        d1.x += hv * b2.x; d1.y += hv * b2.y; d1.z += hv * b2.z; d1.w += hv * b2.w;
        a = *(const float4*)(Wm + k * F + jg * 8); b2 = *(const float4*)(Wm + k * F + jg * 8 + 4);
        m0.x += hv * a.x; m0.y += hv * a.y; m0.z += hv * a.z; m0.w += hv * a.w;
        m1.x += hv * b2.x; m1.y += hv * b2.y; m1.z += hv * b2.z; m1.w += hv * b2.w;
    }
    size_t o = (size_t)(rbase + rl) * F + jg * 8;
    *(ushort4*)(xs + o) = pack4(s0); *(ushort4*)(xs + o + 4) = pack4(s1);
    *(ushort4*)(xd + o) = pack4(d0); *(ushort4*)(xd + o + 4) = pack4(d1);
    *(ushort4*)(xm + o) = pack4(m0); *(ushort4*)(xm + o + 4) = pack4(m1);
}

// ---- fused attention: one wave per dst node; logits + joint softmax ----
__global__ __launch_bounds__(256) void k_attn(const unsigned short* __restrict__ ea_csr,
        const unsigned short* __restrict__ xs, const unsigned short* __restrict__ xd,
        const int* __restrict__ srcp, const int* __restrict__ row_start,
        const int* __restrict__ counts, const int* __restrict__ csr_e,
        const float* __restrict__ dw, const float* __restrict__ db,
        float* __restrict__ alphaT) {
    __shared__ float lg[4][512];                    // 8 KB; items cap 512
    int wv = threadIdx.x >> 6, lane = threadIdx.x & 63;
    int n = blockIdx.x * 4 + wv;
    if (n >= N_NODES) return;
    int start = row_start[n];
    int items = counts[n] * 4;
    float4 wreg[8];
#pragma unroll
    for (int q = 0; q < 8; q++) wreg[q] = *(const float4*)(dw + q * 4);
    float dbv = db[0];
    const unsigned short* xsr = xs + (size_t)n * NHF;
    float m = -1e30f;
    for (int i = lane; i < items; i += 64) {
        int ii = i >> 2, hh = i & 3;
        int p = start + ii;
        int s = srcp[p];
        const unsigned short* ear = ea_csr + (size_t)p * F;
        const unsigned short* xsh = xsr + hh * F;
        const unsigned short* xdh = xd + (size_t)s * NHF + hh * F;
        float acc = 0.f;
#pragma unroll
        for (int q = 0; q < 8; q++) {
            ushort4 ue = *(const ushort4*)(ear + q * 4);
            ushort4 ua = *(const ushort4*)(xsh + q * 4);
            ushort4 ub = *(const ushort4*)(xdh + q * 4);
            acc += fmaxf(bf2f(ua.x) + bf2f(ub.x) + bf2f(ue.x), 0.f) * wreg[q].x;
            acc += fmaxf(bf2f(ua.y) + bf2f(ub.y) + bf2f(ue.y), 0.f) * wreg[q].y;
            acc += fmaxf(bf2f(ua.z) + bf2f(ub.z) + bf2f(ue.z), 0.f) * wreg[q].z;
            acc += fmaxf(bf2f(ua.w) + bf2f(ub.w) + bf2f(ue.w), 0.f) * wreg[q].w;
        }
        float l = acc + dbv;
        lg[wv][i] = l;
        m = fmaxf(m, l);
    }
#pragma unroll
    for (int d = 1; d < 64; d <<= 1) m = fmaxf(m, __shfl_xor(m, d));
    float ssum = 0.f;
    for (int i = lane; i < items; i += 64) ssum += __expf(lg[wv][i] - m);
#pragma unroll
    for (int d = 1; d < 64; d <<= 1) ssum += __shfl_xor(ssum, d);
    float inv = 1.f / (ssum + 1e-8f);
    for (int i = lane; i < items; i += 64) {
        int ii = i >> 2, hh = i & 3;
        int e = csr_e[start + ii];
        float a = __expf(lg[wv][i] - m) * inv;
        alphaT[(size_t)(e % EQ) * 16 + hh * 4 + (e / EQ)] = a;
    }
}

// ---- q-major message build ----
__global__ __launch_bounds__(256) void k_msgq(const float* __restrict__ alphaT,
        const unsigned short* __restrict__ emX, const unsigned short* __restrict__ xm,
        const int* __restrict__ dst, const int* __restrict__ inv_pos,
        unsigned short* __restrict__ ems_csr) {
    int g = blockIdx.x * 8 + (threadIdx.x >> 5);
    if (g >= EQ) return;
    int f = threadIdx.x & 31;
    const float4* a4 = (const float4*)(alphaT + (size_t)g * 16);
    float4 ac[4] = {a4[0], a4[1], a4[2], a4[3]};    // ac[c] = alphas over j
    int4 dj = make_int4(dst[g], dst[g + EQ], dst[g + 2 * EQ], dst[g + 3 * EQ]);
    float out[4] = {0.f, 0.f, 0.f, 0.f};
#pragma unroll
    for (int j = 0; j < 4; j++) {
        int d = (j == 0) ? dj.x : (j == 1) ? dj.y : (j == 2) ? dj.z : dj.w;
        float emv = bf2f(emX[(size_t)g * NHF + j * F + f]);
        const unsigned short* xr = xm + (size_t)d * NHF + f;
#pragma unroll
        for (int c = 0; c < 4; c++) {
            float a = (j == 0) ? ac[c].x : (j == 1) ? ac[c].y
                    : (j == 2) ? ac[c].z : ac[c].w;
            out[c] += a * (bf2f(xr[c * F]) + emv);
        }
    }
    const int4 pos = *(const int4*)(inv_pos + (size_t)g * 4);
#pragma unroll
    for (int c = 0; c < 4; c++) {
        int p = (c == 0) ? pos.x : (c == 1) ? pos.y : (c == 2) ? pos.z : pos.w;
        ems_csr[(size_t)p * F + f] = f2bf(out[c]);
    }
}

// ---- combine, retiled: 64 flat rows (16 nodes)/block ----
__global__ __launch_bounds__(256) void k_combine(const float* __restrict__ h,
        const unsigned short* __restrict__ ems_csr, const int* __restrict__ row_start,
        const int* __restrict__ counts, const float* __restrict__ atom_in,
        const float* __restrict__ wn, const float* __restrict__ bn,
        float* __restrict__ hout, float* __restrict__ final_out, int is_final) {
    __shared__ float W[F * F];                           // 4 KB
    __shared__ float hrt[F][64];                         // 8 KB
    __shared__ float smv[64][F + 4];                     // 9 KB (final epilogue)
    for (int i = threadIdx.x; i < F * F; i += 256) W[i] = wn[i];
    int rbase = blockIdx.x * 64;
    for (int i = threadIdx.x; i < 512; i += 256) {
        int row = i >> 3, kq = i & 7;
        float4 v = *(const float4*)(h + (size_t)(rbase + row) * F + kq * 4);
        hrt[kq * 4 + 0][row] = v.x; hrt[kq * 4 + 1][row] = v.y;
        hrt[kq * 4 + 2][row] = v.z; hrt[kq * 4 + 3][row] = v.w;
    }
    __syncthreads();
    int rl = threadIdx.x >> 2;                           // flat row local 0..63
    int jg = threadIdx.x & 3;                            // 8-col group
    float4 a0 = *(const float4*)(bn + jg * 8);
    float4 a1 = *(const float4*)(bn + jg * 8 + 4);
    for (int k = 0; k < F; k++) {
        float hv = hrt[k][rl];
        float4 w0 = *(const float4*)(W + k * F + jg * 8);
        float4 w1 = *(const float4*)(W + k * F + jg * 8 + 4);
        a0.x += hv * w0.x; a0.y += hv * w0.y; a0.z += hv * w0.z; a0.w += hv * w0.w;
        a1.x += hv * w1.x; a1.y += hv * w1.y; a1.z += hv * w1.z; a1.w += hv * w1.w;
    }
    int m = rbase + rl;                                  // flat row of (N*H,F)
    float4 g0 = make_float4(0.f, 0.f, 0.f, 0.f);
    float4 g1 = make_float4(0.f, 0.f, 0.f, 0.f);
    if (m < N_NODES) {                                   // rows >= N get no msgs
        int st = row_start[m], deg = counts[m];
        const unsigned short* er = ems_csr + (size_t)st * F + jg * 8;
        int p = 0;
        for (; p + 2 <= deg; p += 2) {
            ushort4 u0 = *(const ushort4*)(er);
            ushort4 u1 = *(const ushort4*)(er + 4);
            ushort4 v0 = *(const ushort4*)(er + F);
            ushort4 v1 = *(const ushort4*)(er + F + 4);
            g0.x += bf2f(u0.x) + bf2f(v0.x); g0.y += bf2f(u0.y) + bf2f(v0.y);
            g0.z += bf2f(u0.z) + bf2f(v0.z); g0.w += bf2f(u0.w) + bf2f(v0.w);
            g1.x += bf2f(u1.x) + bf2f(v1.x); g1.y += bf2f(u1.y) + bf2f(v1.y);
            g1.z += bf2f(u1.z) + bf2f(v1.z); g1.w += bf2f(u1.w) + bf2f(v1.w);
            er += 2 * F;
        }
        if (p < deg) {
            ushort4 u0 = *(const ushort4*)(er);
            ushort4 u1 = *(const ushort4*)(er + 4);
            g0.x += bf2f(u0.x); g0.y += bf2f(u0.y);
            g0.z += bf2f(u0.z); g0.w += bf2f(u0.w);
            g1.x += bf2f(u1.x); g1.y += bf2f(u1.y);
            g1.z += bf2f(u1.z); g1.w += bf2f(u1.w);
        }
    }
    size_t idx = (size_t)m * F + jg * 8;                 // == n*NHF+head*F+jg*8
    float4 t0 = *(const float4*)(atom_in + idx);
    float4 t1 = *(const float4*)(atom_in + idx + 4);
    float4 v0, v1;
    v0.x = fmaxf(a0.x + g0.x + t0.x, 0.f); v0.y = fmaxf(a0.y + g0.y + t0.y, 0.f);
    v0.z = fmaxf(a0.z + g0.z + t0.z, 0.f); v0.w = fmaxf(a0.w + g0.w + t0.w, 0.f);
    v1.x = fmaxf(a1.x + g1.x + t1.x, 0.f); v1.y = fmaxf(a1.y + g1.y + t1.y, 0.f);
    v1.z = fmaxf(a1.z + g1.z + t1.z, 0.f); v1.w = fmaxf(a1.w + g1.w + t1.w, 0.f);
    if (!is_final) {
        *(float4*)(hout + idx) = v0;
        *(float4*)(hout + idx + 4) = v1;
    } else {
        *(float4*)(&smv[rl][jg * 8]) = v0;
        *(float4*)(&smv[rl][jg * 8 + 4]) = v1;
        __syncthreads();
#pragma unroll
        for (int it = 0; it < 2; it++) {
            int oi = threadIdx.x + it * 256;
            int nl = oi >> 5, f = oi & 31;               // node-local, feature
            float o = 0.25f * (smv[nl * 4 + 0][f] + smv[nl * 4 + 1][f] +
                               smv[nl * 4 + 2][f] + smv[nl * 4 + 3][f]);
            final_out[((size_t)(rbase >> 2) + nl) * F + f] = o;
        }
    }
}

extern "C" void kernel_launch(void* const* d_in, const int* in_sizes, int n_in,
                              void* d_out, int out_size, void* d_ws, size_t ws_size,
                              hipStream_t stream) {
    const float* x         = (const float*)d_in[0];
    const float* edge_attr = (const float*)d_in[1];
    const int*   eidx      = (const int*)d_in[2];
    const int*   src       = eidx;
    const int*   dst       = eidx + N_EDGES;
    const float* atom_w    = (const float*)d_in[3];
    const float* atom_b    = (const float*)d_in[4];
    const float* asw = (const float*)d_in[5],  *asb = (const float*)d_in[6];
    const float* adw = (const float*)d_in[7],  *adb = (const float*)d_in[8];
    const float* aew = (const float*)d_in[9],  *aeb = (const float*)d_in[10];
    const float* dww = (const float*)d_in[11], *dwb = (const float*)d_in[12];
    const float* mdw = (const float*)d_in[13], *mdb = (const float*)d_in[14];
    const float* mew = (const float*)d_in[15], *meb = (const float*)d_in[16];
    const float* wnw = (const float*)d_in[17], *wnb = (const float*)d_in[18];
    float* out = (float*)d_out;

    float* ws = (float*)d_ws;
    size_t off = 0;
    float* atom_in = ws + off; off += (size_t)N_NODES * NHF;
    float* hbuf    = ws + off; off += (size_t)N_NODES * NHF;
    unsigned short* xs_bf  = (unsigned short*)(ws + off); off += (size_t)N_NODES * NHF / 2;
    unsigned short* xd_bf  = (unsigned short*)(ws + off); off += (size_t)N_NODES * NHF / 2;
    unsigned short* xm_bf  = (unsigned short*)(ws + off); off += (size_t)N_NODES * NHF / 2;
    unsigned short* ea_csr = (unsigned short*)(ws + off); off += (size_t)N_EDGES * F / 2;
    unsigned short* emX    = (unsigned short*)(ws + off); off += (size_t)N_EDGES * F / 2;
    unsigned short* ems    = (unsigned short*)(ws + off); off += (size_t)N_EDGES * F / 2;
    unsigned short* eaA    = (unsigned short*)(ws + off); off += (size_t)N_EDGES * F_EDGE / 2;
    float* alphaT  = ws + off; off += (size_t)N_EDGES * H;
    int* counts    = (int*)(ws + off); off += N_NODES;
    int* row_start = (int*)(ws + off); off += N_NODES;
    int* cursor    = (int*)(ws + off); off += N_NODES;
    int* excl      = (int*)(ws + off); off += N_NODES;
    int* bsum      = (int*)(ws + off); off += 128;
    int* csr_e     = (int*)(ws + off); off += N_EDGES;
    int* srcp      = (int*)(ws + off); off += N_EDGES;
    int* inv_pos   = (int*)(ws + off); off += N_EDGES;

    // ---- CSR build (dst is layer-invariant) ----
    hipMemsetAsync(counts, 0, N_NODES * sizeof(int), stream);
    k_hist <<<(N_EDGES + 255) / 256, 256, 0, stream>>>(dst, counts);
    k_scan1<<<N_SCAN_BLKS, SCAN_BLK, 0, stream>>>(counts, excl, bsum);
    k_scan2<<<1, 128, 0, stream>>>(bsum);
    k_scan3<<<N_SCAN_BLKS, SCAN_BLK, 0, stream>>>(excl, bsum, row_start, cursor);
    k_fill <<<(N_EDGES + 255) / 256, 256, 0, stream>>>(src, dst, cursor, csr_e,
                                                       srcp, inv_pos);
    k_cast <<<(N_TILES * 64) / 256, 256, 0, stream>>>(edge_attr, eaA);

    k_atom<<<(N_NODES + 63) / 64, 256, 0, stream>>>(x, atom_w, atom_b, atom_in);

    for (int l = 0; l < 2; l++) {
        const float* hin  = (l == 0) ? atom_in : hbuf;
        float*       hout = hbuf;
        int is_final = (l == 1);
        k_nodelin3<<<(N_NODES * H) / 64, 256, 0, stream>>>(
            hin, asw + l * F * F, asb + l * F, adw + l * F * F, adb + l * F,
            mdw + l * F * F, mdb + l * F, xs_bf, xd_bf, xm_bf);
        k_edgepair<<<(N_TILES + 15) / 16, 256, 0, stream>>>(
            eaA, aew + l * F_EDGE * F, aeb + l * F,
            mew + l * F_EDGE * F, meb + l * F, inv_pos, ea_csr, emX);
        k_attn<<<(N_NODES + 3) / 4, 256, 0, stream>>>(
            ea_csr, xs_bf, xd_bf, srcp, row_start, counts, csr_e,
            dww + l * F, dwb + l, alphaT);
        k_msgq<<<(EQ + 7) / 8, 256, 0, stream>>>(alphaT, emX, xm_bf, dst,
                                                 inv_pos, ems);
        k_combine<<<(N_NODES * H) / 64, 256, 0, stream>>>(
            hin, ems, row_start, counts, atom_in, wnw + l * F * F,
            wnb + l * F, hout, out, is_final);
    }
}